// Round 14
// baseline (264.590 us; speedup 1.0000x reference)
//
#include <hip/hip_runtime.h>
#include <math.h>

// Problem dims (fixed by setup_inputs)
#define DD    512
#define CNUM  64
#define SHOTS 16
#define NSUP  1024
#define QNQ   2048
#define REGP  0.1f
#define XKS   4      // xmu split-K parts

typedef __attribute__((ext_vector_type(8))) short short8;   // 8 bf16 = 4 VGPRs
typedef __attribute__((ext_vector_type(4))) float f32x4;

// bf16 round-to-nearest-even, raw bits
__device__ __forceinline__ unsigned short f2bf(float f) {
  unsigned int u = __float_as_uint(f);
  unsigned int r = (u + 0x7fffu + ((u >> 16) & 1u)) >> 16;
  return (unsigned short)r;
}
__device__ __forceinline__ float bf2f(unsigned short h) {
  return __uint_as_float((unsigned int)h << 16);
}

// ---------------- workspace layout (in floats) ----------------
static constexpr size_t OFF_L     = 0;                       // 512*512
static constexpr size_t OFF_W     = OFF_L     + 512*512;     // 512*512
static constexpr size_t OFF_MU    = OFF_W     + 512*512;     // 64*512
static constexpr size_t OFF_Y     = OFF_MU    + 64*512;      // 3136*512
static constexpr size_t OFF_Z     = OFF_Y     + 3136*512;    // 3136 (2048 used)
static constexpr size_t OFF_WM    = OFF_Z     + 3136;        // 512
static constexpr size_t OFF_CONST = OFF_WM    + 512;         // 16
static constexpr size_t OFF_IDX   = OFF_CONST + 16;          // 1024 ints
static constexpr size_t OFF_RMAP  = OFF_IDX   + 1024;        // 1088 ints
static constexpr size_t OFF_ZG    = OFF_RMAP  + 1088;        // 1088
static constexpr size_t OFF_VMU   = OFF_ZG    + 1088;        // 1088
static constexpr size_t OFF_MUBMU = OFF_VMU   + 1088;        // 64
static constexpr size_t OFF_MUN   = OFF_MUBMU + 64;          // 64
static constexpr size_t OFF_MINV  = OFF_MUN   + 64;          // 64*289
static constexpr size_t OFF_BIAS  = OFF_MINV  + 64*289;      // 64
static constexpr size_t OFF_QNRM  = OFF_BIAS  + 64;          // 2048
static constexpr size_t OFF_YN    = OFF_QNRM  + 2048;        // 2048
static constexpr size_t OFF_XMU   = OFF_YN    + 2048;        // XKS*2048*64
static constexpr size_t OFF_TMP   = OFF_XMU   + (size_t)XKS*2048*64; // 65536 (trinv T)
static constexpr size_t OFF_P     = OFF_TMP   + 65536;       // 3136*1024 bf16 (Y split)
static constexpr size_t OFF_PX    = OFF_P     + 3136*512;    // 3136*1024 bf16 (X split)
static constexpr size_t OFF_PW    = OFF_PX    + 3136*512;    // 512*1024 bf16 (W split)

// consts: 0 kap, 1 scale, 2 common, 3 coef, 4 bias0, 5 jlast,
// 6 cmu_m, 7 cmu_x, 8 D*log(scale), 9 Jinv_last, 10 c_sm, 11 logdetB

// ============ F1: L/W/PW init + consts + classidx + mu/mun(+PX) + diag-inv(+PW) + PX(X) ============
__global__ __launch_bounds__(256) void f_init(const float* tdiag, const float* tlow,
    const float* kappa, const float* nu, const int* labels, const float* Xs,
    const float* Xq, const float* m, float* L, float* W, float* cst, int* idx,
    int* rowmap, float* mu, float* mun,
    unsigned short* PX, unsigned short* PW) {
  __shared__ float sh[2 * 64 * 68];   // 34.8 KB union
  __shared__ int sidx[SHOTS];
  int b = blockIdx.x, tid = threadIdx.x;
  if (b < 1024) {
    int t = b * 256 + tid;
    int i = t >> 9, j = t & 511;
    L[t] = (i == j) ? fabsf(tdiag[i]) : (i > j ? tlow[t] : 0.0f);
    if ((i >> 6) < (j >> 6)) {          // strict-upper 64-blocks: zero W and PW
      W[t] = 0.0f;
      PW[(size_t)i * 1024 + j] = 0;
      PW[(size_t)i * 1024 + 512 + j] = 0;
    }
  } else if (b == 1024) {
    if (tid == 0) {
      float kap = fabsf(kappa[0]) + 1e-6f;
      float nu_ = fmaxf(nu[0], (float)(DD - 1) + 1e-6f);
      float common = nu_ + (float)SHOTS + 1.0f - (float)DD;
      float scale = (kap + SHOTS + 1.0f) / ((nu_ + SHOTS - DD + 1.0f) * (kap + SHOTS));
      cst[0] = kap;
      cst[1] = scale;
      cst[2] = common;
      cst[3] = 0.5f * (common + DD);
      cst[4] = lgammaf(0.5f * (common + DD)) - lgammaf(0.5f * common)
               - 0.5f * (float)DD * logf(common);
      cst[5] = -(kap + SHOTS);
      cst[6] = kap / (kap + SHOTS);
      cst[7] = 1.0f / (kap + SHOTS);
      cst[8] = (float)DD * logf(scale);
      cst[9] = -1.0f / (kap + SHOTS);
    }
  } else if (b < 1089) {
    int c = b - 1025;
    if (tid < 64) {
      int lane = tid, cnt = 0;
      for (int i0 = 0; i0 < NSUP; i0 += 64) {
        int lab = labels[i0 + lane];
        unsigned long long mm = __ballot(lab == c);
        if (lab == c) {
          int pos = cnt + __popcll(mm & ((1ull << lane) - 1ull));
          if (pos < SHOTS) idx[c * SHOTS + pos] = i0 + lane;
        }
        cnt += __popcll(mm);
      }
    }
    __syncthreads();
    if (tid < 17)
      rowmap[c * 17 + tid] = (tid < SHOTS) ? (QNQ + idx[c * SHOTS + tid])
                                           : (QNQ + NSUP + c);
  } else if (b < 1153) {
    // mu/mun with locally re-derived idx; also emit PX for mu rows
    int c = b - 1089;
    if (tid < 64) {
      int lane = tid, cnt = 0;
      for (int i0 = 0; i0 < NSUP; i0 += 64) {
        int lab = labels[i0 + lane];
        unsigned long long mm = __ballot(lab == c);
        if (lab == c) {
          int pos = cnt + __popcll(mm & ((1ull << lane) - 1ull));
          if (pos < SHOTS) sidx[pos] = i0 + lane;
        }
        cnt += __popcll(mm);
      }
    }
    __syncthreads();
    float kap = fabsf(kappa[0]) + 1e-6f;
    float cm = kap / (kap + SHOTS), cx = 1.0f / (kap + SHOTS);
    float* red = sh;
    float acc = 0.0f;
    size_t prow = (size_t)(3072 + c) * 1024;
    for (int d = tid; d < DD; d += 256) {
      float s = 0.0f;
      for (int sh_ = 0; sh_ < SHOTS; sh_++)
        s += Xs[(size_t)sidx[sh_] * DD + d];
      float v = cm * m[d] + cx * s;
      mu[(size_t)c * DD + d] = v;
      unsigned short h = f2bf(v), l = f2bf(v - bf2f(h));
      PX[prow + d] = h;
      PX[prow + 512 + d] = l;
      acc += v * v;
    }
    red[tid] = acc;
    __syncthreads();
    for (int off = 128; off > 0; off >>= 1) {
      if (tid < off) red[tid] += red[tid + off];
      __syncthreads();
    }
    if (tid == 0) mun[c] = red[0];
  } else if (b < 1161) {
    // diag 64x64 inverse + PW emit
    int jb = b - 1153;
    float* Ld = sh;             // [64][68]
    float* Wd = sh + 64 * 68;   // [64][68]
    for (int t = tid; t < 4096; t += 256) {
      int r = t >> 6, c = t & 63;
      int gr = jb * 64 + r;
      float v = (r == c) ? fabsf(tdiag[gr])
              : (r > c ? tlow[(size_t)gr * DD + jb * 64 + c] : 0.0f);
      Ld[r * 68 + c] = v;
    }
    __syncthreads();
    if (tid < 64) {
      for (int i = 0; i < 64; i++) {
        float w = (i == tid) ? 1.0f : 0.0f;
        for (int k = 0; k < i; k++) w -= Ld[i * 68 + k] * Wd[k * 68 + tid];
        Wd[i * 68 + tid] = w / Ld[i * 68 + i];
      }
    }
    __syncthreads();
    float* Wblk = W + (size_t)(jb * 64) * DD + jb * 64;
    for (int t = tid; t < 4096; t += 256) {
      int r = t >> 6, c = t & 63;
      float v = Wd[r * 68 + c];
      Wblk[(size_t)r * DD + c] = v;
      unsigned short h = f2bf(v), l = f2bf(v - bf2f(h));
      size_t prow = (size_t)(jb * 64 + r) * 1024 + jb * 64 + c;
      PW[prow] = h;
      PW[prow + 512] = l;
    }
  } else {
    // PX for Xq/Xs rows: 4 rows per block
    int r0 = (b - 1161) * 4;
    int row = r0 + (tid >> 6), lane = tid & 63;
    const float* src = (row < QNQ) ? Xq + (size_t)row * DD
                                   : Xs + (size_t)(row - QNQ) * DD;
    size_t prow = (size_t)row * 1024;
    #pragma unroll
    for (int p = 0; p < 2; p++) {
      int col = lane * 8 + p * 4;
      float4 v = *(const float4*)(src + col);
      ushort4 hi, lo;
      hi.x = f2bf(v.x); lo.x = f2bf(v.x - bf2f(hi.x));
      hi.y = f2bf(v.y); lo.y = f2bf(v.y - bf2f(hi.y));
      hi.z = f2bf(v.z); lo.z = f2bf(v.z - bf2f(hi.z));
      hi.w = f2bf(v.w); lo.w = f2bf(v.w - bf2f(hi.w));
      *(ushort4*)(PX + prow + col) = hi;
      *(ushort4*)(PX + prow + 512 + col) = lo;
    }
  }
}

// 64x64 NN GEMM tile on caller LDS (stride 68): Cd = sgn * A[:,k0:k1] * B[k0:k1,:]
// If Pw != nullptr, also emit bf16 hi/lo split at PW[gr0+.., gc0+..].
__device__ __forceinline__ void nn64_sh(float* As, float* Bs,
    const float* __restrict__ A, int lda, const float* __restrict__ B, int ldb,
    float* __restrict__ Cd, int ldc, int k0, int k1, float sgn,
    unsigned short* __restrict__ Pw, int gr0, int gc0) {
  int tid = threadIdx.x, tr = tid >> 4, tc = tid & 15;
  float acc[4][4] = {};
  for (int kc = k0; kc < k1; kc += 64) {
    #pragma unroll
    for (int p = 0; p < 4; p++) {
      int f4 = tid + 256 * p;
      int row = f4 >> 4, c4 = f4 & 15;
      *(float4*)&As[row * 68 + c4 * 4] = *(const float4*)(A + (size_t)row * lda + kc + c4 * 4);
      *(float4*)&Bs[row * 68 + c4 * 4] = *(const float4*)(B + (size_t)(kc + row) * ldb + c4 * 4);
    }
    __syncthreads();
    #pragma unroll
    for (int kk = 0; kk < 64; kk++) {
      float a[4];
      #pragma unroll
      for (int x = 0; x < 4; x++) a[x] = As[(tr * 4 + x) * 68 + kk];
      float4 bv = *(const float4*)&Bs[kk * 68 + tc * 4];
      float bb[4] = {bv.x, bv.y, bv.z, bv.w};
      #pragma unroll
      for (int x = 0; x < 4; x++)
        #pragma unroll
        for (int y = 0; y < 4; y++) acc[x][y] += a[x] * bb[y];
    }
    __syncthreads();
  }
  #pragma unroll
  for (int x = 0; x < 4; x++) {
    float4 v = make_float4(sgn * acc[x][0], sgn * acc[x][1],
                           sgn * acc[x][2], sgn * acc[x][3]);
    *(float4*)(Cd + (size_t)(tr * 4 + x) * ldc + tc * 4) = v;
    if (Pw) {
      size_t prow = (size_t)(gr0 + tr * 4 + x) * 1024 + gc0 + tc * 4;
      float vv[4] = {v.x, v.y, v.z, v.w};
      #pragma unroll
      for (int y = 0; y < 4; y++) {
        unsigned short h = f2bf(vv[y]), l = f2bf(vv[y] - bf2f(h));
        Pw[prow + y] = h;
        Pw[prow + 512 + y] = l;
      }
    }
  }
}

#define GBK 16
// ============ triT level 128 fused with xmu partials ============
__global__ __launch_bounds__(256) void k_triT128_xmu(const float* __restrict__ L,
    const float* __restrict__ W, float* __restrict__ T,
    const float* __restrict__ Xq, const float* __restrict__ Mu,
    float* __restrict__ xmup) {
  __shared__ float sh[2 * 64 * 68];
  int b = blockIdx.x, tid = threadIdx.x;
  if (b < 4) {              // triT, s=128: h=64, tiles=1
    int g = b, base = g * 128;
    const float* A = L + (size_t)(base + 64) * DD + base;
    const float* B = W + (size_t)base * DD + base;
    float* Cd = T + (size_t)g * 64 * 64;
    nn64_sh(sh, sh + 64 * 68, A, DD, B, DD, Cd, 64, 0, 64, 1.0f, nullptr, 0, 0);
  } else {                  // xmu partials: 32 q-rows, split-K=4
    float* As = sh;               // stride 36, 16 rows
    float* Bs = sh + 16 * 36;     // stride 68, 16 rows
    int xb = b - 4;
    int bm = (xb & 63) * 32, kq = xb >> 6;
    int tr = tid >> 4, tc = tid & 15;
    float acc[2][4] = {};
    int k0s = kq * (DD / XKS), k0e = k0s + DD / XKS;
    for (int k0 = k0s; k0 < k0e; k0 += GBK) {
      if (tid < 128) {
        int row = tid >> 2, k4 = tid & 3;
        float4 v = *(const float4*)(Xq + (size_t)(bm + row) * DD + k0 + k4 * 4);
        As[(k4 * 4 + 0) * 36 + row] = v.x; As[(k4 * 4 + 1) * 36 + row] = v.y;
        As[(k4 * 4 + 2) * 36 + row] = v.z; As[(k4 * 4 + 3) * 36 + row] = v.w;
      }
      {
        int row = tid >> 2, k4 = tid & 3;
        float4 v = *(const float4*)(Mu + (size_t)row * DD + k0 + k4 * 4);
        Bs[(k4 * 4 + 0) * 68 + row] = v.x; Bs[(k4 * 4 + 1) * 68 + row] = v.y;
        Bs[(k4 * 4 + 2) * 68 + row] = v.z; Bs[(k4 * 4 + 3) * 68 + row] = v.w;
      }
      __syncthreads();
      #pragma unroll
      for (int kk = 0; kk < GBK; kk++) {
        float a[2] = {As[kk * 36 + tr * 2], As[kk * 36 + tr * 2 + 1]};
        float4 b0 = *(const float4*)&Bs[kk * 68 + tc * 4];
        float bb[4] = {b0.x, b0.y, b0.z, b0.w};
        #pragma unroll
        for (int x = 0; x < 2; x++)
          #pragma unroll
          for (int y = 0; y < 4; y++) acc[x][y] += a[x] * bb[y];
      }
      __syncthreads();
    }
    #pragma unroll
    for (int x = 0; x < 2; x++) {
      int q = bm + tr * 2 + x;
      float4 v = make_float4(acc[x][0], acc[x][1], acc[x][2], acc[x][3]);
      *(float4*)(xmup + ((size_t)kq * QNQ + q) * CNUM + tc * 4) = v;
    }
  }
}

// generic trinv doubling levels
__global__ __launch_bounds__(256) void k_triT(const float* __restrict__ L,
                                              const float* __restrict__ W,
                                              float* __restrict__ T, int s) {
  __shared__ float sh[2 * 64 * 68];
  int h = s >> 1, tiles = h >> 6, per = tiles * tiles;
  int g = blockIdx.x / per, rem = blockIdx.x % per;
  int ti = rem / tiles, tj = rem % tiles;
  int base = g * s;
  const float* A = L + (size_t)(base + h + ti * 64) * DD + base;
  const float* B = W + (size_t)base * DD + base + tj * 64;
  float* Cd = T + (size_t)g * h * h + (size_t)(ti * 64) * h + tj * 64;
  nn64_sh(sh, sh + 64 * 68, A, DD, B, DD, Cd, h, tj * 64, h, 1.0f, nullptr, 0, 0);
}

// triX also emits PW (the bf16 hi/lo of the W blocks it writes)
__global__ __launch_bounds__(256) void k_triX(float* __restrict__ W,
                                              const float* __restrict__ T, int s,
                                              unsigned short* __restrict__ PW) {
  __shared__ float sh[2 * 64 * 68];
  int h = s >> 1, tiles = h >> 6, per = tiles * tiles;
  int g = blockIdx.x / per, rem = blockIdx.x % per;
  int ti = rem / tiles, tj = rem % tiles;
  int base = g * s;
  const float* A = W + (size_t)(base + h + ti * 64) * DD + base + h;
  const float* B = T + (size_t)g * h * h + tj * 64;
  int gr0 = base + h + ti * 64, gc0 = base + tj * 64;
  float* Cd = W + (size_t)gr0 * DD + gc0;
  nn64_sh(sh, sh + 64 * 68, A, DD, B, h, Cd, DD, 0, (ti + 1) * 64, -1.0f, PW, gr0, gc0);
}

#define PSTR 80   // LDS row stride in bf16
// ============ F3: Y-GEMM via 4-combo bf16-split MFMA (tri-skip) + wm ============
__global__ __launch_bounds__(256) void f_y_wm(const unsigned short* __restrict__ PX,
    const unsigned short* __restrict__ PW, const float* __restrict__ W,
    const float* __restrict__ m, float* __restrict__ Y,
    unsigned short* __restrict__ Pm, float* __restrict__ wm) {
  __shared__ unsigned short AshH[64 * PSTR];
  __shared__ unsigned short AshL[64 * PSTR];
  __shared__ unsigned short BshH[64 * PSTR];
  __shared__ unsigned short BshL[64 * PSTR];
  int b = blockIdx.x, tid = threadIdx.x;
  if (b < 392) {            // 49 m-tiles x 8 n-tiles, 64x64
    int mt = b >> 3, nt = b & 7;
    int bm = mt * 64, bn = nt * 64;
    int lane = tid & 63, wave = tid >> 6;
    int wr = wave >> 1, wc = wave & 1;
    int mrow = lane & 15, q = lane >> 4;
    f32x4 acc00 = {}, acc01 = {}, acc10 = {}, acc11 = {};
    int kchunks = nt + 1;   // W lower-triangular: k < bn+64
    for (int it = 0; it < kchunks; it++) {
      int kc = it * 64;
      #pragma unroll
      for (int p = 0; p < 2; p++) {
        int idx = tid + 256 * p;
        int row = idx >> 3, c8 = (idx & 7) * 8;
        *(short8*)&AshH[row * PSTR + c8] =
            *(const short8*)(PX + (size_t)(bm + row) * 1024 + kc + c8);
        *(short8*)&AshL[row * PSTR + c8] =
            *(const short8*)(PX + (size_t)(bm + row) * 1024 + 512 + kc + c8);
        *(short8*)&BshH[row * PSTR + c8] =
            *(const short8*)(PW + (size_t)(bn + row) * 1024 + kc + c8);
        *(short8*)&BshL[row * PSTR + c8] =
            *(const short8*)(PW + (size_t)(bn + row) * 1024 + 512 + kc + c8);
      }
      __syncthreads();
      #pragma unroll
      for (int ks = 0; ks < 2; ks++) {
        int ko = ks * 32 + q * 8;
        short8 ah0 = *(const short8*)&AshH[(wr * 32 + mrow) * PSTR + ko];
        short8 ah1 = *(const short8*)&AshH[(wr * 32 + 16 + mrow) * PSTR + ko];
        short8 al0 = *(const short8*)&AshL[(wr * 32 + mrow) * PSTR + ko];
        short8 al1 = *(const short8*)&AshL[(wr * 32 + 16 + mrow) * PSTR + ko];
        short8 bh0 = *(const short8*)&BshH[(wc * 32 + mrow) * PSTR + ko];
        short8 bh1 = *(const short8*)&BshH[(wc * 32 + 16 + mrow) * PSTR + ko];
        short8 bl0 = *(const short8*)&BshL[(wc * 32 + mrow) * PSTR + ko];
        short8 bl1 = *(const short8*)&BshL[(wc * 32 + 16 + mrow) * PSTR + ko];
        acc00 = __builtin_amdgcn_mfma_f32_16x16x32_bf16(ah0, bh0, acc00, 0, 0, 0);
        acc00 = __builtin_amdgcn_mfma_f32_16x16x32_bf16(ah0, bl0, acc00, 0, 0, 0);
        acc00 = __builtin_amdgcn_mfma_f32_16x16x32_bf16(al0, bh0, acc00, 0, 0, 0);
        acc00 = __builtin_amdgcn_mfma_f32_16x16x32_bf16(al0, bl0, acc00, 0, 0, 0);
        acc01 = __builtin_amdgcn_mfma_f32_16x16x32_bf16(ah0, bh1, acc01, 0, 0, 0);
        acc01 = __builtin_amdgcn_mfma_f32_16x16x32_bf16(ah0, bl1, acc01, 0, 0, 0);
        acc01 = __builtin_amdgcn_mfma_f32_16x16x32_bf16(al0, bh1, acc01, 0, 0, 0);
        acc01 = __builtin_amdgcn_mfma_f32_16x16x32_bf16(al0, bl1, acc01, 0, 0, 0);
        acc10 = __builtin_amdgcn_mfma_f32_16x16x32_bf16(ah1, bh0, acc10, 0, 0, 0);
        acc10 = __builtin_amdgcn_mfma_f32_16x16x32_bf16(ah1, bl0, acc10, 0, 0, 0);
        acc10 = __builtin_amdgcn_mfma_f32_16x16x32_bf16(al1, bh0, acc10, 0, 0, 0);
        acc10 = __builtin_amdgcn_mfma_f32_16x16x32_bf16(al1, bl0, acc10, 0, 0, 0);
        acc11 = __builtin_amdgcn_mfma_f32_16x16x32_bf16(ah1, bh1, acc11, 0, 0, 0);
        acc11 = __builtin_amdgcn_mfma_f32_16x16x32_bf16(ah1, bl1, acc11, 0, 0, 0);
        acc11 = __builtin_amdgcn_mfma_f32_16x16x32_bf16(al1, bh1, acc11, 0, 0, 0);
        acc11 = __builtin_amdgcn_mfma_f32_16x16x32_bf16(al1, bl1, acc11, 0, 0, 0);
      }
      __syncthreads();
    }
    #pragma unroll
    for (int r = 0; r < 4; r++) {
      int row0 = bm + wr * 32 + q * 4 + r;
      int row1 = row0 + 16;
      int col0 = bn + wc * 32 + mrow;
      float vv[4] = {acc00[r], acc01[r], acc10[r], acc11[r]};
      int rows[4] = {row0, row0, row1, row1};
      int cols[4] = {col0, col0 + 16, col0, col0 + 16};
      #pragma unroll
      for (int e = 0; e < 4; e++) {
        Y[(size_t)rows[e] * DD + cols[e]] = vv[e];
        unsigned short h = f2bf(vv[e]), l = f2bf(vv[e] - bf2f(h));
        Pm[(size_t)rows[e] * 1024 + cols[e]] = h;
        Pm[(size_t)rows[e] * 1024 + 512 + cols[e]] = l;
      }
    }
  } else {                  // wm[row] = W[row,:] . m  (4 rows/block)
    int wave = tid >> 6, lane = tid & 63;
    int row = (b - 392) * 4 + wave;
    float s = 0.0f;
    for (int j = lane; j < DD; j += 64) s += W[(size_t)row * DD + j] * m[j];
    for (int off = 32; off > 0; off >>= 1) s += __shfl_down(s, off);
    if (lane == 0) wm[row] = s;
  }
}

// ============ k_sm_z: block 0 = SM consts; blocks 1..512 = per-query z/qn/yn ============
// z[q] = Y_q . wm  (== F_q . u, since u = W^T wm and Y = F W^T)
__global__ __launch_bounds__(256) void k_sm_z(const float* L, const float* wm,
    const float* Xq, const float* Y, float* cst,
    float* z, float* qn, float* yn) {
  int b = blockIdx.x, tid = threadIdx.x;
  if (b == 0) {
    __shared__ float red[256], red2[256];
    float a = 0.0f, l = 0.0f;
    for (int t = tid; t < DD; t += 256) {
      float w = wm[t]; a += w * w;
      l += logf(fabsf(L[(size_t)t * DD + t]));
    }
    red[tid] = a; red2[tid] = l;
    __syncthreads();
    for (int off = 128; off > 0; off >>= 1) {
      if (tid < off) { red[tid] += red[tid + off]; red2[tid] += red2[tid + off]; }
      __syncthreads();
    }
    if (tid == 0) {
      float kap = cst[0], ss = red[0];
      cst[10] = kap / (1.0f + kap * ss);
      cst[11] = 2.0f * red2[0] + logf(1.0f + kap * ss);
    }
  } else {
    int wave = tid >> 6, lane = tid & 63;
    int row = (b - 1) * 4 + wave;
    const float* xr = Xq + (size_t)row * DD;
    const float* yr = Y + (size_t)row * DD;
    float sz = 0.0f, s1 = 0.0f, s2 = 0.0f;
    for (int j4 = lane; j4 < 128; j4 += 64) {
      float4 xv = *(const float4*)(xr + j4 * 4);
      float4 yv = *(const float4*)(yr + j4 * 4);
      float4 wv = *(const float4*)(wm + j4 * 4);
      sz += yv.x * wv.x + yv.y * wv.y + yv.z * wv.z + yv.w * wv.w;
      s1 += xv.x * xv.x + xv.y * xv.y + xv.z * xv.z + xv.w * xv.w;
      s2 += yv.x * yv.x + yv.y * yv.y + yv.z * yv.z + yv.w * yv.w;
    }
    for (int off = 32; off > 0; off >>= 1) {
      sz += __shfl_down(sz, off);
      s1 += __shfl_down(s1, off);
      s2 += __shfl_down(s2, off);
    }
    if (lane == 0) {
      z[row] = sz;
      qn[row] = s1;
      yn[row] = s2;
    }
  }
}

// ============ F6: per-class Gram (zs = Y.wm) + GJ inverse + bias ============
#define YSTRIDE 516
__global__ __launch_bounds__(256) void k_gramminv(const float* Y, const float* wm,
    const int* rowmap, const float* cst, float* zg, float* Vmu, float* muBmu,
    float* Minv, float* bias) {
  __shared__ float Ys[17 * YSTRIDE];
  __shared__ float zs[17];
  __shared__ float aug[17][35];
  __shared__ float colk[17];
  __shared__ int pivrow;
  __shared__ float detacc;
  int c = blockIdx.x, tid = threadIdx.x;
  for (int t = tid; t < 17 * 128; t += 256) {
    int r = t >> 7, col = t & 127;
    *(float4*)&Ys[r * YSTRIDE + col * 4] =
        *(const float4*)(Y + (size_t)rowmap[c * 17 + r] * DD + col * 4);
  }
  __syncthreads();
  {
    int wave = tid >> 6, lane = tid & 63;
    for (int a = wave; a < 17; a += 4) {
      float s = 0.0f;
      for (int j = lane; j < DD; j += 64) s += Ys[a * YSTRIDE + j] * wm[j];
      for (int off = 32; off > 0; off >>= 1) s += __shfl_down(s, off);
      if (lane == 0) zs[a] = s;
    }
  }
  __syncthreads();
  float csm = cst[10];
  for (int e = tid; e < 289; e += 256) {
    int a = e / 17, bb = e % 17;
    const float* ra = &Ys[a * YSTRIDE];
    const float* rb = &Ys[bb * YSTRIDE];
    float s = 0.0f;
    for (int k = 0; k < 128; k++) {
      float4 va = *(const float4*)&ra[k * 4];
      float4 vb = *(const float4*)&rb[k * 4];
      s += va.x * vb.x + va.y * vb.y + va.z * vb.z + va.w * vb.w;
    }
    float g = s - csm * zs[a] * zs[bb];
    if (a == bb) g += (a < 16) ? 1.0f : cst[9];
    aug[a][bb] = g;
    aug[a][17 + bb] = (a == bb) ? 1.0f : 0.0f;
  }
  __syncthreads();
  if (tid < 17) {
    float gv = aug[tid][16];
    if (tid == 16) gv -= cst[9];
    Vmu[c * 17 + tid] = gv;
    if (tid == 16) muBmu[c] = gv;
    zg[c * 17 + tid] = zs[tid];
  }
  if (tid == 0) detacc = 0.0f;
  __syncthreads();
  for (int k = 0; k < 17; k++) {
    if (tid == 0) {
      int p = k; float best = fabsf(aug[k][k]);
      for (int r = k + 1; r < 17; r++) {
        float v = fabsf(aug[r][k]);
        if (v > best) { best = v; p = r; }
      }
      pivrow = p;
    }
    __syncthreads();
    int p = pivrow;
    if (p != k) {
      for (int cc = tid; cc < 34; cc += 256) {
        float tmp = aug[k][cc]; aug[k][cc] = aug[p][cc]; aug[p][cc] = tmp;
      }
    }
    __syncthreads();
    if (tid == 0) detacc += logf(fabsf(aug[k][k]));
    if (tid < 17) colk[tid] = aug[tid][k];
    __syncthreads();
    float invp = 1.0f / aug[k][k];
    for (int cc = tid; cc < 34; cc += 256) aug[k][cc] *= invp;
    __syncthreads();
    for (int t = tid; t < 17 * 34; t += 256) {
      int r = t / 34, cc = t % 34;
      if (r != k) aug[r][cc] -= colk[r] * aug[k][cc];
    }
    __syncthreads();
  }
  for (int t = tid; t < 289; t += 256) Minv[(size_t)c * 289 + t] = aug[t / 17][17 + t % 17];
  if (tid == 0) {
    float slog = logf(fabsf(cst[5])) + detacc;
    float logdetSigma = cst[8] + cst[11] + slog;
    bias[c] = cst[4] - 0.5f * logdetSigma;
  }
}

// ============ F7: fused R-tile MFMA + Woodbury epilogue -> logits ============
// Block = (4-class group cg, 128-query tile qt). A = 68 gathered P rows (pad 80),
// B = 128 query P rows (both xor-passes). Epilogue applies Woodbury inline.
#define ASTR 72
__global__ __launch_bounds__(256) void f_rg_logits(
    const unsigned short* __restrict__ Pm, const int* __restrict__ rowmap,
    const float* __restrict__ z, const float* __restrict__ qn,
    const float* __restrict__ yn, const float* __restrict__ xmup,
    const float* __restrict__ zg, const float* __restrict__ Vmu,
    const float* __restrict__ muBmu, const float* __restrict__ mun,
    const float* __restrict__ Minv, const float* __restrict__ bias,
    const float* __restrict__ cst, float* __restrict__ out) {
  __shared__ float shf[12096];   // 48.4 KB union: staging <-> epilogue
  unsigned short* ush = (unsigned short*)shf;
  unsigned short* Ash = ush;                         // 80 x ASTR
  unsigned short* Bsh = ush + 80 * ASTR;             // 128 x ASTR
  unsigned short* Csh = ush + (80 + 128) * ASTR;     // 128 x ASTR
  int b = blockIdx.x, tid = threadIdx.x;
  int cg = b >> 4, qt = b & 15;
  int c0 = cg * 4, q0 = qt * 128;
  int lane = tid & 63, wave = tid >> 6;
  int mrow = lane & 15, qq = lane >> 4;
  f32x4 acc[5][2] = {};
  for (int it = 0; it < 16; it++) {
    int kc = it * 64, kcX = kc ^ 512;
    for (int t = tid; t < 640; t += 256) {
      int row = t >> 3, c8 = (t & 7) * 8;
      int rm = (row < 68) ? row : 0;
      int arow = rowmap[cg * 68 + rm];
      *(short8*)&Ash[row * ASTR + c8] =
          *(const short8*)(Pm + (size_t)arow * 1024 + kc + c8);
    }
    for (int t = tid; t < 1024; t += 256) {
      int row = t >> 3, c8 = (t & 7) * 8;
      *(short8*)&Bsh[row * ASTR + c8] =
          *(const short8*)(Pm + (size_t)(q0 + row) * 1024 + kc + c8);
      *(short8*)&Csh[row * ASTR + c8] =
          *(const short8*)(Pm + (size_t)(q0 + row) * 1024 + kcX + c8);
    }
    __syncthreads();
    #pragma unroll
    for (int ks = 0; ks < 2; ks++) {
      int ko = ks * 32 + qq * 8;
      short8 bfr[2], cfr[2];
      #pragma unroll
      for (int n = 0; n < 2; n++) {
        bfr[n] = *(const short8*)&Bsh[(wave * 32 + n * 16 + mrow) * ASTR + ko];
        cfr[n] = *(const short8*)&Csh[(wave * 32 + n * 16 + mrow) * ASTR + ko];
      }
      #pragma unroll
      for (int f = 0; f < 5; f++) {
        short8 af = *(const short8*)&Ash[(f * 16 + mrow) * ASTR + ko];
        #pragma unroll
        for (int n = 0; n < 2; n++) {
          acc[f][n] = __builtin_amdgcn_mfma_f32_16x16x32_bf16(af, bfr[n], acc[f][n], 0, 0, 0);
          acc[f][n] = __builtin_amdgcn_mfma_f32_16x16x32_bf16(af, cfr[n], acc[f][n], 0, 0, 0);
        }
      }
    }
    __syncthreads();
  }
  // epilogue LDS layout (reuses staging space; all waves are past the last use)
  float* RL  = shf;               // 68 x 132
  float* Mi  = shf + 68 * 132;    // 4 x 289
  float* zgs = Mi + 4 * 289;      // 68
  float* vms = zgs + 68;          // 68
  float* mbm = vms + 68;          // 4
  float* bis = mbm + 4;           // 4
  float* mns = bis + 4;           // 4
  float* zl  = mns + 4;           // 128
  float* qnl = zl + 128;          // 128
  float* ynl = qnl + 128;         // 128
  // transpose acc -> RL  (C/D: row = f*16 + qq*4 + r, col = wave*32 + n*16 + mrow)
  #pragma unroll
  for (int f = 0; f < 5; f++)
    #pragma unroll
    for (int n = 0; n < 2; n++)
      #pragma unroll
      for (int r = 0; r < 4; r++) {
        int row = f * 16 + qq * 4 + r;
        if (row < 68) RL[row * 132 + wave * 32 + n * 16 + mrow] = acc[f][n][r];
      }
  for (int t = tid; t < 68; t += 256) {
    zgs[t] = zg[cg * 68 + t];
    vms[t] = Vmu[cg * 68 + t];
  }
  for (int t = tid; t < 4 * 289; t += 256)
    Mi[t] = Minv[(size_t)c0 * 289 + t];
  if (tid < 4) {
    mbm[tid] = muBmu[c0 + tid];
    bis[tid] = bias[c0 + tid];
    mns[tid] = mun[c0 + tid];
  }
  for (int t = tid; t < 128; t += 256) {
    zl[t] = z[q0 + t];
    qnl[t] = qn[q0 + t];
    ynl[t] = yn[q0 + t];
  }
  __syncthreads();
  float csm = cst[10], scale = cst[1], common = cst[2], coef = cst[3];
  #pragma unroll
  for (int pp = 0; pp < 2; pp++) {
    int pidx = tid + pp * 256;
    int qi = pidx & 127, ci = pidx >> 7;
    int q = q0 + qi, c = c0 + ci;
    float zq = zl[qi];
    float r[17];
    float xBmu = 0.0f;
    #pragma unroll
    for (int a = 0; a < 17; a++) {
      float raw = RL[(ci * 17 + a) * 132 + qi] - csm * zgs[ci * 17 + a] * zq;
      if (a == 16) xBmu = raw;
      r[a] = raw - vms[ci * 17 + a];
    }
    float qB = ynl[qi] - csm * zq * zq;
    float quadB = qB - 2.0f * xBmu + mbm[ci];
    float corr = 0.0f;
    for (int a = 0; a < 17; a++) {
      float e = 0.0f;
      for (int b2 = 0; b2 < 17; b2++) e += Mi[ci * 289 + a * 17 + b2] * r[b2];
      corr += r[a] * e;
    }
    float distB = (quadB - corr) / scale;
    float xm = 0.0f;
    #pragma unroll
    for (int p = 0; p < XKS; p++)
      xm += xmup[((size_t)p * QNQ + q) * CNUM + c];
    float dn = qnl[qi] - 2.0f * xm + mns[ci];
    float dist = (1.0f - REGP) * distB + REGP * dn;
    out[(size_t)q * CNUM + c] = bis[ci] - coef * log1pf(dist / common);
  }
}

// ---------------- host ----------------
extern "C" void kernel_launch(void* const* d_in, const int* in_sizes, int n_in,
                              void* d_out, int out_size, void* d_ws, size_t ws_size,
                              hipStream_t stream) {
  const float* Xs    = (const float*)d_in[0];
  const int*   labels= (const int*)d_in[1];
  const float* Xq    = (const float*)d_in[2];
  const float* m     = (const float*)d_in[3];
  const float* kappa = (const float*)d_in[4];
  const float* nu    = (const float*)d_in[5];
  const float* tdiag = (const float*)d_in[6];
  const float* tlow  = (const float*)d_in[7];
  float* ws = (float*)d_ws;
  float* L    = ws + OFF_L;
  float* W    = ws + OFF_W;
  float* mu   = ws + OFF_MU;
  float* Y    = ws + OFF_Y;
  float* z    = ws + OFF_Z;
  float* wm   = ws + OFF_WM;
  float* cst  = ws + OFF_CONST;
  int*   idx  = (int*)(ws + OFF_IDX);
  int*   rmap = (int*)(ws + OFF_RMAP);
  float* zg   = ws + OFF_ZG;
  float* Vmu  = ws + OFF_VMU;
  float* muBmu= ws + OFF_MUBMU;
  float* mun  = ws + OFF_MUN;
  float* Minv = ws + OFF_MINV;
  float* bias = ws + OFF_BIAS;
  float* qn   = ws + OFF_QNRM;
  float* yn   = ws + OFF_YN;
  float* xmup = ws + OFF_XMU;
  float* Ttmp = ws + OFF_TMP;
  unsigned short* P  = (unsigned short*)(ws + OFF_P);
  unsigned short* PX = (unsigned short*)(ws + OFF_PX);
  unsigned short* PW = (unsigned short*)(ws + OFF_PW);
  float* out  = (float*)d_out;

  // F1: init (L/W/PW) + consts + classidx + mu/mun(+PX) + diag-inv(+PW) + PX(Xq/Xs)
  f_init<<<1161 + 768, 256, 0, stream>>>(tdiag, tlow, kappa, nu, labels, Xs, Xq, m,
                                         L, W, cst, idx, rmap, mu, mun, PX, PW);
  // trinv recursive doubling; level-128 T fused with xmu partials; triX emits PW
  k_triT128_xmu<<<260, 256, 0, stream>>>(L, W, Ttmp, Xq, mu, xmup);
  k_triX<<<4, 256, 0, stream>>>(W, Ttmp, 128, PW);
  k_triT<<<8, 256, 0, stream>>>(L, W, Ttmp, 256);
  k_triX<<<8, 256, 0, stream>>>(W, Ttmp, 256, PW);
  k_triT<<<16, 256, 0, stream>>>(L, W, Ttmp, 512);
  k_triX<<<16, 256, 0, stream>>>(W, Ttmp, 512, PW);
  // Y via 4-combo split MFMA (tri-skip) + wm; emits Y fp32 + P
  f_y_wm<<<520, 256, 0, stream>>>(PX, PW, W, m, Y, P, wm);
  // SM consts + per-query z/qn/yn  (z = Y.wm; no u needed)
  k_sm_z<<<513, 256, 0, stream>>>(L, wm, Xq, Y, cst, z, qn, yn);
  // Gram (zs = Y.wm) + 17x17 inverse + bias
  k_gramminv<<<64, 256, 0, stream>>>(Y, wm, rmap, cst, zg, Vmu, muBmu, Minv, bias);
  // fused R-tile MFMA + Woodbury logits (no Rg round-trip)
  f_rg_logits<<<256, 256, 0, stream>>>(P, rmap, z, qn, yn, xmup, zg, Vmu, muBmu,
                                       mun, Minv, bias, cst, out);
  (void)in_sizes; (void)n_in; (void)out_size; (void)ws_size;
}

// Round 15
// 242.866 us; speedup vs baseline: 1.0895x; 1.0895x over previous
//
#include <hip/hip_runtime.h>
#include <math.h>

// Problem dims (fixed by setup_inputs)
#define DD    512
#define CNUM  64
#define SHOTS 16
#define NSUP  1024
#define QNQ   2048
#define REGP  0.1f
#define XKS   4      // xmu split-K parts

typedef __attribute__((ext_vector_type(8))) short short8;   // 8 bf16 = 4 VGPRs
typedef __attribute__((ext_vector_type(4))) float f32x4;

// bf16 round-to-nearest-even, raw bits
__device__ __forceinline__ unsigned short f2bf(float f) {
  unsigned int u = __float_as_uint(f);
  unsigned int r = (u + 0x7fffu + ((u >> 16) & 1u)) >> 16;
  return (unsigned short)r;
}
__device__ __forceinline__ float bf2f(unsigned short h) {
  return __uint_as_float((unsigned int)h << 16);
}

// ---------------- workspace layout (in floats) ----------------
static constexpr size_t OFF_L     = 0;                       // 512*512
static constexpr size_t OFF_W     = OFF_L     + 512*512;     // 512*512
static constexpr size_t OFF_MU    = OFF_W     + 512*512;     // 64*512
static constexpr size_t OFF_Y     = OFF_MU    + 64*512;      // 3136*512
static constexpr size_t OFF_Z     = OFF_Y     + 3136*512;    // 2048
static constexpr size_t OFF_WM    = OFF_Z     + 3136;        // 512
static constexpr size_t OFF_CONST = OFF_WM    + 512;         // 16
static constexpr size_t OFF_IDX   = OFF_CONST + 16;          // 1024 ints
static constexpr size_t OFF_RMAP  = OFF_IDX   + 1024;        // 1088 ints
static constexpr size_t OFF_ZG    = OFF_RMAP  + 1088;        // 1088
static constexpr size_t OFF_VMU   = OFF_ZG    + 1088;        // 1088
static constexpr size_t OFF_MUBMU = OFF_VMU   + 1088;        // 64
static constexpr size_t OFF_MUN   = OFF_MUBMU + 64;          // 64
static constexpr size_t OFF_MINV  = OFF_MUN   + 64;          // 64*289
static constexpr size_t OFF_BIAS  = OFF_MINV  + 64*289;      // 64
static constexpr size_t OFF_QNRM  = OFF_BIAS  + 64;          // 2048
static constexpr size_t OFF_YN    = OFF_QNRM  + 2048;        // 2048
static constexpr size_t OFF_XMU   = OFF_YN    + 2048;        // XKS*2048*64
static constexpr size_t OFF_RG    = OFF_XMU   + (size_t)XKS*2048*64; // 1088*2048 (also trinv T)
static constexpr size_t OFF_P     = OFF_RG    + 1088*2048;   // 3136*1024 bf16 (Y split)
static constexpr size_t OFF_PX    = OFF_P     + 3136*512;    // 3136*1024 bf16 (X split)
static constexpr size_t OFF_PW    = OFF_PX    + 3136*512;    // 512*1024 bf16 (W split)

// consts: 0 kap, 1 scale, 2 common, 3 coef, 4 bias0, 5 jlast,
// 6 cmu_m, 7 cmu_x, 8 D*log(scale), 9 Jinv_last, 10 c_sm, 11 logdetB

// ============ F1: L/W/PW init + consts + classidx + mu/mun(+PX) + diag-inv(+PW) + PX(X) ============
__global__ __launch_bounds__(256) void f_init(const float* tdiag, const float* tlow,
    const float* kappa, const float* nu, const int* labels, const float* Xs,
    const float* Xq, const float* m, float* L, float* W, float* cst, int* idx,
    int* rowmap, float* mu, float* mun,
    unsigned short* PX, unsigned short* PW) {
  __shared__ float sh[2 * 64 * 68];   // 34.8 KB union
  __shared__ int sidx[SHOTS];
  int b = blockIdx.x, tid = threadIdx.x;
  if (b < 1024) {
    int t = b * 256 + tid;
    int i = t >> 9, j = t & 511;
    L[t] = (i == j) ? fabsf(tdiag[i]) : (i > j ? tlow[t] : 0.0f);
    if ((i >> 6) < (j >> 6)) {          // strict-upper 64-blocks: zero W and PW
      W[t] = 0.0f;
      PW[(size_t)i * 1024 + j] = 0;
      PW[(size_t)i * 1024 + 512 + j] = 0;
    }
  } else if (b == 1024) {
    if (tid == 0) {
      float kap = fabsf(kappa[0]) + 1e-6f;
      float nu_ = fmaxf(nu[0], (float)(DD - 1) + 1e-6f);
      float common = nu_ + (float)SHOTS + 1.0f - (float)DD;
      float scale = (kap + SHOTS + 1.0f) / ((nu_ + SHOTS - DD + 1.0f) * (kap + SHOTS));
      cst[0] = kap;
      cst[1] = scale;
      cst[2] = common;
      cst[3] = 0.5f * (common + DD);
      cst[4] = lgammaf(0.5f * (common + DD)) - lgammaf(0.5f * common)
               - 0.5f * (float)DD * logf(common);
      cst[5] = -(kap + SHOTS);
      cst[6] = kap / (kap + SHOTS);
      cst[7] = 1.0f / (kap + SHOTS);
      cst[8] = (float)DD * logf(scale);
      cst[9] = -1.0f / (kap + SHOTS);
    }
  } else if (b < 1089) {
    int c = b - 1025;
    if (tid < 64) {
      int lane = tid, cnt = 0;
      for (int i0 = 0; i0 < NSUP; i0 += 64) {
        int lab = labels[i0 + lane];
        unsigned long long mm = __ballot(lab == c);
        if (lab == c) {
          int pos = cnt + __popcll(mm & ((1ull << lane) - 1ull));
          if (pos < SHOTS) idx[c * SHOTS + pos] = i0 + lane;
        }
        cnt += __popcll(mm);
      }
    }
    __syncthreads();
    if (tid < 17)
      rowmap[c * 17 + tid] = (tid < SHOTS) ? (QNQ + idx[c * SHOTS + tid])
                                           : (QNQ + NSUP + c);
  } else if (b < 1153) {
    // mu/mun with locally re-derived idx; also emit PX for mu rows
    int c = b - 1089;
    if (tid < 64) {
      int lane = tid, cnt = 0;
      for (int i0 = 0; i0 < NSUP; i0 += 64) {
        int lab = labels[i0 + lane];
        unsigned long long mm = __ballot(lab == c);
        if (lab == c) {
          int pos = cnt + __popcll(mm & ((1ull << lane) - 1ull));
          if (pos < SHOTS) sidx[pos] = i0 + lane;
        }
        cnt += __popcll(mm);
      }
    }
    __syncthreads();
    float kap = fabsf(kappa[0]) + 1e-6f;
    float cm = kap / (kap + SHOTS), cx = 1.0f / (kap + SHOTS);
    float* red = sh;
    float acc = 0.0f;
    size_t prow = (size_t)(3072 + c) * 1024;
    for (int d = tid; d < DD; d += 256) {
      float s = 0.0f;
      for (int sh_ = 0; sh_ < SHOTS; sh_++)
        s += Xs[(size_t)sidx[sh_] * DD + d];
      float v = cm * m[d] + cx * s;
      mu[(size_t)c * DD + d] = v;
      unsigned short h = f2bf(v), l = f2bf(v - bf2f(h));
      PX[prow + d] = h;
      PX[prow + 512 + d] = l;
      acc += v * v;
    }
    red[tid] = acc;
    __syncthreads();
    for (int off = 128; off > 0; off >>= 1) {
      if (tid < off) red[tid] += red[tid + off];
      __syncthreads();
    }
    if (tid == 0) mun[c] = red[0];
  } else if (b < 1161) {
    // diag 64x64 inverse + PW emit
    int jb = b - 1153;
    float* Ld = sh;             // [64][68]
    float* Wd = sh + 64 * 68;   // [64][68]
    for (int t = tid; t < 4096; t += 256) {
      int r = t >> 6, c = t & 63;
      int gr = jb * 64 + r;
      float v = (r == c) ? fabsf(tdiag[gr])
              : (r > c ? tlow[(size_t)gr * DD + jb * 64 + c] : 0.0f);
      Ld[r * 68 + c] = v;
    }
    __syncthreads();
    if (tid < 64) {
      for (int i = 0; i < 64; i++) {
        float w = (i == tid) ? 1.0f : 0.0f;
        for (int k = 0; k < i; k++) w -= Ld[i * 68 + k] * Wd[k * 68 + tid];
        Wd[i * 68 + tid] = w / Ld[i * 68 + i];
      }
    }
    __syncthreads();
    float* Wblk = W + (size_t)(jb * 64) * DD + jb * 64;
    for (int t = tid; t < 4096; t += 256) {
      int r = t >> 6, c = t & 63;
      float v = Wd[r * 68 + c];
      Wblk[(size_t)r * DD + c] = v;
      unsigned short h = f2bf(v), l = f2bf(v - bf2f(h));
      size_t prow = (size_t)(jb * 64 + r) * 1024 + jb * 64 + c;
      PW[prow] = h;
      PW[prow + 512] = l;
    }
  } else {
    // PX for Xq/Xs rows: 4 rows per block
    int r0 = (b - 1161) * 4;
    int row = r0 + (tid >> 6), lane = tid & 63;
    const float* src = (row < QNQ) ? Xq + (size_t)row * DD
                                   : Xs + (size_t)(row - QNQ) * DD;
    size_t prow = (size_t)row * 1024;
    #pragma unroll
    for (int p = 0; p < 2; p++) {
      int col = lane * 8 + p * 4;
      float4 v = *(const float4*)(src + col);
      ushort4 hi, lo;
      hi.x = f2bf(v.x); lo.x = f2bf(v.x - bf2f(hi.x));
      hi.y = f2bf(v.y); lo.y = f2bf(v.y - bf2f(hi.y));
      hi.z = f2bf(v.z); lo.z = f2bf(v.z - bf2f(hi.z));
      hi.w = f2bf(v.w); lo.w = f2bf(v.w - bf2f(hi.w));
      *(ushort4*)(PX + prow + col) = hi;
      *(ushort4*)(PX + prow + 512 + col) = lo;
    }
  }
}

// 64x64 NN GEMM tile on caller LDS (stride 68): Cd = sgn * A[:,k0:k1] * B[k0:k1,:]
// If Pw != nullptr, also emit bf16 hi/lo split at PW[gr0+.., gc0+..].
__device__ __forceinline__ void nn64_sh(float* As, float* Bs,
    const float* __restrict__ A, int lda, const float* __restrict__ B, int ldb,
    float* __restrict__ Cd, int ldc, int k0, int k1, float sgn,
    unsigned short* __restrict__ Pw, int gr0, int gc0) {
  int tid = threadIdx.x, tr = tid >> 4, tc = tid & 15;
  float acc[4][4] = {};
  for (int kc = k0; kc < k1; kc += 64) {
    #pragma unroll
    for (int p = 0; p < 4; p++) {
      int f4 = tid + 256 * p;
      int row = f4 >> 4, c4 = f4 & 15;
      *(float4*)&As[row * 68 + c4 * 4] = *(const float4*)(A + (size_t)row * lda + kc + c4 * 4);
      *(float4*)&Bs[row * 68 + c4 * 4] = *(const float4*)(B + (size_t)(kc + row) * ldb + c4 * 4);
    }
    __syncthreads();
    #pragma unroll
    for (int kk = 0; kk < 64; kk++) {
      float a[4];
      #pragma unroll
      for (int x = 0; x < 4; x++) a[x] = As[(tr * 4 + x) * 68 + kk];
      float4 bv = *(const float4*)&Bs[kk * 68 + tc * 4];
      float bb[4] = {bv.x, bv.y, bv.z, bv.w};
      #pragma unroll
      for (int x = 0; x < 4; x++)
        #pragma unroll
        for (int y = 0; y < 4; y++) acc[x][y] += a[x] * bb[y];
    }
    __syncthreads();
  }
  #pragma unroll
  for (int x = 0; x < 4; x++) {
    float4 v = make_float4(sgn * acc[x][0], sgn * acc[x][1],
                           sgn * acc[x][2], sgn * acc[x][3]);
    *(float4*)(Cd + (size_t)(tr * 4 + x) * ldc + tc * 4) = v;
    if (Pw) {
      size_t prow = (size_t)(gr0 + tr * 4 + x) * 1024 + gc0 + tc * 4;
      float vv[4] = {v.x, v.y, v.z, v.w};
      #pragma unroll
      for (int y = 0; y < 4; y++) {
        unsigned short h = f2bf(vv[y]), l = f2bf(vv[y] - bf2f(h));
        Pw[prow + y] = h;
        Pw[prow + 512 + y] = l;
      }
    }
  }
}

#define GBK 16
// ============ triT level 128 fused with xmu partials ============
__global__ __launch_bounds__(256) void k_triT128_xmu(const float* __restrict__ L,
    const float* __restrict__ W, float* __restrict__ T,
    const float* __restrict__ Xq, const float* __restrict__ Mu,
    float* __restrict__ xmup) {
  __shared__ float sh[2 * 64 * 68];
  int b = blockIdx.x, tid = threadIdx.x;
  if (b < 4) {              // triT, s=128: h=64, tiles=1
    int g = b, base = g * 128;
    const float* A = L + (size_t)(base + 64) * DD + base;
    const float* B = W + (size_t)base * DD + base;
    float* Cd = T + (size_t)g * 64 * 64;
    nn64_sh(sh, sh + 64 * 68, A, DD, B, DD, Cd, 64, 0, 64, 1.0f, nullptr, 0, 0);
  } else {                  // xmu partials: 32 q-rows, split-K=4
    float* As = sh;               // stride 36, 16 rows
    float* Bs = sh + 16 * 36;     // stride 68, 16 rows
    int xb = b - 4;
    int bm = (xb & 63) * 32, kq = xb >> 6;
    int tr = tid >> 4, tc = tid & 15;
    float acc[2][4] = {};
    int k0s = kq * (DD / XKS), k0e = k0s + DD / XKS;
    for (int k0 = k0s; k0 < k0e; k0 += GBK) {
      if (tid < 128) {
        int row = tid >> 2, k4 = tid & 3;
        float4 v = *(const float4*)(Xq + (size_t)(bm + row) * DD + k0 + k4 * 4);
        As[(k4 * 4 + 0) * 36 + row] = v.x; As[(k4 * 4 + 1) * 36 + row] = v.y;
        As[(k4 * 4 + 2) * 36 + row] = v.z; As[(k4 * 4 + 3) * 36 + row] = v.w;
      }
      {
        int row = tid >> 2, k4 = tid & 3;
        float4 v = *(const float4*)(Mu + (size_t)row * DD + k0 + k4 * 4);
        Bs[(k4 * 4 + 0) * 68 + row] = v.x; Bs[(k4 * 4 + 1) * 68 + row] = v.y;
        Bs[(k4 * 4 + 2) * 68 + row] = v.z; Bs[(k4 * 4 + 3) * 68 + row] = v.w;
      }
      __syncthreads();
      #pragma unroll
      for (int kk = 0; kk < GBK; kk++) {
        float a[2] = {As[kk * 36 + tr * 2], As[kk * 36 + tr * 2 + 1]};
        float4 b0 = *(const float4*)&Bs[kk * 68 + tc * 4];
        float bb[4] = {b0.x, b0.y, b0.z, b0.w};
        #pragma unroll
        for (int x = 0; x < 2; x++)
          #pragma unroll
          for (int y = 0; y < 4; y++) acc[x][y] += a[x] * bb[y];
      }
      __syncthreads();
    }
    #pragma unroll
    for (int x = 0; x < 2; x++) {
      int q = bm + tr * 2 + x;
      float4 v = make_float4(acc[x][0], acc[x][1], acc[x][2], acc[x][3]);
      *(float4*)(xmup + ((size_t)kq * QNQ + q) * CNUM + tc * 4) = v;
    }
  }
}

// generic trinv doubling levels
__global__ __launch_bounds__(256) void k_triT(const float* __restrict__ L,
                                              const float* __restrict__ W,
                                              float* __restrict__ T, int s) {
  __shared__ float sh[2 * 64 * 68];
  int h = s >> 1, tiles = h >> 6, per = tiles * tiles;
  int g = blockIdx.x / per, rem = blockIdx.x % per;
  int ti = rem / tiles, tj = rem % tiles;
  int base = g * s;
  const float* A = L + (size_t)(base + h + ti * 64) * DD + base;
  const float* B = W + (size_t)base * DD + base + tj * 64;
  float* Cd = T + (size_t)g * h * h + (size_t)(ti * 64) * h + tj * 64;
  nn64_sh(sh, sh + 64 * 68, A, DD, B, DD, Cd, h, tj * 64, h, 1.0f, nullptr, 0, 0);
}

// triX also emits PW (the bf16 hi/lo of the W blocks it writes)
__global__ __launch_bounds__(256) void k_triX(float* __restrict__ W,
                                              const float* __restrict__ T, int s,
                                              unsigned short* __restrict__ PW) {
  __shared__ float sh[2 * 64 * 68];
  int h = s >> 1, tiles = h >> 6, per = tiles * tiles;
  int g = blockIdx.x / per, rem = blockIdx.x % per;
  int ti = rem / tiles, tj = rem % tiles;
  int base = g * s;
  const float* A = W + (size_t)(base + h + ti * 64) * DD + base + h;
  const float* B = T + (size_t)g * h * h + tj * 64;
  int gr0 = base + h + ti * 64, gc0 = base + tj * 64;
  float* Cd = W + (size_t)gr0 * DD + gc0;
  nn64_sh(sh, sh + 64 * 68, A, DD, B, h, Cd, DD, 0, (ti + 1) * 64, -1.0f, PW, gr0, gc0);
}

#define PSTR 80   // LDS row stride in bf16
// ============ F3: Y-GEMM via 4-combo bf16-split MFMA (tri-skip) + wm ============
__global__ __launch_bounds__(256) void f_y_wm(const unsigned short* __restrict__ PX,
    const unsigned short* __restrict__ PW, const float* __restrict__ W,
    const float* __restrict__ m, float* __restrict__ Y,
    unsigned short* __restrict__ Pm, float* __restrict__ wm) {
  __shared__ unsigned short AshH[64 * PSTR];
  __shared__ unsigned short AshL[64 * PSTR];
  __shared__ unsigned short BshH[64 * PSTR];
  __shared__ unsigned short BshL[64 * PSTR];
  int b = blockIdx.x, tid = threadIdx.x;
  if (b < 392) {            // 49 m-tiles x 8 n-tiles, 64x64
    int mt = b >> 3, nt = b & 7;
    int bm = mt * 64, bn = nt * 64;
    int lane = tid & 63, wave = tid >> 6;
    int wr = wave >> 1, wc = wave & 1;
    int mrow = lane & 15, q = lane >> 4;
    f32x4 acc00 = {}, acc01 = {}, acc10 = {}, acc11 = {};
    int kchunks = nt + 1;   // W lower-triangular: k < bn+64
    for (int it = 0; it < kchunks; it++) {
      int kc = it * 64;
      #pragma unroll
      for (int p = 0; p < 2; p++) {
        int idx = tid + 256 * p;
        int row = idx >> 3, c8 = (idx & 7) * 8;
        *(short8*)&AshH[row * PSTR + c8] =
            *(const short8*)(PX + (size_t)(bm + row) * 1024 + kc + c8);
        *(short8*)&AshL[row * PSTR + c8] =
            *(const short8*)(PX + (size_t)(bm + row) * 1024 + 512 + kc + c8);
        *(short8*)&BshH[row * PSTR + c8] =
            *(const short8*)(PW + (size_t)(bn + row) * 1024 + kc + c8);
        *(short8*)&BshL[row * PSTR + c8] =
            *(const short8*)(PW + (size_t)(bn + row) * 1024 + 512 + kc + c8);
      }
      __syncthreads();
      #pragma unroll
      for (int ks = 0; ks < 2; ks++) {
        int ko = ks * 32 + q * 8;
        short8 ah0 = *(const short8*)&AshH[(wr * 32 + mrow) * PSTR + ko];
        short8 ah1 = *(const short8*)&AshH[(wr * 32 + 16 + mrow) * PSTR + ko];
        short8 al0 = *(const short8*)&AshL[(wr * 32 + mrow) * PSTR + ko];
        short8 al1 = *(const short8*)&AshL[(wr * 32 + 16 + mrow) * PSTR + ko];
        short8 bh0 = *(const short8*)&BshH[(wc * 32 + mrow) * PSTR + ko];
        short8 bh1 = *(const short8*)&BshH[(wc * 32 + 16 + mrow) * PSTR + ko];
        short8 bl0 = *(const short8*)&BshL[(wc * 32 + mrow) * PSTR + ko];
        short8 bl1 = *(const short8*)&BshL[(wc * 32 + 16 + mrow) * PSTR + ko];
        acc00 = __builtin_amdgcn_mfma_f32_16x16x32_bf16(ah0, bh0, acc00, 0, 0, 0);
        acc00 = __builtin_amdgcn_mfma_f32_16x16x32_bf16(ah0, bl0, acc00, 0, 0, 0);
        acc00 = __builtin_amdgcn_mfma_f32_16x16x32_bf16(al0, bh0, acc00, 0, 0, 0);
        acc00 = __builtin_amdgcn_mfma_f32_16x16x32_bf16(al0, bl0, acc00, 0, 0, 0);
        acc01 = __builtin_amdgcn_mfma_f32_16x16x32_bf16(ah0, bh1, acc01, 0, 0, 0);
        acc01 = __builtin_amdgcn_mfma_f32_16x16x32_bf16(ah0, bl1, acc01, 0, 0, 0);
        acc01 = __builtin_amdgcn_mfma_f32_16x16x32_bf16(al0, bh1, acc01, 0, 0, 0);
        acc01 = __builtin_amdgcn_mfma_f32_16x16x32_bf16(al0, bl1, acc01, 0, 0, 0);
        acc10 = __builtin_amdgcn_mfma_f32_16x16x32_bf16(ah1, bh0, acc10, 0, 0, 0);
        acc10 = __builtin_amdgcn_mfma_f32_16x16x32_bf16(ah1, bl0, acc10, 0, 0, 0);
        acc10 = __builtin_amdgcn_mfma_f32_16x16x32_bf16(al1, bh0, acc10, 0, 0, 0);
        acc10 = __builtin_amdgcn_mfma_f32_16x16x32_bf16(al1, bl0, acc10, 0, 0, 0);
        acc11 = __builtin_amdgcn_mfma_f32_16x16x32_bf16(ah1, bh1, acc11, 0, 0, 0);
        acc11 = __builtin_amdgcn_mfma_f32_16x16x32_bf16(ah1, bl1, acc11, 0, 0, 0);
        acc11 = __builtin_amdgcn_mfma_f32_16x16x32_bf16(al1, bh1, acc11, 0, 0, 0);
        acc11 = __builtin_amdgcn_mfma_f32_16x16x32_bf16(al1, bl1, acc11, 0, 0, 0);
      }
      __syncthreads();
    }
    #pragma unroll
    for (int r = 0; r < 4; r++) {
      int row0 = bm + wr * 32 + q * 4 + r;
      int row1 = row0 + 16;
      int col0 = bn + wc * 32 + mrow;
      float vv[4] = {acc00[r], acc01[r], acc10[r], acc11[r]};
      int rows[4] = {row0, row0, row1, row1};
      int cols[4] = {col0, col0 + 16, col0, col0 + 16};
      #pragma unroll
      for (int e = 0; e < 4; e++) {
        Y[(size_t)rows[e] * DD + cols[e]] = vv[e];
        unsigned short h = f2bf(vv[e]), l = f2bf(vv[e] - bf2f(h));
        Pm[(size_t)rows[e] * 1024 + cols[e]] = h;
        Pm[(size_t)rows[e] * 1024 + 512 + cols[e]] = l;
      }
    }
  } else {                  // wm[row] = W[row,:] . m  (4 rows/block)
    int wave = tid >> 6, lane = tid & 63;
    int row = (b - 392) * 4 + wave;
    float s = 0.0f;
    for (int j = lane; j < DD; j += 64) s += W[(size_t)row * DD + j] * m[j];
    for (int off = 32; off > 0; off >>= 1) s += __shfl_down(s, off);
    if (lane == 0) wm[row] = s;
  }
}

// ============ F5: Rg MFMA (both xor-passes, single buffer) + query z/qn/yn + SM consts ============
__global__ __launch_bounds__(256) void f_z_rg(const unsigned short* __restrict__ Pm,
    const float* __restrict__ Y, const float* __restrict__ L,
    const int* __restrict__ rowmap, const float* __restrict__ Xq,
    const float* __restrict__ wm, float* __restrict__ cst,
    float* __restrict__ Rg,
    float* __restrict__ z, float* __restrict__ qn, float* __restrict__ yn) {
  __shared__ unsigned short Ash[64 * PSTR];   // 10.2 KB
  __shared__ unsigned short Bsh[64 * PSTR];
  __shared__ unsigned short Csh[64 * PSTR];
  int b = blockIdx.x, tid = threadIdx.x;
  if (b < 544) {            // 17 m-tiles x 32 n-tiles, 64x64 out
    int bm = (b >> 5) * 64, bn = (b & 31) * 64;
    int lane = tid & 63, wave = tid >> 6;
    int wr = wave >> 1, wc = wave & 1;
    int mrow = lane & 15, q = lane >> 4;
    int srowA[2];
    #pragma unroll
    for (int p = 0; p < 2; p++) srowA[p] = rowmap[bm + ((tid + 256 * p) >> 3)];
    f32x4 acc00 = {}, acc01 = {}, acc10 = {}, acc11 = {};
    for (int it = 0; it < 16; it++) {
      int kc = it * 64;
      int kcX = kc ^ 512;
      #pragma unroll
      for (int p = 0; p < 2; p++) {
        int idx = tid + 256 * p;
        int row = idx >> 3, c8 = (idx & 7) * 8;
        *(short8*)&Ash[row * PSTR + c8] =
            *(const short8*)(Pm + (size_t)srowA[p] * 1024 + kc + c8);
        *(short8*)&Bsh[row * PSTR + c8] =
            *(const short8*)(Pm + (size_t)(bn + row) * 1024 + kc + c8);
        *(short8*)&Csh[row * PSTR + c8] =
            *(const short8*)(Pm + (size_t)(bn + row) * 1024 + kcX + c8);
      }
      __syncthreads();
      #pragma unroll
      for (int ks = 0; ks < 2; ks++) {
        int ko = ks * 32 + q * 8;
        short8 a0 = *(const short8*)&Ash[(wr * 32 + mrow) * PSTR + ko];
        short8 a1 = *(const short8*)&Ash[(wr * 32 + 16 + mrow) * PSTR + ko];
        short8 b0 = *(const short8*)&Bsh[(wc * 32 + mrow) * PSTR + ko];
        short8 b1 = *(const short8*)&Bsh[(wc * 32 + 16 + mrow) * PSTR + ko];
        short8 c0 = *(const short8*)&Csh[(wc * 32 + mrow) * PSTR + ko];
        short8 c1 = *(const short8*)&Csh[(wc * 32 + 16 + mrow) * PSTR + ko];
        acc00 = __builtin_amdgcn_mfma_f32_16x16x32_bf16(a0, b0, acc00, 0, 0, 0);
        acc01 = __builtin_amdgcn_mfma_f32_16x16x32_bf16(a0, b1, acc01, 0, 0, 0);
        acc10 = __builtin_amdgcn_mfma_f32_16x16x32_bf16(a1, b0, acc10, 0, 0, 0);
        acc11 = __builtin_amdgcn_mfma_f32_16x16x32_bf16(a1, b1, acc11, 0, 0, 0);
        acc00 = __builtin_amdgcn_mfma_f32_16x16x32_bf16(a0, c0, acc00, 0, 0, 0);
        acc01 = __builtin_amdgcn_mfma_f32_16x16x32_bf16(a0, c1, acc01, 0, 0, 0);
        acc10 = __builtin_amdgcn_mfma_f32_16x16x32_bf16(a1, c0, acc10, 0, 0, 0);
        acc11 = __builtin_amdgcn_mfma_f32_16x16x32_bf16(a1, c1, acc11, 0, 0, 0);
      }
      __syncthreads();
    }
    #pragma unroll
    for (int r = 0; r < 4; r++) {
      int row0 = bm + wr * 32 + q * 4 + r;
      int row1 = row0 + 16;
      int col0 = bn + wc * 32 + mrow;
      Rg[(size_t)row0 * QNQ + col0]      = acc00[r];
      Rg[(size_t)row0 * QNQ + col0 + 16] = acc01[r];
      Rg[(size_t)row1 * QNQ + col0]      = acc10[r];
      Rg[(size_t)row1 * QNQ + col0 + 16] = acc11[r];
    }
  } else if (b < 1056) {    // query rows: z = Y.wm, qn = |x|^2, yn = |Y|^2
    int wave = tid >> 6, lane = tid & 63;
    int row = (b - 544) * 4 + wave;
    const float* xr = Xq + (size_t)row * DD;
    const float* yr = Y + (size_t)row * DD;
    float sz = 0.0f, s1 = 0.0f, s2 = 0.0f;
    for (int j4 = lane; j4 < 128; j4 += 64) {
      float4 xv = *(const float4*)(xr + j4 * 4);
      float4 yv = *(const float4*)(yr + j4 * 4);
      float4 wv = *(const float4*)(wm + j4 * 4);
      sz += yv.x * wv.x + yv.y * wv.y + yv.z * wv.z + yv.w * wv.w;
      s1 += xv.x * xv.x + xv.y * xv.y + xv.z * xv.z + xv.w * xv.w;
      s2 += yv.x * yv.x + yv.y * yv.y + yv.z * yv.z + yv.w * yv.w;
    }
    for (int off = 32; off > 0; off >>= 1) {
      sz += __shfl_down(sz, off);
      s1 += __shfl_down(s1, off);
      s2 += __shfl_down(s2, off);
    }
    if (lane == 0) {
      z[row] = sz;
      qn[row] = s1;
      yn[row] = s2;
    }
  } else {                  // SM consts (needs only wm, L)
    __shared__ float red[256], red2[256];
    float a = 0.0f, l = 0.0f;
    for (int t = tid; t < DD; t += 256) {
      float w = wm[t]; a += w * w;
      l += logf(fabsf(L[(size_t)t * DD + t]));
    }
    red[tid] = a; red2[tid] = l;
    __syncthreads();
    for (int off = 128; off > 0; off >>= 1) {
      if (tid < off) { red[tid] += red[tid + off]; red2[tid] += red2[tid + off]; }
      __syncthreads();
    }
    if (tid == 0) {
      float kap = cst[0], ss = red[0];
      cst[10] = kap / (1.0f + kap * ss);
      cst[11] = 2.0f * red2[0] + logf(1.0f + kap * ss);
    }
  }
}

// ============ F6: per-class Gram (zs = Y.wm) + GJ inverse + bias ============
#define YSTRIDE 516
__global__ __launch_bounds__(256) void k_gramminv(const float* Y, const float* wm,
    const int* rowmap, const float* cst, float* zg, float* Vmu, float* muBmu,
    float* Minv, float* bias) {
  __shared__ float Ys[17 * YSTRIDE];
  __shared__ float zs[17];
  __shared__ float aug[17][35];
  __shared__ float colk[17];
  __shared__ int pivrow;
  __shared__ float detacc;
  int c = blockIdx.x, tid = threadIdx.x;
  for (int t = tid; t < 17 * 128; t += 256) {
    int r = t >> 7, col = t & 127;
    *(float4*)&Ys[r * YSTRIDE + col * 4] =
        *(const float4*)(Y + (size_t)rowmap[c * 17 + r] * DD + col * 4);
  }
  __syncthreads();
  {
    int wave = tid >> 6, lane = tid & 63;
    for (int a = wave; a < 17; a += 4) {
      float s = 0.0f;
      for (int j = lane; j < DD; j += 64) s += Ys[a * YSTRIDE + j] * wm[j];
      for (int off = 32; off > 0; off >>= 1) s += __shfl_down(s, off);
      if (lane == 0) zs[a] = s;
    }
  }
  __syncthreads();
  float csm = cst[10];
  for (int e = tid; e < 289; e += 256) {
    int a = e / 17, bb = e % 17;
    const float* ra = &Ys[a * YSTRIDE];
    const float* rb = &Ys[bb * YSTRIDE];
    float s = 0.0f;
    for (int k = 0; k < 128; k++) {
      float4 va = *(const float4*)&ra[k * 4];
      float4 vb = *(const float4*)&rb[k * 4];
      s += va.x * vb.x + va.y * vb.y + va.z * vb.z + va.w * vb.w;
    }
    float g = s - csm * zs[a] * zs[bb];
    if (a == bb) g += (a < 16) ? 1.0f : cst[9];
    aug[a][bb] = g;
    aug[a][17 + bb] = (a == bb) ? 1.0f : 0.0f;
  }
  __syncthreads();
  if (tid < 17) {
    float gv = aug[tid][16];
    if (tid == 16) gv -= cst[9];
    Vmu[c * 17 + tid] = gv;
    if (tid == 16) muBmu[c] = gv;
    zg[c * 17 + tid] = zs[tid];
  }
  if (tid == 0) detacc = 0.0f;
  __syncthreads();
  for (int k = 0; k < 17; k++) {
    if (tid == 0) {
      int p = k; float best = fabsf(aug[k][k]);
      for (int r = k + 1; r < 17; r++) {
        float v = fabsf(aug[r][k]);
        if (v > best) { best = v; p = r; }
      }
      pivrow = p;
    }
    __syncthreads();
    int p = pivrow;
    if (p != k) {
      for (int cc = tid; cc < 34; cc += 256) {
        float tmp = aug[k][cc]; aug[k][cc] = aug[p][cc]; aug[p][cc] = tmp;
      }
    }
    __syncthreads();
    if (tid == 0) detacc += logf(fabsf(aug[k][k]));
    if (tid < 17) colk[tid] = aug[tid][k];
    __syncthreads();
    float invp = 1.0f / aug[k][k];
    for (int cc = tid; cc < 34; cc += 256) aug[k][cc] *= invp;
    __syncthreads();
    for (int t = tid; t < 17 * 34; t += 256) {
      int r = t / 34, cc = t % 34;
      if (r != k) aug[r][cc] -= colk[r] * aug[k][cc];
    }
    __syncthreads();
  }
  for (int t = tid; t < 289; t += 256) Minv[(size_t)c * 289 + t] = aug[t / 17][17 + t % 17];
  if (tid == 0) {
    float slog = logf(fabsf(cst[5])) + detacc;
    float logdetSigma = cst[8] + cst[11] + slog;
    bias[c] = cst[4] - 0.5f * logdetSigma;
  }
}

// final epilogue: Woodbury-corrected Mahalanobis -> logits[q,c]
__global__ __launch_bounds__(256) void k_logits(const float* __restrict__ Rg,
    const float* z, const float* zg,
    const float* Vmu, const float* muBmu, const float* mun, const float* yn,
    const float* qn, const float* xmup, const float* Minv, const float* bias,
    const float* cst, float* out) {
  __shared__ float Ms[289], Vs[17], Zs[17];
  int c = blockIdx.y;
  int q = blockIdx.x * 256 + threadIdx.x;
  for (int t = threadIdx.x; t < 289; t += 256) Ms[t] = Minv[(size_t)c * 289 + t];
  if (threadIdx.x < 17) {
    Vs[threadIdx.x] = Vmu[c * 17 + threadIdx.x];
    Zs[threadIdx.x] = zg[c * 17 + threadIdx.x];
  }
  __syncthreads();
  float csm = cst[10], scale = cst[1], common = cst[2], coef = cst[3];
  float zq = z[q];
  float r[17];
  float xBmu = 0.0f;
  for (int a = 0; a < 17; a++) {
    float raw = Rg[(size_t)(c * 17 + a) * QNQ + q] - csm * Zs[a] * zq;
    if (a == 16) xBmu = raw;
    r[a] = raw - Vs[a];
  }
  float qB = yn[q] - csm * zq * zq;
  float quadB = qB - 2.0f * xBmu + muBmu[c];
  float corr = 0.0f;
  for (int a = 0; a < 17; a++) {
    float e = 0.0f;
    for (int bb = 0; bb < 17; bb++) e += Ms[a * 17 + bb] * r[bb];
    corr += r[a] * e;
  }
  float distB = (quadB - corr) / scale;
  float xm = 0.0f;
  #pragma unroll
  for (int p = 0; p < XKS; p++)
    xm += xmup[((size_t)p * QNQ + q) * CNUM + c];
  float dn = qn[q] - 2.0f * xm + mun[c];
  float dist = (1.0f - REGP) * distB + REGP * dn;
  out[(size_t)q * CNUM + c] = bias[c] - coef * log1pf(dist / common);
}

// ---------------- host ----------------
extern "C" void kernel_launch(void* const* d_in, const int* in_sizes, int n_in,
                              void* d_out, int out_size, void* d_ws, size_t ws_size,
                              hipStream_t stream) {
  const float* Xs    = (const float*)d_in[0];
  const int*   labels= (const int*)d_in[1];
  const float* Xq    = (const float*)d_in[2];
  const float* m     = (const float*)d_in[3];
  const float* kappa = (const float*)d_in[4];
  const float* nu    = (const float*)d_in[5];
  const float* tdiag = (const float*)d_in[6];
  const float* tlow  = (const float*)d_in[7];
  float* ws = (float*)d_ws;
  float* L    = ws + OFF_L;
  float* W    = ws + OFF_W;
  float* mu   = ws + OFF_MU;
  float* Y    = ws + OFF_Y;
  float* z    = ws + OFF_Z;
  float* wm   = ws + OFF_WM;
  float* cst  = ws + OFF_CONST;
  int*   idx  = (int*)(ws + OFF_IDX);
  int*   rmap = (int*)(ws + OFF_RMAP);
  float* zg   = ws + OFF_ZG;
  float* Vmu  = ws + OFF_VMU;
  float* muBmu= ws + OFF_MUBMU;
  float* mun  = ws + OFF_MUN;
  float* Minv = ws + OFF_MINV;
  float* bias = ws + OFF_BIAS;
  float* qn   = ws + OFF_QNRM;
  float* yn   = ws + OFF_YN;
  float* xmup = ws + OFF_XMU;
  float* Rg   = ws + OFF_RG;
  unsigned short* P  = (unsigned short*)(ws + OFF_P);
  unsigned short* PX = (unsigned short*)(ws + OFF_PX);
  unsigned short* PW = (unsigned short*)(ws + OFF_PW);
  float* Ttmp = ws + OFF_RG;       // trinv scratch, reused (Rg written later)
  float* out  = (float*)d_out;

  // F1: init (L/W/PW) + consts + classidx + mu/mun(+PX) + diag-inv(+PW) + PX(Xq/Xs)
  f_init<<<1161 + 768, 256, 0, stream>>>(tdiag, tlow, kappa, nu, labels, Xs, Xq, m,
                                         L, W, cst, idx, rmap, mu, mun, PX, PW);
  // trinv recursive doubling; level-128 T fused with xmu partials; triX emits PW
  k_triT128_xmu<<<260, 256, 0, stream>>>(L, W, Ttmp, Xq, mu, xmup);
  k_triX<<<4, 256, 0, stream>>>(W, Ttmp, 128, PW);
  k_triT<<<8, 256, 0, stream>>>(L, W, Ttmp, 256);
  k_triX<<<8, 256, 0, stream>>>(W, Ttmp, 256, PW);
  k_triT<<<16, 256, 0, stream>>>(L, W, Ttmp, 512);
  k_triX<<<16, 256, 0, stream>>>(W, Ttmp, 512, PW);
  // Y via 4-combo split MFMA (tri-skip) + wm; emits Y fp32 + P
  f_y_wm<<<520, 256, 0, stream>>>(PX, PW, W, m, Y, P, wm);
  // Rg MFMA (single buffer, both passes) + query z/qn/yn + SM consts
  f_z_rg<<<544 + 512 + 1, 256, 0, stream>>>(P, Y, L, rmap, Xq, wm, cst, Rg, z, qn, yn);
  // Gram (zs = Y.wm) + 17x17 inverse + bias
  k_gramminv<<<64, 256, 0, stream>>>(Y, wm, rmap, cst, zg, Vmu, muBmu, Minv, bias);
  k_logits<<<dim3(QNQ / 256, CNUM), 256, 0, stream>>>(Rg, z, zg, Vmu, muBmu,
                                                      mun, yn, qn, xmup, Minv, bias,
                                                      cst, out);
  (void)in_sizes; (void)n_in; (void)out_size; (void)ws_size;
}

// Round 16
// 239.232 us; speedup vs baseline: 1.1060x; 1.0152x over previous
//
#include <hip/hip_runtime.h>
#include <math.h>

// Problem dims (fixed by setup_inputs)
#define DD    512
#define CNUM  64
#define SHOTS 16
#define NSUP  1024
#define QNQ   2048
#define REGP  0.1f
#define XKS   4      // xmu split-K parts

typedef __attribute__((ext_vector_type(8))) short short8;   // 8 bf16 = 4 VGPRs
typedef __attribute__((ext_vector_type(4))) float f32x4;

// bf16 round-to-nearest-even, raw bits
__device__ __forceinline__ unsigned short f2bf(float f) {
  unsigned int u = __float_as_uint(f);
  unsigned int r = (u + 0x7fffu + ((u >> 16) & 1u)) >> 16;
  return (unsigned short)r;
}
__device__ __forceinline__ float bf2f(unsigned short h) {
  return __uint_as_float((unsigned int)h << 16);
}

// ---------------- workspace layout (in floats) ----------------
// L is never materialized: all consumers read tdiag/tlow directly
// (every L-region they touch is strictly lower-triangular or diagonal).
static constexpr size_t OFF_W     = 0;                       // 512*512
static constexpr size_t OFF_MU    = OFF_W     + 512*512;     // 64*512
static constexpr size_t OFF_Y     = OFF_MU    + 64*512;      // 3136*512
static constexpr size_t OFF_Z     = OFF_Y     + 3136*512;    // 2048
static constexpr size_t OFF_WM    = OFF_Z     + 3136;        // 512
static constexpr size_t OFF_CONST = OFF_WM    + 512;         // 16
static constexpr size_t OFF_IDX   = OFF_CONST + 16;          // 1024 ints
static constexpr size_t OFF_RMAP  = OFF_IDX   + 1024;        // 1088 ints
static constexpr size_t OFF_ZG    = OFF_RMAP  + 1088;        // 1088
static constexpr size_t OFF_VMU   = OFF_ZG    + 1088;        // 1088
static constexpr size_t OFF_MUBMU = OFF_VMU   + 1088;        // 64
static constexpr size_t OFF_MUN   = OFF_MUBMU + 64;          // 64
static constexpr size_t OFF_MINV  = OFF_MUN   + 64;          // 64*289
static constexpr size_t OFF_BIAS  = OFF_MINV  + 64*289;      // 64
static constexpr size_t OFF_QNRM  = OFF_BIAS  + 64;          // 2048
static constexpr size_t OFF_YN    = OFF_QNRM  + 2048;        // 2048
static constexpr size_t OFF_XMU   = OFF_YN    + 2048;        // XKS*2048*64
static constexpr size_t OFF_RG    = OFF_XMU   + (size_t)XKS*2048*64; // 1088*2048 (also trinv T)
static constexpr size_t OFF_P     = OFF_RG    + 1088*2048;   // 3136*1024 bf16 (Y split)
static constexpr size_t OFF_PX    = OFF_P     + 3136*512;    // 3136*1024 bf16 (X split)
static constexpr size_t OFF_PW    = OFF_PX    + 3136*512;    // 512*1024 bf16 (W split)

// consts: 0 kap, 1 scale, 2 common, 3 coef, 4 bias0, 5 jlast,
// 6 cmu_m, 7 cmu_x, 8 D*log(scale), 9 Jinv_last, 10 c_sm, 11 logdetB

// ============ F1: consts + classidx + mu/mun(+PX) + diag-inv(+PW) + PX(X) ============
// No L materialization, no strict-upper W/PW zeroing (never read: wm is
// triangular-bounded; f_y_wm k-chunks bounded; triT/triX K-bounded).
__global__ __launch_bounds__(256) void f_init(const float* tdiag, const float* tlow,
    const float* kappa, const float* nu, const int* labels, const float* Xs,
    const float* Xq, const float* m, float* W, float* cst, int* idx,
    int* rowmap, float* mu, float* mun,
    unsigned short* PX, unsigned short* PW) {
  __shared__ float sh[2 * 64 * 68];   // 34.8 KB union
  __shared__ int sidx[SHOTS];
  int b = blockIdx.x, tid = threadIdx.x;
  if (b == 0) {
    if (tid == 0) {
      float kap = fabsf(kappa[0]) + 1e-6f;
      float nu_ = fmaxf(nu[0], (float)(DD - 1) + 1e-6f);
      float common = nu_ + (float)SHOTS + 1.0f - (float)DD;
      float scale = (kap + SHOTS + 1.0f) / ((nu_ + SHOTS - DD + 1.0f) * (kap + SHOTS));
      cst[0] = kap;
      cst[1] = scale;
      cst[2] = common;
      cst[3] = 0.5f * (common + DD);
      cst[4] = lgammaf(0.5f * (common + DD)) - lgammaf(0.5f * common)
               - 0.5f * (float)DD * logf(common);
      cst[5] = -(kap + SHOTS);
      cst[6] = kap / (kap + SHOTS);
      cst[7] = 1.0f / (kap + SHOTS);
      cst[8] = (float)DD * logf(scale);
      cst[9] = -1.0f / (kap + SHOTS);
    }
  } else if (b < 65) {
    int c = b - 1;
    if (tid < 64) {
      int lane = tid, cnt = 0;
      for (int i0 = 0; i0 < NSUP; i0 += 64) {
        int lab = labels[i0 + lane];
        unsigned long long mm = __ballot(lab == c);
        if (lab == c) {
          int pos = cnt + __popcll(mm & ((1ull << lane) - 1ull));
          if (pos < SHOTS) idx[c * SHOTS + pos] = i0 + lane;
        }
        cnt += __popcll(mm);
      }
    }
    __syncthreads();
    if (tid < 17)
      rowmap[c * 17 + tid] = (tid < SHOTS) ? (QNQ + idx[c * SHOTS + tid])
                                           : (QNQ + NSUP + c);
  } else if (b < 129) {
    // mu/mun with locally re-derived idx; also emit PX for mu rows
    int c = b - 65;
    if (tid < 64) {
      int lane = tid, cnt = 0;
      for (int i0 = 0; i0 < NSUP; i0 += 64) {
        int lab = labels[i0 + lane];
        unsigned long long mm = __ballot(lab == c);
        if (lab == c) {
          int pos = cnt + __popcll(mm & ((1ull << lane) - 1ull));
          if (pos < SHOTS) sidx[pos] = i0 + lane;
        }
        cnt += __popcll(mm);
      }
    }
    __syncthreads();
    float kap = fabsf(kappa[0]) + 1e-6f;
    float cm = kap / (kap + SHOTS), cx = 1.0f / (kap + SHOTS);
    float* red = sh;
    float acc = 0.0f;
    size_t prow = (size_t)(3072 + c) * 1024;
    for (int d = tid; d < DD; d += 256) {
      float s = 0.0f;
      for (int sh_ = 0; sh_ < SHOTS; sh_++)
        s += Xs[(size_t)sidx[sh_] * DD + d];
      float v = cm * m[d] + cx * s;
      mu[(size_t)c * DD + d] = v;
      unsigned short h = f2bf(v), l = f2bf(v - bf2f(h));
      PX[prow + d] = h;
      PX[prow + 512 + d] = l;
      acc += v * v;
    }
    red[tid] = acc;
    __syncthreads();
    for (int off = 128; off > 0; off >>= 1) {
      if (tid < off) red[tid] += red[tid + off];
      __syncthreads();
    }
    if (tid == 0) mun[c] = red[0];
  } else if (b < 137) {
    // diag 64x64 inverse (L tile from tdiag/tlow) + PW emit
    int jb = b - 129;
    float* Ld = sh;             // [64][68]
    float* Wd = sh + 64 * 68;   // [64][68]
    for (int t = tid; t < 4096; t += 256) {
      int r = t >> 6, c = t & 63;
      int gr = jb * 64 + r;
      float v = (r == c) ? fabsf(tdiag[gr])
              : (r > c ? tlow[(size_t)gr * DD + jb * 64 + c] : 0.0f);
      Ld[r * 68 + c] = v;
    }
    __syncthreads();
    if (tid < 64) {
      for (int i = 0; i < 64; i++) {
        float w = (i == tid) ? 1.0f : 0.0f;
        for (int k = 0; k < i; k++) w -= Ld[i * 68 + k] * Wd[k * 68 + tid];
        Wd[i * 68 + tid] = w / Ld[i * 68 + i];
      }
    }
    __syncthreads();
    float* Wblk = W + (size_t)(jb * 64) * DD + jb * 64;
    for (int t = tid; t < 4096; t += 256) {
      int r = t >> 6, c = t & 63;
      float v = Wd[r * 68 + c];
      Wblk[(size_t)r * DD + c] = v;
      unsigned short h = f2bf(v), l = f2bf(v - bf2f(h));
      size_t prow = (size_t)(jb * 64 + r) * 1024 + jb * 64 + c;
      PW[prow] = h;
      PW[prow + 512] = l;
    }
  } else {
    // PX for Xq/Xs rows: 4 rows per block
    int r0 = (b - 137) * 4;
    int row = r0 + (tid >> 6), lane = tid & 63;
    const float* src = (row < QNQ) ? Xq + (size_t)row * DD
                                   : Xs + (size_t)(row - QNQ) * DD;
    size_t prow = (size_t)row * 1024;
    #pragma unroll
    for (int p = 0; p < 2; p++) {
      int col = lane * 8 + p * 4;
      float4 v = *(const float4*)(src + col);
      ushort4 hi, lo;
      hi.x = f2bf(v.x); lo.x = f2bf(v.x - bf2f(hi.x));
      hi.y = f2bf(v.y); lo.y = f2bf(v.y - bf2f(hi.y));
      hi.z = f2bf(v.z); lo.z = f2bf(v.z - bf2f(hi.z));
      hi.w = f2bf(v.w); lo.w = f2bf(v.w - bf2f(hi.w));
      *(ushort4*)(PX + prow + col) = hi;
      *(ushort4*)(PX + prow + 512 + col) = lo;
    }
  }
}

// ---- 64x64 tile helpers (stride-68 LDS) ----
__device__ __forceinline__ void tile_stage(float* S, const float* __restrict__ G, int ldg) {
  int tid = threadIdx.x;
  #pragma unroll
  for (int p = 0; p < 4; p++) {
    int f4 = tid + 256 * p;
    int row = f4 >> 4, c4 = (f4 & 15) * 4;
    *(float4*)&S[row * 68 + c4] = *(const float4*)(G + (size_t)row * ldg + c4);
  }
}
__device__ __forceinline__ void tile_fma(float acc[4][4], const float* As, const float* Bs) {
  int tid = threadIdx.x, tr = tid >> 4, tc = tid & 15;
  #pragma unroll
  for (int kk = 0; kk < 64; kk++) {
    float a[4];
    #pragma unroll
    for (int x = 0; x < 4; x++) a[x] = As[(tr * 4 + x) * 68 + kk];
    float4 bv = *(const float4*)&Bs[kk * 68 + tc * 4];
    float bb[4] = {bv.x, bv.y, bv.z, bv.w};
    #pragma unroll
    for (int x = 0; x < 4; x++)
      #pragma unroll
      for (int y = 0; y < 4; y++) acc[x][y] += a[x] * bb[y];
  }
}
// write -acc to W (fp32) and PW (bf16 hi/lo split)
__device__ __forceinline__ void tile_out_neg(const float acc[4][4], float* W,
    unsigned short* PW, int gr0, int gc0) {
  int tid = threadIdx.x, tr = tid >> 4, tc = tid & 15;
  #pragma unroll
  for (int x = 0; x < 4; x++) {
    #pragma unroll
    for (int y = 0; y < 4; y++) {
      float v = -acc[x][y];
      W[(size_t)(gr0 + tr * 4 + x) * DD + gc0 + tc * 4 + y] = v;
      unsigned short h = f2bf(v), l = f2bf(v - bf2f(h));
      size_t prow = (size_t)(gr0 + tr * 4 + x) * 1024 + gc0 + tc * 4 + y;
      PW[prow] = h;
      PW[prow + 512] = l;
    }
  }
}

#define GBK 16
// ============ merged trinv level 128 (T+X in one) fused with xmu partials ============
__global__ __launch_bounds__(256) void k_m128_xmu(const float* __restrict__ tlow,
    const float* __restrict__ W_, float* __restrict__ Wout,
    const float* __restrict__ Xq, const float* __restrict__ Mu,
    float* __restrict__ xmup, unsigned short* __restrict__ PW) {
  __shared__ float sh[3 * 64 * 68];   // As | Bs | tsh = 52.2 KB
  int b = blockIdx.x, tid = threadIdx.x;
  if (b < 4) {
    float* As = sh;
    float* Bs = sh + 64 * 68;
    float* tsh = sh + 2 * 64 * 68;
    int base = b * 128;
    // t = C * Ainv   (C = tlow[base+64.., base..], Ainv = W diag block)
    float tacc[4][4] = {};
    tile_stage(As, tlow + (size_t)(base + 64) * DD + base, DD);   // C
    tile_stage(Bs, W_ + (size_t)base * DD + base, DD);            // Ainv
    __syncthreads();
    tile_fma(tacc, As, Bs);
    __syncthreads();
    {
      int tr = tid >> 4, tc = tid & 15;
      #pragma unroll
      for (int x = 0; x < 4; x++)
        #pragma unroll
        for (int y = 0; y < 4; y++) tsh[(tr * 4 + x) * 68 + tc * 4 + y] = tacc[x][y];
    }
    tile_stage(As, W_ + (size_t)(base + 64) * DD + base + 64, DD); // Binv
    __syncthreads();
    float xacc[4][4] = {};
    tile_fma(xacc, As, tsh);
    tile_out_neg(xacc, Wout, PW, base + 64, base);
  } else {                  // xmu partials: 32 q-rows, split-K=4
    float* As = sh;               // stride 36, 16 rows
    float* Bs = sh + 16 * 36;     // stride 68, 16 rows
    int xb = b - 4;
    int bm = (xb & 63) * 32, kq = xb >> 6;
    int tr = tid >> 4, tc = tid & 15;
    float acc[2][4] = {};
    int k0s = kq * (DD / XKS), k0e = k0s + DD / XKS;
    for (int k0 = k0s; k0 < k0e; k0 += GBK) {
      if (tid < 128) {
        int row = tid >> 2, k4 = tid & 3;
        float4 v = *(const float4*)(Xq + (size_t)(bm + row) * DD + k0 + k4 * 4);
        As[(k4 * 4 + 0) * 36 + row] = v.x; As[(k4 * 4 + 1) * 36 + row] = v.y;
        As[(k4 * 4 + 2) * 36 + row] = v.z; As[(k4 * 4 + 3) * 36 + row] = v.w;
      }
      {
        int row = tid >> 2, k4 = tid & 3;
        float4 v = *(const float4*)(Mu + (size_t)row * DD + k0 + k4 * 4);
        Bs[(k4 * 4 + 0) * 68 + row] = v.x; Bs[(k4 * 4 + 1) * 68 + row] = v.y;
        Bs[(k4 * 4 + 2) * 68 + row] = v.z; Bs[(k4 * 4 + 3) * 68 + row] = v.w;
      }
      __syncthreads();
      #pragma unroll
      for (int kk = 0; kk < GBK; kk++) {
        float a[2] = {As[kk * 36 + tr * 2], As[kk * 36 + tr * 2 + 1]};
        float4 b0 = *(const float4*)&Bs[kk * 68 + tc * 4];
        float bb[4] = {b0.x, b0.y, b0.z, b0.w};
        #pragma unroll
        for (int x = 0; x < 2; x++)
          #pragma unroll
          for (int y = 0; y < 4; y++) acc[x][y] += a[x] * bb[y];
      }
      __syncthreads();
    }
    #pragma unroll
    for (int x = 0; x < 2; x++) {
      int q = bm + tr * 2 + x;
      float4 v = make_float4(acc[x][0], acc[x][1], acc[x][2], acc[x][3]);
      *(float4*)(xmup + ((size_t)kq * QNQ + q) * CNUM + tc * 4) = v;
    }
  }
}

// ============ merged trinv level 256: X(i,j) = -Binv(i,:)*C*Ainv(:,j) ============
// 8 blocks: (super g, i, j). t chunks k<=i (Binv lower-tri), l>=j (Ainv lower-tri).
__global__ __launch_bounds__(256) void k_m256(const float* __restrict__ tlow,
    float* __restrict__ W, unsigned short* __restrict__ PW) {
  __shared__ float sh[3 * 64 * 68];
  float* As = sh;
  float* Bs = sh + 64 * 68;
  float* tsh = sh + 2 * 64 * 68;
  int b = blockIdx.x, tid = threadIdx.x;
  int g = b >> 2, rem = b & 3, i = rem >> 1, j = rem & 1;
  int base = g * 256;
  float xacc[4][4] = {};
  for (int k = 0; k <= i; k++) {
    float tacc[4][4] = {};
    for (int l = j; l < 2; l++) {
      __syncthreads();
      tile_stage(As, tlow + (size_t)(base + 128 + 64 * k) * DD + base + 64 * l, DD); // C(k,l)
      tile_stage(Bs, W + (size_t)(base + 64 * l) * DD + base + 64 * j, DD);          // Ainv(l,j)
      __syncthreads();
      tile_fma(tacc, As, Bs);
    }
    __syncthreads();
    {
      int tr = tid >> 4, tc = tid & 15;
      #pragma unroll
      for (int x = 0; x < 4; x++)
        #pragma unroll
        for (int y = 0; y < 4; y++) tsh[(tr * 4 + x) * 68 + tc * 4 + y] = tacc[x][y];
    }
    tile_stage(As, W + (size_t)(base + 128 + 64 * i) * DD + base + 128 + 64 * k, DD); // Binv(i,k)
    __syncthreads();
    tile_fma(xacc, As, tsh);
  }
  tile_out_neg(xacc, W, PW, base + 128 + 64 * i, base + 64 * j);
}

// 64x64 NN GEMM tile on caller LDS (stride 68): Cd = sgn * A[:,k0:k1] * B[k0:k1,:]
__device__ __forceinline__ void nn64_sh(float* As, float* Bs,
    const float* __restrict__ A, int lda, const float* __restrict__ B, int ldb,
    float* __restrict__ Cd, int ldc, int k0, int k1, float sgn,
    unsigned short* __restrict__ Pw, int gr0, int gc0) {
  int tid = threadIdx.x, tr = tid >> 4, tc = tid & 15;
  float acc[4][4] = {};
  for (int kc = k0; kc < k1; kc += 64) {
    #pragma unroll
    for (int p = 0; p < 4; p++) {
      int f4 = tid + 256 * p;
      int row = f4 >> 4, c4 = f4 & 15;
      *(float4*)&As[row * 68 + c4 * 4] = *(const float4*)(A + (size_t)row * lda + kc + c4 * 4);
      *(float4*)&Bs[row * 68 + c4 * 4] = *(const float4*)(B + (size_t)(kc + row) * ldb + c4 * 4);
    }
    __syncthreads();
    #pragma unroll
    for (int kk = 0; kk < 64; kk++) {
      float a[4];
      #pragma unroll
      for (int x = 0; x < 4; x++) a[x] = As[(tr * 4 + x) * 68 + kk];
      float4 bv = *(const float4*)&Bs[kk * 68 + tc * 4];
      float bb[4] = {bv.x, bv.y, bv.z, bv.w};
      #pragma unroll
      for (int x = 0; x < 4; x++)
        #pragma unroll
        for (int y = 0; y < 4; y++) acc[x][y] += a[x] * bb[y];
    }
    __syncthreads();
  }
  #pragma unroll
  for (int x = 0; x < 4; x++) {
    float4 v = make_float4(sgn * acc[x][0], sgn * acc[x][1],
                           sgn * acc[x][2], sgn * acc[x][3]);
    *(float4*)(Cd + (size_t)(tr * 4 + x) * ldc + tc * 4) = v;
    if (Pw) {
      size_t prow = (size_t)(gr0 + tr * 4 + x) * 1024 + gc0 + tc * 4;
      float vv[4] = {v.x, v.y, v.z, v.w};
      #pragma unroll
      for (int y = 0; y < 4; y++) {
        unsigned short h = f2bf(vv[y]), l = f2bf(vv[y] - bf2f(h));
        Pw[prow + y] = h;
        Pw[prow + 512 + y] = l;
      }
    }
  }
}

// trinv level-512 T: reads tlow directly (region strictly lower)
__global__ __launch_bounds__(256) void k_triT(const float* __restrict__ tlow,
                                              const float* __restrict__ W,
                                              float* __restrict__ T, int s) {
  __shared__ float sh[2 * 64 * 68];
  int h = s >> 1, tiles = h >> 6, per = tiles * tiles;
  int g = blockIdx.x / per, rem = blockIdx.x % per;
  int ti = rem / tiles, tj = rem % tiles;
  int base = g * s;
  const float* A = tlow + (size_t)(base + h + ti * 64) * DD + base;
  const float* B = W + (size_t)base * DD + base + tj * 64;
  float* Cd = T + (size_t)g * h * h + (size_t)(ti * 64) * h + tj * 64;
  nn64_sh(sh, sh + 64 * 68, A, DD, B, DD, Cd, h, tj * 64, h, 1.0f, nullptr, 0, 0);
}

// trinv level-512 X (emits PW)
__global__ __launch_bounds__(256) void k_triX(float* __restrict__ W,
                                              const float* __restrict__ T, int s,
                                              unsigned short* __restrict__ PW) {
  __shared__ float sh[2 * 64 * 68];
  int h = s >> 1, tiles = h >> 6, per = tiles * tiles;
  int g = blockIdx.x / per, rem = blockIdx.x % per;
  int ti = rem / tiles, tj = rem % tiles;
  int base = g * s;
  const float* A = W + (size_t)(base + h + ti * 64) * DD + base + h;
  const float* B = T + (size_t)g * h * h + tj * 64;
  int gr0 = base + h + ti * 64, gc0 = base + tj * 64;
  float* Cd = W + (size_t)gr0 * DD + gc0;
  nn64_sh(sh, sh + 64 * 68, A, DD, B, h, Cd, DD, 0, (ti + 1) * 64, -1.0f, PW, gr0, gc0);
}

#define PSTR 80   // LDS row stride in bf16
// ============ F3: Y-GEMM via 4-combo bf16-split MFMA (tri-skip) + wm ============
__global__ __launch_bounds__(256) void f_y_wm(const unsigned short* __restrict__ PX,
    const unsigned short* __restrict__ PW, const float* __restrict__ W,
    const float* __restrict__ m, float* __restrict__ Y,
    unsigned short* __restrict__ Pm, float* __restrict__ wm) {
  __shared__ unsigned short AshH[64 * PSTR];
  __shared__ unsigned short AshL[64 * PSTR];
  __shared__ unsigned short BshH[64 * PSTR];
  __shared__ unsigned short BshL[64 * PSTR];
  int b = blockIdx.x, tid = threadIdx.x;
  if (b < 392) {            // 49 m-tiles x 8 n-tiles, 64x64
    int mt = b >> 3, nt = b & 7;
    int bm = mt * 64, bn = nt * 64;
    int lane = tid & 63, wave = tid >> 6;
    int wr = wave >> 1, wc = wave & 1;
    int mrow = lane & 15, q = lane >> 4;
    f32x4 acc00 = {}, acc01 = {}, acc10 = {}, acc11 = {};
    int kchunks = nt + 1;   // W lower-triangular: k < bn+64
    for (int it = 0; it < kchunks; it++) {
      int kc = it * 64;
      #pragma unroll
      for (int p = 0; p < 2; p++) {
        int idx = tid + 256 * p;
        int row = idx >> 3, c8 = (idx & 7) * 8;
        *(short8*)&AshH[row * PSTR + c8] =
            *(const short8*)(PX + (size_t)(bm + row) * 1024 + kc + c8);
        *(short8*)&AshL[row * PSTR + c8] =
            *(const short8*)(PX + (size_t)(bm + row) * 1024 + 512 + kc + c8);
        *(short8*)&BshH[row * PSTR + c8] =
            *(const short8*)(PW + (size_t)(bn + row) * 1024 + kc + c8);
        *(short8*)&BshL[row * PSTR + c8] =
            *(const short8*)(PW + (size_t)(bn + row) * 1024 + 512 + kc + c8);
      }
      __syncthreads();
      #pragma unroll
      for (int ks = 0; ks < 2; ks++) {
        int ko = ks * 32 + q * 8;
        short8 ah0 = *(const short8*)&AshH[(wr * 32 + mrow) * PSTR + ko];
        short8 ah1 = *(const short8*)&AshH[(wr * 32 + 16 + mrow) * PSTR + ko];
        short8 al0 = *(const short8*)&AshL[(wr * 32 + mrow) * PSTR + ko];
        short8 al1 = *(const short8*)&AshL[(wr * 32 + 16 + mrow) * PSTR + ko];
        short8 bh0 = *(const short8*)&BshH[(wc * 32 + mrow) * PSTR + ko];
        short8 bh1 = *(const short8*)&BshH[(wc * 32 + 16 + mrow) * PSTR + ko];
        short8 bl0 = *(const short8*)&BshL[(wc * 32 + mrow) * PSTR + ko];
        short8 bl1 = *(const short8*)&BshL[(wc * 32 + 16 + mrow) * PSTR + ko];
        acc00 = __builtin_amdgcn_mfma_f32_16x16x32_bf16(ah0, bh0, acc00, 0, 0, 0);
        acc00 = __builtin_amdgcn_mfma_f32_16x16x32_bf16(ah0, bl0, acc00, 0, 0, 0);
        acc00 = __builtin_amdgcn_mfma_f32_16x16x32_bf16(al0, bh0, acc00, 0, 0, 0);
        acc00 = __builtin_amdgcn_mfma_f32_16x16x32_bf16(al0, bl0, acc00, 0, 0, 0);
        acc01 = __builtin_amdgcn_mfma_f32_16x16x32_bf16(ah0, bh1, acc01, 0, 0, 0);
        acc01 = __builtin_amdgcn_mfma_f32_16x16x32_bf16(ah0, bl1, acc01, 0, 0, 0);
        acc01 = __builtin_amdgcn_mfma_f32_16x16x32_bf16(al0, bh1, acc01, 0, 0, 0);
        acc01 = __builtin_amdgcn_mfma_f32_16x16x32_bf16(al0, bl1, acc01, 0, 0, 0);
        acc10 = __builtin_amdgcn_mfma_f32_16x16x32_bf16(ah1, bh0, acc10, 0, 0, 0);
        acc10 = __builtin_amdgcn_mfma_f32_16x16x32_bf16(ah1, bl0, acc10, 0, 0, 0);
        acc10 = __builtin_amdgcn_mfma_f32_16x16x32_bf16(al1, bh0, acc10, 0, 0, 0);
        acc10 = __builtin_amdgcn_mfma_f32_16x16x32_bf16(al1, bl0, acc10, 0, 0, 0);
        acc11 = __builtin_amdgcn_mfma_f32_16x16x32_bf16(ah1, bh1, acc11, 0, 0, 0);
        acc11 = __builtin_amdgcn_mfma_f32_16x16x32_bf16(ah1, bl1, acc11, 0, 0, 0);
        acc11 = __builtin_amdgcn_mfma_f32_16x16x32_bf16(al1, bh1, acc11, 0, 0, 0);
        acc11 = __builtin_amdgcn_mfma_f32_16x16x32_bf16(al1, bl1, acc11, 0, 0, 0);
      }
      __syncthreads();
    }
    #pragma unroll
    for (int r = 0; r < 4; r++) {
      int row0 = bm + wr * 32 + q * 4 + r;
      int row1 = row0 + 16;
      int col0 = bn + wc * 32 + mrow;
      float vv[4] = {acc00[r], acc01[r], acc10[r], acc11[r]};
      int rows[4] = {row0, row0, row1, row1};
      int cols[4] = {col0, col0 + 16, col0, col0 + 16};
      #pragma unroll
      for (int e = 0; e < 4; e++) {
        Y[(size_t)rows[e] * DD + cols[e]] = vv[e];
        unsigned short h = f2bf(vv[e]), l = f2bf(vv[e] - bf2f(h));
        Pm[(size_t)rows[e] * 1024 + cols[e]] = h;
        Pm[(size_t)rows[e] * 1024 + 512 + cols[e]] = l;
      }
    }
  } else {                  // wm[row] = W[row, 0..row] . m  (triangular-bounded)
    int wave = tid >> 6, lane = tid & 63;
    int row = (b - 392) * 4 + wave;
    float s = 0.0f;
    for (int j = lane; j <= row; j += 64) s += W[(size_t)row * DD + j] * m[j];
    for (int off = 32; off > 0; off >>= 1) s += __shfl_down(s, off);
    if (lane == 0) wm[row] = s;
  }
}

// ============ F5: Rg MFMA (both xor-passes, single buffer) + query z/qn/yn + SM consts ============
__global__ __launch_bounds__(256) void f_z_rg(const unsigned short* __restrict__ Pm,
    const float* __restrict__ Y, const float* __restrict__ tdiag,
    const int* __restrict__ rowmap, const float* __restrict__ Xq,
    const float* __restrict__ wm, float* __restrict__ cst,
    float* __restrict__ Rg,
    float* __restrict__ z, float* __restrict__ qn, float* __restrict__ yn) {
  __shared__ unsigned short Ash[64 * PSTR];   // 10.2 KB
  __shared__ unsigned short Bsh[64 * PSTR];
  __shared__ unsigned short Csh[64 * PSTR];
  int b = blockIdx.x, tid = threadIdx.x;
  if (b < 544) {            // 17 m-tiles x 32 n-tiles, 64x64 out
    int bm = (b >> 5) * 64, bn = (b & 31) * 64;
    int lane = tid & 63, wave = tid >> 6;
    int wr = wave >> 1, wc = wave & 1;
    int mrow = lane & 15, q = lane >> 4;
    int srowA[2];
    #pragma unroll
    for (int p = 0; p < 2; p++) srowA[p] = rowmap[bm + ((tid + 256 * p) >> 3)];
    f32x4 acc00 = {}, acc01 = {}, acc10 = {}, acc11 = {};
    for (int it = 0; it < 16; it++) {
      int kc = it * 64;
      int kcX = kc ^ 512;
      #pragma unroll
      for (int p = 0; p < 2; p++) {
        int idx = tid + 256 * p;
        int row = idx >> 3, c8 = (idx & 7) * 8;
        *(short8*)&Ash[row * PSTR + c8] =
            *(const short8*)(Pm + (size_t)srowA[p] * 1024 + kc + c8);
        *(short8*)&Bsh[row * PSTR + c8] =
            *(const short8*)(Pm + (size_t)(bn + row) * 1024 + kc + c8);
        *(short8*)&Csh[row * PSTR + c8] =
            *(const short8*)(Pm + (size_t)(bn + row) * 1024 + kcX + c8);
      }
      __syncthreads();
      #pragma unroll
      for (int ks = 0; ks < 2; ks++) {
        int ko = ks * 32 + q * 8;
        short8 a0 = *(const short8*)&Ash[(wr * 32 + mrow) * PSTR + ko];
        short8 a1 = *(const short8*)&Ash[(wr * 32 + 16 + mrow) * PSTR + ko];
        short8 b0 = *(const short8*)&Bsh[(wc * 32 + mrow) * PSTR + ko];
        short8 b1 = *(const short8*)&Bsh[(wc * 32 + 16 + mrow) * PSTR + ko];
        short8 c0 = *(const short8*)&Csh[(wc * 32 + mrow) * PSTR + ko];
        short8 c1 = *(const short8*)&Csh[(wc * 32 + 16 + mrow) * PSTR + ko];
        acc00 = __builtin_amdgcn_mfma_f32_16x16x32_bf16(a0, b0, acc00, 0, 0, 0);
        acc01 = __builtin_amdgcn_mfma_f32_16x16x32_bf16(a0, b1, acc01, 0, 0, 0);
        acc10 = __builtin_amdgcn_mfma_f32_16x16x32_bf16(a1, b0, acc10, 0, 0, 0);
        acc11 = __builtin_amdgcn_mfma_f32_16x16x32_bf16(a1, b1, acc11, 0, 0, 0);
        acc00 = __builtin_amdgcn_mfma_f32_16x16x32_bf16(a0, c0, acc00, 0, 0, 0);
        acc01 = __builtin_amdgcn_mfma_f32_16x16x32_bf16(a0, c1, acc01, 0, 0, 0);
        acc10 = __builtin_amdgcn_mfma_f32_16x16x32_bf16(a1, c0, acc10, 0, 0, 0);
        acc11 = __builtin_amdgcn_mfma_f32_16x16x32_bf16(a1, c1, acc11, 0, 0, 0);
      }
      __syncthreads();
    }
    #pragma unroll
    for (int r = 0; r < 4; r++) {
      int row0 = bm + wr * 32 + q * 4 + r;
      int row1 = row0 + 16;
      int col0 = bn + wc * 32 + mrow;
      Rg[(size_t)row0 * QNQ + col0]      = acc00[r];
      Rg[(size_t)row0 * QNQ + col0 + 16] = acc01[r];
      Rg[(size_t)row1 * QNQ + col0]      = acc10[r];
      Rg[(size_t)row1 * QNQ + col0 + 16] = acc11[r];
    }
  } else if (b < 1056) {    // query rows: z = Y.wm, qn = |x|^2, yn = |Y|^2
    int wave = tid >> 6, lane = tid & 63;
    int row = (b - 544) * 4 + wave;
    const float* xr = Xq + (size_t)row * DD;
    const float* yr = Y + (size_t)row * DD;
    float sz = 0.0f, s1 = 0.0f, s2 = 0.0f;
    for (int j4 = lane; j4 < 128; j4 += 64) {
      float4 xv = *(const float4*)(xr + j4 * 4);
      float4 yv = *(const float4*)(yr + j4 * 4);
      float4 wv = *(const float4*)(wm + j4 * 4);
      sz += yv.x * wv.x + yv.y * wv.y + yv.z * wv.z + yv.w * wv.w;
      s1 += xv.x * xv.x + xv.y * xv.y + xv.z * xv.z + xv.w * xv.w;
      s2 += yv.x * yv.x + yv.y * yv.y + yv.z * yv.z + yv.w * yv.w;
    }
    for (int off = 32; off > 0; off >>= 1) {
      sz += __shfl_down(sz, off);
      s1 += __shfl_down(s1, off);
      s2 += __shfl_down(s2, off);
    }
    if (lane == 0) {
      z[row] = sz;
      qn[row] = s1;
      yn[row] = s2;
    }
  } else {                  // SM consts (wm + tdiag only)
    __shared__ float red[256], red2[256];
    float a = 0.0f, l = 0.0f;
    for (int t = tid; t < DD; t += 256) {
      float w = wm[t]; a += w * w;
      l += logf(fabsf(tdiag[t]));
    }
    red[tid] = a; red2[tid] = l;
    __syncthreads();
    for (int off = 128; off > 0; off >>= 1) {
      if (tid < off) { red[tid] += red[tid + off]; red2[tid] += red2[tid + off]; }
      __syncthreads();
    }
    if (tid == 0) {
      float kap = cst[0], ss = red[0];
      cst[10] = kap / (1.0f + kap * ss);
      cst[11] = 2.0f * red2[0] + logf(1.0f + kap * ss);
    }
  }
}

// ============ F6: per-class Gram (zs = Y.wm) + GJ inverse + bias ============
#define YSTRIDE 516
__global__ __launch_bounds__(256) void k_gramminv(const float* Y, const float* wm,
    const int* rowmap, const float* cst, float* zg, float* Vmu, float* muBmu,
    float* Minv, float* bias) {
  __shared__ float Ys[17 * YSTRIDE];
  __shared__ float zs[17];
  __shared__ float aug[17][35];
  __shared__ float colk[17];
  __shared__ int pivrow;
  __shared__ float detacc;
  int c = blockIdx.x, tid = threadIdx.x;
  for (int t = tid; t < 17 * 128; t += 256) {
    int r = t >> 7, col = t & 127;
    *(float4*)&Ys[r * YSTRIDE + col * 4] =
        *(const float4*)(Y + (size_t)rowmap[c * 17 + r] * DD + col * 4);
  }
  __syncthreads();
  {
    int wave = tid >> 6, lane = tid & 63;
    for (int a = wave; a < 17; a += 4) {
      float s = 0.0f;
      for (int j = lane; j < DD; j += 64) s += Ys[a * YSTRIDE + j] * wm[j];
      for (int off = 32; off > 0; off >>= 1) s += __shfl_down(s, off);
      if (lane == 0) zs[a] = s;
    }
  }
  __syncthreads();
  float csm = cst[10];
  for (int e = tid; e < 289; e += 256) {
    int a = e / 17, bb = e % 17;
    const float* ra = &Ys[a * YSTRIDE];
    const float* rb = &Ys[bb * YSTRIDE];
    float s = 0.0f;
    for (int k = 0; k < 128; k++) {
      float4 va = *(const float4*)&ra[k * 4];
      float4 vb = *(const float4*)&rb[k * 4];
      s += va.x * vb.x + va.y * vb.y + va.z * vb.z + va.w * vb.w;
    }
    float g = s - csm * zs[a] * zs[bb];
    if (a == bb) g += (a < 16) ? 1.0f : cst[9];
    aug[a][bb] = g;
    aug[a][17 + bb] = (a == bb) ? 1.0f : 0.0f;
  }
  __syncthreads();
  if (tid < 17) {
    float gv = aug[tid][16];
    if (tid == 16) gv -= cst[9];
    Vmu[c * 17 + tid] = gv;
    if (tid == 16) muBmu[c] = gv;
    zg[c * 17 + tid] = zs[tid];
  }
  if (tid == 0) detacc = 0.0f;
  __syncthreads();
  for (int k = 0; k < 17; k++) {
    if (tid == 0) {
      int p = k; float best = fabsf(aug[k][k]);
      for (int r = k + 1; r < 17; r++) {
        float v = fabsf(aug[r][k]);
        if (v > best) { best = v; p = r; }
      }
      pivrow = p;
    }
    __syncthreads();
    int p = pivrow;
    if (p != k) {
      for (int cc = tid; cc < 34; cc += 256) {
        float tmp = aug[k][cc]; aug[k][cc] = aug[p][cc]; aug[p][cc] = tmp;
      }
    }
    __syncthreads();
    if (tid == 0) detacc += logf(fabsf(aug[k][k]));
    if (tid < 17) colk[tid] = aug[tid][k];
    __syncthreads();
    float invp = 1.0f / aug[k][k];
    for (int cc = tid; cc < 34; cc += 256) aug[k][cc] *= invp;
    __syncthreads();
    for (int t = tid; t < 17 * 34; t += 256) {
      int r = t / 34, cc = t % 34;
      if (r != k) aug[r][cc] -= colk[r] * aug[k][cc];
    }
    __syncthreads();
  }
  for (int t = tid; t < 289; t += 256) Minv[(size_t)c * 289 + t] = aug[t / 17][17 + t % 17];
  if (tid == 0) {
    float slog = logf(fabsf(cst[5])) + detacc;
    float logdetSigma = cst[8] + cst[11] + slog;
    bias[c] = cst[4] - 0.5f * logdetSigma;
  }
}

// final epilogue: Woodbury-corrected Mahalanobis -> logits[q,c]
__global__ __launch_bounds__(256) void k_logits(const float* __restrict__ Rg,
    const float* z, const float* zg,
    const float* Vmu, const float* muBmu, const float* mun, const float* yn,
    const float* qn, const float* xmup, const float* Minv, const float* bias,
    const float* cst, float* out) {
  __shared__ float Ms[289], Vs[17], Zs[17];
  int c = blockIdx.y;
  int q = blockIdx.x * 256 + threadIdx.x;
  for (int t = threadIdx.x; t < 289; t += 256) Ms[t] = Minv[(size_t)c * 289 + t];
  if (threadIdx.x < 17) {
    Vs[threadIdx.x] = Vmu[c * 17 + threadIdx.x];
    Zs[threadIdx.x] = zg[c * 17 + threadIdx.x];
  }
  __syncthreads();
  float csm = cst[10], scale = cst[1], common = cst[2], coef = cst[3];
  float zq = z[q];
  float r[17];
  float xBmu = 0.0f;
  for (int a = 0; a < 17; a++) {
    float raw = Rg[(size_t)(c * 17 + a) * QNQ + q] - csm * Zs[a] * zq;
    if (a == 16) xBmu = raw;
    r[a] = raw - Vs[a];
  }
  float qB = yn[q] - csm * zq * zq;
  float quadB = qB - 2.0f * xBmu + muBmu[c];
  float corr = 0.0f;
  for (int a = 0; a < 17; a++) {
    float e = 0.0f;
    for (int bb = 0; bb < 17; bb++) e += Ms[a * 17 + bb] * r[bb];
    corr += r[a] * e;
  }
  float distB = (quadB - corr) / scale;
  float xm = 0.0f;
  #pragma unroll
  for (int p = 0; p < XKS; p++)
    xm += xmup[((size_t)p * QNQ + q) * CNUM + c];
  float dn = qn[q] - 2.0f * xm + mun[c];
  float dist = (1.0f - REGP) * distB + REGP * dn;
  out[(size_t)q * CNUM + c] = bias[c] - coef * log1pf(dist / common);
}

// ---------------- host ----------------
extern "C" void kernel_launch(void* const* d_in, const int* in_sizes, int n_in,
                              void* d_out, int out_size, void* d_ws, size_t ws_size,
                              hipStream_t stream) {
  const float* Xs    = (const float*)d_in[0];
  const int*   labels= (const int*)d_in[1];
  const float* Xq    = (const float*)d_in[2];
  const float* m     = (const float*)d_in[3];
  const float* kappa = (const float*)d_in[4];
  const float* nu    = (const float*)d_in[5];
  const float* tdiag = (const float*)d_in[6];
  const float* tlow  = (const float*)d_in[7];
  float* ws = (float*)d_ws;
  float* W    = ws + OFF_W;
  float* mu   = ws + OFF_MU;
  float* Y    = ws + OFF_Y;
  float* z    = ws + OFF_Z;
  float* wm   = ws + OFF_WM;
  float* cst  = ws + OFF_CONST;
  int*   idx  = (int*)(ws + OFF_IDX);
  int*   rmap = (int*)(ws + OFF_RMAP);
  float* zg   = ws + OFF_ZG;
  float* Vmu  = ws + OFF_VMU;
  float* muBmu= ws + OFF_MUBMU;
  float* mun  = ws + OFF_MUN;
  float* Minv = ws + OFF_MINV;
  float* bias = ws + OFF_BIAS;
  float* qn   = ws + OFF_QNRM;
  float* yn   = ws + OFF_YN;
  float* xmup = ws + OFF_XMU;
  float* Rg   = ws + OFF_RG;
  unsigned short* P  = (unsigned short*)(ws + OFF_P);
  unsigned short* PX = (unsigned short*)(ws + OFF_PX);
  unsigned short* PW = (unsigned short*)(ws + OFF_PW);
  float* Ttmp = ws + OFF_RG;       // trinv scratch, reused (Rg written later)
  float* out  = (float*)d_out;

  // F1: consts + classidx + mu/mun(+PX) + diag-inv(+PW) + PX(Xq/Xs)
  f_init<<<905, 256, 0, stream>>>(tdiag, tlow, kappa, nu, labels, Xs, Xq, m,
                                  W, cst, idx, rmap, mu, mun, PX, PW);
  // trinv: merged level-128 (T+X, fused with xmu), merged level-256, split level-512
  k_m128_xmu<<<260, 256, 0, stream>>>(tlow, W, W, Xq, mu, xmup, PW);
  k_m256<<<8, 256, 0, stream>>>(tlow, W, PW);
  k_triT<<<16, 256, 0, stream>>>(tlow, W, Ttmp, 512);
  k_triX<<<16, 256, 0, stream>>>(W, Ttmp, 512, PW);
  // Y via 4-combo split MFMA (tri-skip) + wm (triangular-bounded)
  f_y_wm<<<520, 256, 0, stream>>>(PX, PW, W, m, Y, P, wm);
  // Rg MFMA (single buffer, both passes) + query z/qn/yn + SM consts
  f_z_rg<<<544 + 512 + 1, 256, 0, stream>>>(P, Y, tdiag, rmap, Xq, wm, cst, Rg, z, qn, yn);
  // Gram (zs = Y.wm) + 17x17 inverse + bias
  k_gramminv<<<64, 256, 0, stream>>>(Y, wm, rmap, cst, zg, Vmu, muBmu, Minv, bias);
  k_logits<<<dim3(QNQ / 256, CNUM), 256, 0, stream>>>(Rg, z, zg, Vmu, muBmu,
                                                      mun, yn, qn, xmup, Minv, bias,
                                                      cst, out);
  (void)in_sizes; (void)n_in; (void)out_size; (void)ws_size;
}

// Round 17
// 214.829 us; speedup vs baseline: 1.2316x; 1.1136x over previous
//
#include <hip/hip_runtime.h>
#include <math.h>

// Problem dims (fixed by setup_inputs)
#define DD    512
#define CNUM  64
#define SHOTS 16
#define NSUP  1024
#define QNQ   2048
#define REGP  0.1f
#define XKS   4      // xmu split-K parts

typedef __attribute__((ext_vector_type(8))) short short8;   // 8 bf16 = 4 VGPRs
typedef __attribute__((ext_vector_type(4))) float f32x4;

// bf16 round-to-nearest-even, raw bits
__device__ __forceinline__ unsigned short f2bf(float f) {
  unsigned int u = __float_as_uint(f);
  unsigned int r = (u + 0x7fffu + ((u >> 16) & 1u)) >> 16;
  return (unsigned short)r;
}
__device__ __forceinline__ float bf2f(unsigned short h) {
  return __uint_as_float((unsigned int)h << 16);
}

// ---------------- workspace layout (in floats) ----------------
// L is never materialized: all consumers read tdiag/tlow directly.
static constexpr size_t OFF_W     = 0;                       // 512*512
static constexpr size_t OFF_MU    = OFF_W     + 512*512;     // 64*512
static constexpr size_t OFF_Y     = OFF_MU    + 64*512;      // 3136*512
static constexpr size_t OFF_Z     = OFF_Y     + 3136*512;    // 2048
static constexpr size_t OFF_WM    = OFF_Z     + 3136;        // 512
static constexpr size_t OFF_CONST = OFF_WM    + 512;         // 16
static constexpr size_t OFF_IDX   = OFF_CONST + 16;          // 1024 ints
static constexpr size_t OFF_RMAP  = OFF_IDX   + 1024;        // 1088 ints
static constexpr size_t OFF_ZG    = OFF_RMAP  + 1088;        // 1088
static constexpr size_t OFF_VMU   = OFF_ZG    + 1088;        // 1088
static constexpr size_t OFF_MUBMU = OFF_VMU   + 1088;        // 64
static constexpr size_t OFF_MUN   = OFF_MUBMU + 64;          // 64
static constexpr size_t OFF_MINV  = OFF_MUN   + 64;          // 64*289
static constexpr size_t OFF_BIAS  = OFF_MINV  + 64*289;      // 64
static constexpr size_t OFF_QNRM  = OFF_BIAS  + 64;          // 2048
static constexpr size_t OFF_YN    = OFF_QNRM  + 2048;        // 2048
static constexpr size_t OFF_XMU   = OFF_YN    + 2048;        // XKS*2048*64
static constexpr size_t OFF_RG    = OFF_XMU   + (size_t)XKS*2048*64; // 1088*2048 (also trinv T)
static constexpr size_t OFF_P     = OFF_RG    + 1088*2048;   // 3136*1024 bf16 (Y split)
static constexpr size_t OFF_PX    = OFF_P     + 3136*512;    // 3136*1024 bf16 (X split)
static constexpr size_t OFF_PW    = OFF_PX    + 3136*512;    // 512*1024 bf16 (W split)

// consts: 0 kap, 1 scale, 2 common, 3 coef, 4 bias0, 5 jlast,
// 6 cmu_m, 7 cmu_x, 8 D*log(scale), 9 Jinv_last, 10 c_sm, 11 logdetB

// ============ F1: consts + classidx + mu/mun(+PX) + diag-inv(+PW) + PX(X) ============
__global__ __launch_bounds__(256) void f_init(const float* tdiag, const float* tlow,
    const float* kappa, const float* nu, const int* labels, const float* Xs,
    const float* Xq, const float* m, float* W, float* cst, int* idx,
    int* rowmap, float* mu, float* mun,
    unsigned short* PX, unsigned short* PW) {
  __shared__ float sh[2 * 64 * 68 + 32 * 33];   // Ld | Wd | tsh = 39 KB
  __shared__ int sidx[SHOTS];
  int b = blockIdx.x, tid = threadIdx.x;
  if (b == 0) {
    if (tid == 0) {
      float kap = fabsf(kappa[0]) + 1e-6f;
      float nu_ = fmaxf(nu[0], (float)(DD - 1) + 1e-6f);
      float common = nu_ + (float)SHOTS + 1.0f - (float)DD;
      float scale = (kap + SHOTS + 1.0f) / ((nu_ + SHOTS - DD + 1.0f) * (kap + SHOTS));
      cst[0] = kap;
      cst[1] = scale;
      cst[2] = common;
      cst[3] = 0.5f * (common + DD);
      cst[4] = lgammaf(0.5f * (common + DD)) - lgammaf(0.5f * common)
               - 0.5f * (float)DD * logf(common);
      cst[5] = -(kap + SHOTS);
      cst[6] = kap / (kap + SHOTS);
      cst[7] = 1.0f / (kap + SHOTS);
      cst[8] = (float)DD * logf(scale);
      cst[9] = -1.0f / (kap + SHOTS);
    }
  } else if (b < 65) {
    int c = b - 1;
    if (tid < 64) {
      int lane = tid, cnt = 0;
      for (int i0 = 0; i0 < NSUP; i0 += 64) {
        int lab = labels[i0 + lane];
        unsigned long long mm = __ballot(lab == c);
        if (lab == c) {
          int pos = cnt + __popcll(mm & ((1ull << lane) - 1ull));
          if (pos < SHOTS) idx[c * SHOTS + pos] = i0 + lane;
        }
        cnt += __popcll(mm);
      }
    }
    __syncthreads();
    if (tid < 17)
      rowmap[c * 17 + tid] = (tid < SHOTS) ? (QNQ + idx[c * SHOTS + tid])
                                           : (QNQ + NSUP + c);
  } else if (b < 129) {
    // mu/mun with locally re-derived idx; also emit PX for mu rows
    int c = b - 65;
    if (tid < 64) {
      int lane = tid, cnt = 0;
      for (int i0 = 0; i0 < NSUP; i0 += 64) {
        int lab = labels[i0 + lane];
        unsigned long long mm = __ballot(lab == c);
        if (lab == c) {
          int pos = cnt + __popcll(mm & ((1ull << lane) - 1ull));
          if (pos < SHOTS) sidx[pos] = i0 + lane;
        }
        cnt += __popcll(mm);
      }
    }
    __syncthreads();
    float kap = fabsf(kappa[0]) + 1e-6f;
    float cm = kap / (kap + SHOTS), cx = 1.0f / (kap + SHOTS);
    float* red = sh;
    float acc = 0.0f;
    size_t prow = (size_t)(3072 + c) * 1024;
    for (int d = tid; d < DD; d += 256) {
      float s = 0.0f;
      for (int sh_ = 0; sh_ < SHOTS; sh_++)
        s += Xs[(size_t)sidx[sh_] * DD + d];
      float v = cm * m[d] + cx * s;
      mu[(size_t)c * DD + d] = v;
      unsigned short h = f2bf(v), l = f2bf(v - bf2f(h));
      PX[prow + d] = h;
      PX[prow + 512 + d] = l;
      acc += v * v;
    }
    red[tid] = acc;
    __syncthreads();
    for (int off = 128; off > 0; off >>= 1) {
      if (tid < off) red[tid] += red[tid + off];
      __syncthreads();
    }
    if (tid == 0) mun[c] = red[0];
  } else if (b < 137) {
    // diag 64x64 inverse via blocked 16->32->64 (parallel; short serial chains)
    int jb = b - 129;
    float* Ld = sh;                   // [64][68]
    float* Wd = sh + 64 * 68;         // [64][68]
    float* tsh = sh + 2 * 64 * 68;    // [32][33]
    for (int t = tid; t < 4096; t += 256) {
      int r = t >> 6, c = t & 63;
      int gr = jb * 64 + r;
      float v = (r == c) ? fabsf(tdiag[gr])
              : (r > c ? tlow[(size_t)gr * DD + jb * 64 + c] : 0.0f);
      Ld[r * 68 + c] = v;
      Wd[r * 68 + c] = 0.0f;
    }
    __syncthreads();
    // step 1: four 16x16 per-column inverses (64 thread-columns, chain 16)
    if (tid < 64) {
      int s = tid >> 4, t = tid & 15;
      int r0 = s * 16;
      #pragma unroll
      for (int i = 0; i < 16; i++) {
        float w = (i == t) ? 1.0f : 0.0f;
        #pragma unroll
        for (int k = 0; k < 16; k++)
          if (k < i) w -= Ld[(r0 + i) * 68 + r0 + k] * Wd[(r0 + k) * 68 + r0 + t];
        Wd[(r0 + i) * 68 + r0 + t] = w / Ld[(r0 + i) * 68 + r0 + i];
      }
    }
    __syncthreads();
    // step 2: two 32-merges: X = -A22inv(16) @ L21(16) @ A11inv(16)
    for (int g2 = 0; g2 < 2; g2++) {
      int r0 = g2 * 32 + 16, c0 = g2 * 32;
      int rr = tid >> 4, cc = tid & 15;
      float t_ = 0.0f;
      #pragma unroll
      for (int k = 0; k < 16; k++)
        t_ += Ld[(r0 + rr) * 68 + c0 + k] * Wd[(c0 + k) * 68 + c0 + cc];
      tsh[rr * 33 + cc] = t_;
      __syncthreads();
      float x = 0.0f;
      #pragma unroll
      for (int k = 0; k < 16; k++)
        x -= Wd[(r0 + rr) * 68 + r0 + k] * tsh[k * 33 + cc];
      Wd[(r0 + rr) * 68 + c0 + cc] = x;
      __syncthreads();
    }
    // step 3: 64-merge: X(32x32) = -Binv(32) @ L21(32) @ Ainv(32)
    {
      int rr = tid >> 6, cc = tid & 63;   // 4 rows x 64 -> covers 32x32 in 8-row steps
      #pragma unroll
      for (int p = 0; p < 4; p++) {
        int r = rr + p * 4, c = cc;
        if (c < 32) {
          float t_ = 0.0f;
          #pragma unroll
          for (int k = 0; k < 32; k++)
            t_ += Ld[(32 + r) * 68 + k] * Wd[k * 68 + c];
          tsh[r * 33 + c] = t_;
        } else {
          int c2 = c - 32;
          float t_ = 0.0f;
          #pragma unroll
          for (int k = 0; k < 32; k++)
            t_ += Ld[(32 + r + 16) * 68 + k] * Wd[k * 68 + c2];
          tsh[(r + 16) * 33 + c2] = t_;
        }
      }
      __syncthreads();
      #pragma unroll
      for (int p = 0; p < 4; p++) {
        int r = rr + p * 4, c = cc;
        int r2 = (c < 32) ? r : r + 16;
        int c2 = (c < 32) ? c : c - 32;
        float x = 0.0f;
        #pragma unroll
        for (int k = 0; k < 32; k++)
          x -= Wd[(32 + r2) * 68 + 32 + k] * tsh[k * 33 + c2];
        Wd[(32 + r2) * 68 + c2] = x;
      }
    }
    __syncthreads();
    float* Wblk = W + (size_t)(jb * 64) * DD + jb * 64;
    for (int t = tid; t < 4096; t += 256) {
      int r = t >> 6, c = t & 63;
      float v = Wd[r * 68 + c];
      Wblk[(size_t)r * DD + c] = v;
      unsigned short h = f2bf(v), l = f2bf(v - bf2f(h));
      size_t prow = (size_t)(jb * 64 + r) * 1024 + jb * 64 + c;
      PW[prow] = h;
      PW[prow + 512] = l;
    }
  } else {
    // PX for Xq/Xs rows: 4 rows per block
    int r0 = (b - 137) * 4;
    int row = r0 + (tid >> 6), lane = tid & 63;
    const float* src = (row < QNQ) ? Xq + (size_t)row * DD
                                   : Xs + (size_t)(row - QNQ) * DD;
    size_t prow = (size_t)row * 1024;
    #pragma unroll
    for (int p = 0; p < 2; p++) {
      int col = lane * 8 + p * 4;
      float4 v = *(const float4*)(src + col);
      ushort4 hi, lo;
      hi.x = f2bf(v.x); lo.x = f2bf(v.x - bf2f(hi.x));
      hi.y = f2bf(v.y); lo.y = f2bf(v.y - bf2f(hi.y));
      hi.z = f2bf(v.z); lo.z = f2bf(v.z - bf2f(hi.z));
      hi.w = f2bf(v.w); lo.w = f2bf(v.w - bf2f(hi.w));
      *(ushort4*)(PX + prow + col) = hi;
      *(ushort4*)(PX + prow + 512 + col) = lo;
    }
  }
}

// ---- 64x64 tile helpers (stride-68 LDS) ----
__device__ __forceinline__ void tile_stage(float* S, const float* __restrict__ G, int ldg) {
  int tid = threadIdx.x;
  #pragma unroll
  for (int p = 0; p < 4; p++) {
    int f4 = tid + 256 * p;
    int row = f4 >> 4, c4 = (f4 & 15) * 4;
    *(float4*)&S[row * 68 + c4] = *(const float4*)(G + (size_t)row * ldg + c4);
  }
}
__device__ __forceinline__ void tile_fma(float acc[4][4], const float* As, const float* Bs) {
  int tid = threadIdx.x, tr = tid >> 4, tc = tid & 15;
  #pragma unroll
  for (int kk = 0; kk < 64; kk++) {
    float a[4];
    #pragma unroll
    for (int x = 0; x < 4; x++) a[x] = As[(tr * 4 + x) * 68 + kk];
    float4 bv = *(const float4*)&Bs[kk * 68 + tc * 4];
    float bb[4] = {bv.x, bv.y, bv.z, bv.w};
    #pragma unroll
    for (int x = 0; x < 4; x++)
      #pragma unroll
      for (int y = 0; y < 4; y++) acc[x][y] += a[x] * bb[y];
  }
}
// write -acc to W (fp32) and PW (bf16 hi/lo split)
__device__ __forceinline__ void tile_out_neg(const float acc[4][4], float* W,
    unsigned short* PW, int gr0, int gc0) {
  int tid = threadIdx.x, tr = tid >> 4, tc = tid & 15;
  #pragma unroll
  for (int x = 0; x < 4; x++) {
    #pragma unroll
    for (int y = 0; y < 4; y++) {
      float v = -acc[x][y];
      W[(size_t)(gr0 + tr * 4 + x) * DD + gc0 + tc * 4 + y] = v;
      unsigned short h = f2bf(v), l = f2bf(v - bf2f(h));
      size_t prow = (size_t)(gr0 + tr * 4 + x) * 1024 + gc0 + tc * 4 + y;
      PW[prow] = h;
      PW[prow + 512] = l;
    }
  }
}

#define GBK 16
// ============ merged trinv level 128 (T+X in one) fused with xmu partials ============
__global__ __launch_bounds__(256) void k_m128_xmu(const float* __restrict__ tlow,
    const float* __restrict__ W_, float* __restrict__ Wout,
    const float* __restrict__ Xq, const float* __restrict__ Mu,
    float* __restrict__ xmup, unsigned short* __restrict__ PW) {
  __shared__ float sh[3 * 64 * 68];   // As | Bs | tsh = 52.2 KB
  int b = blockIdx.x, tid = threadIdx.x;
  if (b < 4) {
    float* As = sh;
    float* Bs = sh + 64 * 68;
    float* tsh = sh + 2 * 64 * 68;
    int base = b * 128;
    float tacc[4][4] = {};
    tile_stage(As, tlow + (size_t)(base + 64) * DD + base, DD);   // C
    tile_stage(Bs, W_ + (size_t)base * DD + base, DD);            // Ainv
    __syncthreads();
    tile_fma(tacc, As, Bs);
    __syncthreads();
    {
      int tr = tid >> 4, tc = tid & 15;
      #pragma unroll
      for (int x = 0; x < 4; x++)
        #pragma unroll
        for (int y = 0; y < 4; y++) tsh[(tr * 4 + x) * 68 + tc * 4 + y] = tacc[x][y];
    }
    tile_stage(As, W_ + (size_t)(base + 64) * DD + base + 64, DD); // Binv
    __syncthreads();
    float xacc[4][4] = {};
    tile_fma(xacc, As, tsh);
    tile_out_neg(xacc, Wout, PW, base + 64, base);
  } else {                  // xmu partials: 32 q-rows, split-K=4
    float* As = sh;               // stride 36, 16 rows
    float* Bs = sh + 16 * 36;     // stride 68, 16 rows
    int xb = b - 4;
    int bm = (xb & 63) * 32, kq = xb >> 6;
    int tr = tid >> 4, tc = tid & 15;
    float acc[2][4] = {};
    int k0s = kq * (DD / XKS), k0e = k0s + DD / XKS;
    for (int k0 = k0s; k0 < k0e; k0 += GBK) {
      if (tid < 128) {
        int row = tid >> 2, k4 = tid & 3;
        float4 v = *(const float4*)(Xq + (size_t)(bm + row) * DD + k0 + k4 * 4);
        As[(k4 * 4 + 0) * 36 + row] = v.x; As[(k4 * 4 + 1) * 36 + row] = v.y;
        As[(k4 * 4 + 2) * 36 + row] = v.z; As[(k4 * 4 + 3) * 36 + row] = v.w;
      }
      {
        int row = tid >> 2, k4 = tid & 3;
        float4 v = *(const float4*)(Mu + (size_t)row * DD + k0 + k4 * 4);
        Bs[(k4 * 4 + 0) * 68 + row] = v.x; Bs[(k4 * 4 + 1) * 68 + row] = v.y;
        Bs[(k4 * 4 + 2) * 68 + row] = v.z; Bs[(k4 * 4 + 3) * 68 + row] = v.w;
      }
      __syncthreads();
      #pragma unroll
      for (int kk = 0; kk < GBK; kk++) {
        float a[2] = {As[kk * 36 + tr * 2], As[kk * 36 + tr * 2 + 1]};
        float4 b0 = *(const float4*)&Bs[kk * 68 + tc * 4];
        float bb[4] = {b0.x, b0.y, b0.z, b0.w};
        #pragma unroll
        for (int x = 0; x < 2; x++)
          #pragma unroll
          for (int y = 0; y < 4; y++) acc[x][y] += a[x] * bb[y];
      }
      __syncthreads();
    }
    #pragma unroll
    for (int x = 0; x < 2; x++) {
      int q = bm + tr * 2 + x;
      float4 v = make_float4(acc[x][0], acc[x][1], acc[x][2], acc[x][3]);
      *(float4*)(xmup + ((size_t)kq * QNQ + q) * CNUM + tc * 4) = v;
    }
  }
}

// ============ merged trinv level 256: X(i,j) = -Binv(i,:)*C*Ainv(:,j) ============
__global__ __launch_bounds__(256) void k_m256(const float* __restrict__ tlow,
    float* __restrict__ W, unsigned short* __restrict__ PW) {
  __shared__ float sh[3 * 64 * 68];
  float* As = sh;
  float* Bs = sh + 64 * 68;
  float* tsh = sh + 2 * 64 * 68;
  int b = blockIdx.x, tid = threadIdx.x;
  int g = b >> 2, rem = b & 3, i = rem >> 1, j = rem & 1;
  int base = g * 256;
  float xacc[4][4] = {};
  for (int k = 0; k <= i; k++) {
    float tacc[4][4] = {};
    for (int l = j; l < 2; l++) {
      __syncthreads();
      tile_stage(As, tlow + (size_t)(base + 128 + 64 * k) * DD + base + 64 * l, DD); // C(k,l)
      tile_stage(Bs, W + (size_t)(base + 64 * l) * DD + base + 64 * j, DD);          // Ainv(l,j)
      __syncthreads();
      tile_fma(tacc, As, Bs);
    }
    __syncthreads();
    {
      int tr = tid >> 4, tc = tid & 15;
      #pragma unroll
      for (int x = 0; x < 4; x++)
        #pragma unroll
        for (int y = 0; y < 4; y++) tsh[(tr * 4 + x) * 68 + tc * 4 + y] = tacc[x][y];
    }
    tile_stage(As, W + (size_t)(base + 128 + 64 * i) * DD + base + 128 + 64 * k, DD); // Binv(i,k)
    __syncthreads();
    tile_fma(xacc, As, tsh);
  }
  tile_out_neg(xacc, W, PW, base + 128 + 64 * i, base + 64 * j);
}

// 64x64 NN GEMM tile on caller LDS (stride 68): Cd = sgn * A[:,k0:k1] * B[k0:k1,:]
__device__ __forceinline__ void nn64_sh(float* As, float* Bs,
    const float* __restrict__ A, int lda, const float* __restrict__ B, int ldb,
    float* __restrict__ Cd, int ldc, int k0, int k1, float sgn,
    unsigned short* __restrict__ Pw, int gr0, int gc0) {
  int tid = threadIdx.x, tr = tid >> 4, tc = tid & 15;
  float acc[4][4] = {};
  for (int kc = k0; kc < k1; kc += 64) {
    #pragma unroll
    for (int p = 0; p < 4; p++) {
      int f4 = tid + 256 * p;
      int row = f4 >> 4, c4 = f4 & 15;
      *(float4*)&As[row * 68 + c4 * 4] = *(const float4*)(A + (size_t)row * lda + kc + c4 * 4);
      *(float4*)&Bs[row * 68 + c4 * 4] = *(const float4*)(B + (size_t)(kc + row) * ldb + c4 * 4);
    }
    __syncthreads();
    #pragma unroll
    for (int kk = 0; kk < 64; kk++) {
      float a[4];
      #pragma unroll
      for (int x = 0; x < 4; x++) a[x] = As[(tr * 4 + x) * 68 + kk];
      float4 bv = *(const float4*)&Bs[kk * 68 + tc * 4];
      float bb[4] = {bv.x, bv.y, bv.z, bv.w};
      #pragma unroll
      for (int x = 0; x < 4; x++)
        #pragma unroll
        for (int y = 0; y < 4; y++) acc[x][y] += a[x] * bb[y];
    }
    __syncthreads();
  }
  #pragma unroll
  for (int x = 0; x < 4; x++) {
    float4 v = make_float4(sgn * acc[x][0], sgn * acc[x][1],
                           sgn * acc[x][2], sgn * acc[x][3]);
    *(float4*)(Cd + (size_t)(tr * 4 + x) * ldc + tc * 4) = v;
    if (Pw) {
      size_t prow = (size_t)(gr0 + tr * 4 + x) * 1024 + gc0 + tc * 4;
      float vv[4] = {v.x, v.y, v.z, v.w};
      #pragma unroll
      for (int y = 0; y < 4; y++) {
        unsigned short h = f2bf(vv[y]), l = f2bf(vv[y] - bf2f(h));
        Pw[prow + y] = h;
        Pw[prow + 512 + y] = l;
      }
    }
  }
}

// trinv level-512 T: reads tlow directly (region strictly lower)
__global__ __launch_bounds__(256) void k_triT(const float* __restrict__ tlow,
                                              const float* __restrict__ W,
                                              float* __restrict__ T, int s) {
  __shared__ float sh[2 * 64 * 68];
  int h = s >> 1, tiles = h >> 6, per = tiles * tiles;
  int g = blockIdx.x / per, rem = blockIdx.x % per;
  int ti = rem / tiles, tj = rem % tiles;
  int base = g * s;
  const float* A = tlow + (size_t)(base + h + ti * 64) * DD + base;
  const float* B = W + (size_t)base * DD + base + tj * 64;
  float* Cd = T + (size_t)g * h * h + (size_t)(ti * 64) * h + tj * 64;
  nn64_sh(sh, sh + 64 * 68, A, DD, B, DD, Cd, h, tj * 64, h, 1.0f, nullptr, 0, 0);
}

// trinv level-512 X (emits PW)
__global__ __launch_bounds__(256) void k_triX(float* __restrict__ W,
                                              const float* __restrict__ T, int s,
                                              unsigned short* __restrict__ PW) {
  __shared__ float sh[2 * 64 * 68];
  int h = s >> 1, tiles = h >> 6, per = tiles * tiles;
  int g = blockIdx.x / per, rem = blockIdx.x % per;
  int ti = rem / tiles, tj = rem % tiles;
  int base = g * s;
  const float* A = W + (size_t)(base + h + ti * 64) * DD + base + h;
  const float* B = T + (size_t)g * h * h + tj * 64;
  int gr0 = base + h + ti * 64, gc0 = base + tj * 64;
  float* Cd = W + (size_t)gr0 * DD + gc0;
  nn64_sh(sh, sh + 64 * 68, A, DD, B, h, Cd, DD, 0, (ti + 1) * 64, -1.0f, PW, gr0, gc0);
}

#define PSTR 80   // LDS row stride in bf16
// ============ F3: Y-GEMM via 4-combo bf16-split MFMA (tri-skip) + wm ============
__global__ __launch_bounds__(256) void f_y_wm(const unsigned short* __restrict__ PX,
    const unsigned short* __restrict__ PW, const float* __restrict__ W,
    const float* __restrict__ m, float* __restrict__ Y,
    unsigned short* __restrict__ Pm, float* __restrict__ wm) {
  __shared__ unsigned short AshH[64 * PSTR];
  __shared__ unsigned short AshL[64 * PSTR];
  __shared__ unsigned short BshH[64 * PSTR];
  __shared__ unsigned short BshL[64 * PSTR];
  int b = blockIdx.x, tid = threadIdx.x;
  if (b < 392) {            // 49 m-tiles x 8 n-tiles, 64x64
    int mt = b >> 3, nt = b & 7;
    int bm = mt * 64, bn = nt * 64;
    int lane = tid & 63, wave = tid >> 6;
    int wr = wave >> 1, wc = wave & 1;
    int mrow = lane & 15, q = lane >> 4;
    f32x4 acc00 = {}, acc01 = {}, acc10 = {}, acc11 = {};
    int kchunks = nt + 1;   // W lower-triangular: k < bn+64
    for (int it = 0; it < kchunks; it++) {
      int kc = it * 64;
      #pragma unroll
      for (int p = 0; p < 2; p++) {
        int idx = tid + 256 * p;
        int row = idx >> 3, c8 = (idx & 7) * 8;
        *(short8*)&AshH[row * PSTR + c8] =
            *(const short8*)(PX + (size_t)(bm + row) * 1024 + kc + c8);
        *(short8*)&AshL[row * PSTR + c8] =
            *(const short8*)(PX + (size_t)(bm + row) * 1024 + 512 + kc + c8);
        *(short8*)&BshH[row * PSTR + c8] =
            *(const short8*)(PW + (size_t)(bn + row) * 1024 + kc + c8);
        *(short8*)&BshL[row * PSTR + c8] =
            *(const short8*)(PW + (size_t)(bn + row) * 1024 + 512 + kc + c8);
      }
      __syncthreads();
      #pragma unroll
      for (int ks = 0; ks < 2; ks++) {
        int ko = ks * 32 + q * 8;
        short8 ah0 = *(const short8*)&AshH[(wr * 32 + mrow) * PSTR + ko];
        short8 ah1 = *(const short8*)&AshH[(wr * 32 + 16 + mrow) * PSTR + ko];
        short8 al0 = *(const short8*)&AshL[(wr * 32 + mrow) * PSTR + ko];
        short8 al1 = *(const short8*)&AshL[(wr * 32 + 16 + mrow) * PSTR + ko];
        short8 bh0 = *(const short8*)&BshH[(wc * 32 + mrow) * PSTR + ko];
        short8 bh1 = *(const short8*)&BshH[(wc * 32 + 16 + mrow) * PSTR + ko];
        short8 bl0 = *(const short8*)&BshL[(wc * 32 + mrow) * PSTR + ko];
        short8 bl1 = *(const short8*)&BshL[(wc * 32 + 16 + mrow) * PSTR + ko];
        acc00 = __builtin_amdgcn_mfma_f32_16x16x32_bf16(ah0, bh0, acc00, 0, 0, 0);
        acc00 = __builtin_amdgcn_mfma_f32_16x16x32_bf16(ah0, bl0, acc00, 0, 0, 0);
        acc00 = __builtin_amdgcn_mfma_f32_16x16x32_bf16(al0, bh0, acc00, 0, 0, 0);
        acc00 = __builtin_amdgcn_mfma_f32_16x16x32_bf16(al0, bl0, acc00, 0, 0, 0);
        acc01 = __builtin_amdgcn_mfma_f32_16x16x32_bf16(ah0, bh1, acc01, 0, 0, 0);
        acc01 = __builtin_amdgcn_mfma_f32_16x16x32_bf16(ah0, bl1, acc01, 0, 0, 0);
        acc01 = __builtin_amdgcn_mfma_f32_16x16x32_bf16(al0, bh1, acc01, 0, 0, 0);
        acc01 = __builtin_amdgcn_mfma_f32_16x16x32_bf16(al0, bl1, acc01, 0, 0, 0);
        acc10 = __builtin_amdgcn_mfma_f32_16x16x32_bf16(ah1, bh0, acc10, 0, 0, 0);
        acc10 = __builtin_amdgcn_mfma_f32_16x16x32_bf16(ah1, bl0, acc10, 0, 0, 0);
        acc10 = __builtin_amdgcn_mfma_f32_16x16x32_bf16(al1, bh0, acc10, 0, 0, 0);
        acc10 = __builtin_amdgcn_mfma_f32_16x16x32_bf16(al1, bl0, acc10, 0, 0, 0);
        acc11 = __builtin_amdgcn_mfma_f32_16x16x32_bf16(ah1, bh1, acc11, 0, 0, 0);
        acc11 = __builtin_amdgcn_mfma_f32_16x16x32_bf16(ah1, bl1, acc11, 0, 0, 0);
        acc11 = __builtin_amdgcn_mfma_f32_16x16x32_bf16(al1, bh1, acc11, 0, 0, 0);
        acc11 = __builtin_amdgcn_mfma_f32_16x16x32_bf16(al1, bl1, acc11, 0, 0, 0);
      }
      __syncthreads();
    }
    #pragma unroll
    for (int r = 0; r < 4; r++) {
      int row0 = bm + wr * 32 + q * 4 + r;
      int row1 = row0 + 16;
      int col0 = bn + wc * 32 + mrow;
      float vv[4] = {acc00[r], acc01[r], acc10[r], acc11[r]};
      int rows[4] = {row0, row0, row1, row1};
      int cols[4] = {col0, col0 + 16, col0, col0 + 16};
      #pragma unroll
      for (int e = 0; e < 4; e++) {
        Y[(size_t)rows[e] * DD + cols[e]] = vv[e];
        unsigned short h = f2bf(vv[e]), l = f2bf(vv[e] - bf2f(h));
        Pm[(size_t)rows[e] * 1024 + cols[e]] = h;
        Pm[(size_t)rows[e] * 1024 + 512 + cols[e]] = l;
      }
    }
  } else {                  // wm[row] = W[row, 0..row] . m  (triangular-bounded)
    int wave = tid >> 6, lane = tid & 63;
    int row = (b - 392) * 4 + wave;
    float s = 0.0f;
    for (int j = lane; j <= row; j += 64) s += W[(size_t)row * DD + j] * m[j];
    for (int off = 32; off > 0; off >>= 1) s += __shfl_down(s, off);
    if (lane == 0) wm[row] = s;
  }
}

// ============ F5: Rg MFMA (both xor-passes, single buffer) + query z/qn/yn + SM consts ============
__global__ __launch_bounds__(256) void f_z_rg(const unsigned short* __restrict__ Pm,
    const float* __restrict__ Y, const float* __restrict__ tdiag,
    const int* __restrict__ rowmap, const float* __restrict__ Xq,
    const float* __restrict__ wm, float* __restrict__ cst,
    float* __restrict__ Rg,
    float* __restrict__ z, float* __restrict__ qn, float* __restrict__ yn) {
  __shared__ unsigned short Ash[64 * PSTR];   // 10.2 KB
  __shared__ unsigned short Bsh[64 * PSTR];
  __shared__ unsigned short Csh[64 * PSTR];
  int b = blockIdx.x, tid = threadIdx.x;
  if (b < 544) {            // 17 m-tiles x 32 n-tiles, 64x64 out
    int bm = (b >> 5) * 64, bn = (b & 31) * 64;
    int lane = tid & 63, wave = tid >> 6;
    int wr = wave >> 1, wc = wave & 1;
    int mrow = lane & 15, q = lane >> 4;
    int srowA[2];
    #pragma unroll
    for (int p = 0; p < 2; p++) srowA[p] = rowmap[bm + ((tid + 256 * p) >> 3)];
    f32x4 acc00 = {}, acc01 = {}, acc10 = {}, acc11 = {};
    for (int it = 0; it < 16; it++) {
      int kc = it * 64;
      int kcX = kc ^ 512;
      #pragma unroll
      for (int p = 0; p < 2; p++) {
        int idx = tid + 256 * p;
        int row = idx >> 3, c8 = (idx & 7) * 8;
        *(short8*)&Ash[row * PSTR + c8] =
            *(const short8*)(Pm + (size_t)srowA[p] * 1024 + kc + c8);
        *(short8*)&Bsh[row * PSTR + c8] =
            *(const short8*)(Pm + (size_t)(bn + row) * 1024 + kc + c8);
        *(short8*)&Csh[row * PSTR + c8] =
            *(const short8*)(Pm + (size_t)(bn + row) * 1024 + kcX + c8);
      }
      __syncthreads();
      #pragma unroll
      for (int ks = 0; ks < 2; ks++) {
        int ko = ks * 32 + q * 8;
        short8 a0 = *(const short8*)&Ash[(wr * 32 + mrow) * PSTR + ko];
        short8 a1 = *(const short8*)&Ash[(wr * 32 + 16 + mrow) * PSTR + ko];
        short8 b0 = *(const short8*)&Bsh[(wc * 32 + mrow) * PSTR + ko];
        short8 b1 = *(const short8*)&Bsh[(wc * 32 + 16 + mrow) * PSTR + ko];
        short8 c0 = *(const short8*)&Csh[(wc * 32 + mrow) * PSTR + ko];
        short8 c1 = *(const short8*)&Csh[(wc * 32 + 16 + mrow) * PSTR + ko];
        acc00 = __builtin_amdgcn_mfma_f32_16x16x32_bf16(a0, b0, acc00, 0, 0, 0);
        acc01 = __builtin_amdgcn_mfma_f32_16x16x32_bf16(a0, b1, acc01, 0, 0, 0);
        acc10 = __builtin_amdgcn_mfma_f32_16x16x32_bf16(a1, b0, acc10, 0, 0, 0);
        acc11 = __builtin_amdgcn_mfma_f32_16x16x32_bf16(a1, b1, acc11, 0, 0, 0);
        acc00 = __builtin_amdgcn_mfma_f32_16x16x32_bf16(a0, c0, acc00, 0, 0, 0);
        acc01 = __builtin_amdgcn_mfma_f32_16x16x32_bf16(a0, c1, acc01, 0, 0, 0);
        acc10 = __builtin_amdgcn_mfma_f32_16x16x32_bf16(a1, c0, acc10, 0, 0, 0);
        acc11 = __builtin_amdgcn_mfma_f32_16x16x32_bf16(a1, c1, acc11, 0, 0, 0);
      }
      __syncthreads();
    }
    #pragma unroll
    for (int r = 0; r < 4; r++) {
      int row0 = bm + wr * 32 + q * 4 + r;
      int row1 = row0 + 16;
      int col0 = bn + wc * 32 + mrow;
      Rg[(size_t)row0 * QNQ + col0]      = acc00[r];
      Rg[(size_t)row0 * QNQ + col0 + 16] = acc01[r];
      Rg[(size_t)row1 * QNQ + col0]      = acc10[r];
      Rg[(size_t)row1 * QNQ + col0 + 16] = acc11[r];
    }
  } else if (b < 1056) {    // query rows: z = Y.wm, qn = |x|^2, yn = |Y|^2
    int wave = tid >> 6, lane = tid & 63;
    int row = (b - 544) * 4 + wave;
    const float* xr = Xq + (size_t)row * DD;
    const float* yr = Y + (size_t)row * DD;
    float sz = 0.0f, s1 = 0.0f, s2 = 0.0f;
    for (int j4 = lane; j4 < 128; j4 += 64) {
      float4 xv = *(const float4*)(xr + j4 * 4);
      float4 yv = *(const float4*)(yr + j4 * 4);
      float4 wv = *(const float4*)(wm + j4 * 4);
      sz += yv.x * wv.x + yv.y * wv.y + yv.z * wv.z + yv.w * wv.w;
      s1 += xv.x * xv.x + xv.y * xv.y + xv.z * xv.z + xv.w * xv.w;
      s2 += yv.x * yv.x + yv.y * yv.y + yv.z * yv.z + yv.w * yv.w;
    }
    for (int off = 32; off > 0; off >>= 1) {
      sz += __shfl_down(sz, off);
      s1 += __shfl_down(s1, off);
      s2 += __shfl_down(s2, off);
    }
    if (lane == 0) {
      z[row] = sz;
      qn[row] = s1;
      yn[row] = s2;
    }
  } else {                  // SM consts (wm + tdiag only)
    __shared__ float red[256], red2[256];
    float a = 0.0f, l = 0.0f;
    for (int t = tid; t < DD; t += 256) {
      float w = wm[t]; a += w * w;
      l += logf(fabsf(tdiag[t]));
    }
    red[tid] = a; red2[tid] = l;
    __syncthreads();
    for (int off = 128; off > 0; off >>= 1) {
      if (tid < off) { red[tid] += red[tid + off]; red2[tid] += red2[tid + off]; }
      __syncthreads();
    }
    if (tid == 0) {
      float kap = cst[0], ss = red[0];
      cst[10] = kap / (1.0f + kap * ss);
      cst[11] = 2.0f * red2[0] + logf(1.0f + kap * ss);
    }
  }
}

// ============ F6: per-class Gram (zs = Y.wm) + GJ inverse + bias ============
#define YSTRIDE 516
__global__ __launch_bounds__(256) void k_gramminv(const float* Y, const float* wm,
    const int* rowmap, const float* cst, float* zg, float* Vmu, float* muBmu,
    float* Minv, float* bias) {
  __shared__ float Ys[17 * YSTRIDE];
  __shared__ float zs[17];
  __shared__ float aug[17][35];
  __shared__ float colk[17];
  __shared__ int pivrow;
  __shared__ float detacc;
  int c = blockIdx.x, tid = threadIdx.x;
  for (int t = tid; t < 17 * 128; t += 256) {
    int r = t >> 7, col = t & 127;
    *(float4*)&Ys[r * YSTRIDE + col * 4] =
        *(const float4*)(Y + (size_t)rowmap[c * 17 + r] * DD + col * 4);
  }
  __syncthreads();
  {
    int wave = tid >> 6, lane = tid & 63;
    for (int a = wave; a < 17; a += 4) {
      float s = 0.0f;
      for (int j = lane; j < DD; j += 64) s += Ys[a * YSTRIDE + j] * wm[j];
      for (int off = 32; off > 0; off >>= 1) s += __shfl_down(s, off);
      if (lane == 0) zs[a] = s;
    }
  }
  __syncthreads();
  float csm = cst[10];
  for (int e = tid; e < 289; e += 256) {
    int a = e / 17, bb = e % 17;
    const float* ra = &Ys[a * YSTRIDE];
    const float* rb = &Ys[bb * YSTRIDE];
    float s = 0.0f;
    for (int k = 0; k < 128; k++) {
      float4 va = *(const float4*)&ra[k * 4];
      float4 vb = *(const float4*)&rb[k * 4];
      s += va.x * vb.x + va.y * vb.y + va.z * vb.z + va.w * vb.w;
    }
    float g = s - csm * zs[a] * zs[bb];
    if (a == bb) g += (a < 16) ? 1.0f : cst[9];
    aug[a][bb] = g;
    aug[a][17 + bb] = (a == bb) ? 1.0f : 0.0f;
  }
  __syncthreads();
  if (tid < 17) {
    float gv = aug[tid][16];
    if (tid == 16) gv -= cst[9];
    Vmu[c * 17 + tid] = gv;
    if (tid == 16) muBmu[c] = gv;
    zg[c * 17 + tid] = zs[tid];
  }
  if (tid == 0) detacc = 0.0f;
  __syncthreads();
  for (int k = 0; k < 17; k++) {
    if (tid == 0) {
      int p = k; float best = fabsf(aug[k][k]);
      for (int r = k + 1; r < 17; r++) {
        float v = fabsf(aug[r][k]);
        if (v > best) { best = v; p = r; }
      }
      pivrow = p;
    }
    __syncthreads();
    int p = pivrow;
    if (p != k) {
      for (int cc = tid; cc < 34; cc += 256) {
        float tmp = aug[k][cc]; aug[k][cc] = aug[p][cc]; aug[p][cc] = tmp;
      }
    }
    __syncthreads();
    if (tid == 0) detacc += logf(fabsf(aug[k][k]));
    if (tid < 17) colk[tid] = aug[tid][k];
    __syncthreads();
    float invp = 1.0f / aug[k][k];
    for (int cc = tid; cc < 34; cc += 256) aug[k][cc] *= invp;
    __syncthreads();
    for (int t = tid; t < 17 * 34; t += 256) {
      int r = t / 34, cc = t % 34;
      if (r != k) aug[r][cc] -= colk[r] * aug[k][cc];
    }
    __syncthreads();
  }
  for (int t = tid; t < 289; t += 256) Minv[(size_t)c * 289 + t] = aug[t / 17][17 + t % 17];
  if (tid == 0) {
    float slog = logf(fabsf(cst[5])) + detacc;
    float logdetSigma = cst[8] + cst[11] + slog;
    bias[c] = cst[4] - 0.5f * logdetSigma;
  }
}

// final epilogue: Woodbury-corrected Mahalanobis -> logits[q,c]
__global__ __launch_bounds__(256) void k_logits(const float* __restrict__ Rg,
    const float* z, const float* zg,
    const float* Vmu, const float* muBmu, const float* mun, const float* yn,
    const float* qn, const float* xmup, const float* Minv, const float* bias,
    const float* cst, float* out) {
  __shared__ float Ms[289], Vs[17], Zs[17];
  int c = blockIdx.y;
  int q = blockIdx.x * 256 + threadIdx.x;
  for (int t = threadIdx.x; t < 289; t += 256) Ms[t] = Minv[(size_t)c * 289 + t];
  if (threadIdx.x < 17) {
    Vs[threadIdx.x] = Vmu[c * 17 + threadIdx.x];
    Zs[threadIdx.x] = zg[c * 17 + threadIdx.x];
  }
  __syncthreads();
  float csm = cst[10], scale = cst[1], common = cst[2], coef = cst[3];
  float zq = z[q];
  float r[17];
  float xBmu = 0.0f;
  for (int a = 0; a < 17; a++) {
    float raw = Rg[(size_t)(c * 17 + a) * QNQ + q] - csm * Zs[a] * zq;
    if (a == 16) xBmu = raw;
    r[a] = raw - Vs[a];
  }
  float qB = yn[q] - csm * zq * zq;
  float quadB = qB - 2.0f * xBmu + muBmu[c];
  float corr = 0.0f;
  for (int a = 0; a < 17; a++) {
    float e = 0.0f;
    for (int bb = 0; bb < 17; bb++) e += Ms[a * 17 + bb] * r[bb];
    corr += r[a] * e;
  }
  float distB = (quadB - corr) / scale;
  float xm = 0.0f;
  #pragma unroll
  for (int p = 0; p < XKS; p++)
    xm += xmup[((size_t)p * QNQ + q) * CNUM + c];
  float dn = qn[q] - 2.0f * xm + mun[c];
  float dist = (1.0f - REGP) * distB + REGP * dn;
  out[(size_t)q * CNUM + c] = bias[c] - coef * log1pf(dist / common);
}

// ---------------- host ----------------
extern "C" void kernel_launch(void* const* d_in, const int* in_sizes, int n_in,
                              void* d_out, int out_size, void* d_ws, size_t ws_size,
                              hipStream_t stream) {
  const float* Xs    = (const float*)d_in[0];
  const int*   labels= (const int*)d_in[1];
  const float* Xq    = (const float*)d_in[2];
  const float* m     = (const float*)d_in[3];
  const float* kappa = (const float*)d_in[4];
  const float* nu    = (const float*)d_in[5];
  const float* tdiag = (const float*)d_in[6];
  const float* tlow  = (const float*)d_in[7];
  float* ws = (float*)d_ws;
  float* W    = ws + OFF_W;
  float* mu   = ws + OFF_MU;
  float* Y    = ws + OFF_Y;
  float* z    = ws + OFF_Z;
  float* wm   = ws + OFF_WM;
  float* cst  = ws + OFF_CONST;
  int*   idx  = (int*)(ws + OFF_IDX);
  int*   rmap = (int*)(ws + OFF_RMAP);
  float* zg   = ws + OFF_ZG;
  float* Vmu  = ws + OFF_VMU;
  float* muBmu= ws + OFF_MUBMU;
  float* mun  = ws + OFF_MUN;
  float* Minv = ws + OFF_MINV;
  float* bias = ws + OFF_BIAS;
  float* qn   = ws + OFF_QNRM;
  float* yn   = ws + OFF_YN;
  float* xmup = ws + OFF_XMU;
  float* Rg   = ws + OFF_RG;
  unsigned short* P  = (unsigned short*)(ws + OFF_P);
  unsigned short* PX = (unsigned short*)(ws + OFF_PX);
  unsigned short* PW = (unsigned short*)(ws + OFF_PW);
  float* Ttmp = ws + OFF_RG;       // trinv scratch, reused (Rg written later)
  float* out  = (float*)d_out;

  // F1: consts + classidx + mu/mun(+PX) + diag-inv(+PW) + PX(Xq/Xs)
  f_init<<<905, 256, 0, stream>>>(tdiag, tlow, kappa, nu, labels, Xs, Xq, m,
                                  W, cst, idx, rmap, mu, mun, PX, PW);
  // trinv: merged level-128 (T+X, fused with xmu), merged level-256, split level-512
  k_m128_xmu<<<260, 256, 0, stream>>>(tlow, W, W, Xq, mu, xmup, PW);
  k_m256<<<8, 256, 0, stream>>>(tlow, W, PW);
  k_triT<<<16, 256, 0, stream>>>(tlow, W, Ttmp, 512);
  k_triX<<<16, 256, 0, stream>>>(W, Ttmp, 512, PW);
  // Y via 4-combo split MFMA (tri-skip) + wm (triangular-bounded)
  f_y_wm<<<520, 256, 0, stream>>>(PX, PW, W, m, Y, P, wm);
  // Rg MFMA (single buffer, both passes) + query z/qn/yn + SM consts
  f_z_rg<<<544 + 512 + 1, 256, 0, stream>>>(P, Y, tdiag, rmap, Xq, wm, cst, Rg, z, qn, yn);
  // Gram (zs = Y.wm) + 17x17 inverse + bias
  k_gramminv<<<64, 256, 0, stream>>>(Y, wm, rmap, cst, zg, Vmu, muBmu, Minv, bias);
  k_logits<<<dim3(QNQ / 256, CNUM), 256, 0, stream>>>(Rg, z, zg, Vmu, muBmu,
                                                      mun, yn, qn, xmup, Minv, bias,
                                                      cst, out);
  (void)in_sizes; (void)n_in; (void)out_size; (void)ws_size;
}

// Round 18
// 204.496 us; speedup vs baseline: 1.2939x; 1.0505x over previous
//
#include <hip/hip_runtime.h>
#include <math.h>

// Problem dims (fixed by setup_inputs)
#define DD    512
#define CNUM  64
#define SHOTS 16
#define NSUP  1024
#define QNQ   2048
#define REGP  0.1f
#define XKS   4      // xmu split-K parts

typedef __attribute__((ext_vector_type(8))) short short8;   // 8 bf16 = 4 VGPRs
typedef __attribute__((ext_vector_type(4))) float f32x4;

// bf16 round-to-nearest-even, raw bits
__device__ __forceinline__ unsigned short f2bf(float f) {
  unsigned int u = __float_as_uint(f);
  unsigned int r = (u + 0x7fffu + ((u >> 16) & 1u)) >> 16;
  return (unsigned short)r;
}
__device__ __forceinline__ float bf2f(unsigned short h) {
  return __uint_as_float((unsigned int)h << 16);
}

// ---------------- workspace layout (in floats) ----------------
// L is never materialized: all consumers read tdiag/tlow directly.
static constexpr size_t OFF_W     = 0;                       // 512*512
static constexpr size_t OFF_MU    = OFF_W     + 512*512;     // 64*512
static constexpr size_t OFF_Y     = OFF_MU    + 64*512;      // 3136*512
static constexpr size_t OFF_Z     = OFF_Y     + 3136*512;    // 2048
static constexpr size_t OFF_WM    = OFF_Z     + 3136;        // 512
static constexpr size_t OFF_CONST = OFF_WM    + 512;         // 16
static constexpr size_t OFF_IDX   = OFF_CONST + 16;          // 1024 ints
static constexpr size_t OFF_RMAP  = OFF_IDX   + 1024;        // 1088 ints
static constexpr size_t OFF_ZG    = OFF_RMAP  + 1088;        // 1088
static constexpr size_t OFF_VMU   = OFF_ZG    + 1088;        // 1088
static constexpr size_t OFF_MUBMU = OFF_VMU   + 1088;        // 64
static constexpr size_t OFF_MUN   = OFF_MUBMU + 64;          // 64
static constexpr size_t OFF_MINV  = OFF_MUN   + 64;          // 64*289
static constexpr size_t OFF_BIAS  = OFF_MINV  + 64*289;      // 64
static constexpr size_t OFF_QNRM  = OFF_BIAS  + 64;          // 2048
static constexpr size_t OFF_YN    = OFF_QNRM  + 2048;        // 2048
static constexpr size_t OFF_XMU   = OFF_YN    + 2048;        // XKS*64*2048 ([p][c][q])
static constexpr size_t OFF_RG    = OFF_XMU   + (size_t)XKS*2048*64; // 1088*2048 (also trinv T)
static constexpr size_t OFF_P     = OFF_RG    + 1088*2048;   // 3136*1024 bf16 (Y split)
static constexpr size_t OFF_PX    = OFF_P     + 3136*512;    // 3136*1024 bf16 (X split)
static constexpr size_t OFF_PW    = OFF_PX    + 3136*512;    // 512*1024 bf16 (W split)

// consts: 0 kap, 1 scale, 2 common, 3 coef, 4 bias0, 5 jlast,
// 6 cmu_m, 7 cmu_x, 8 D*log(scale), 9 Jinv_last, 10 c_sm, 11 logdetB

// ============ F1: consts + classidx + mu/mun(+PX) + diag-inv(+PW) + PX(X) ============
__global__ __launch_bounds__(256) void f_init(const float* tdiag, const float* tlow,
    const float* kappa, const float* nu, const int* labels, const float* Xs,
    const float* Xq, const float* m, float* W, float* cst, int* idx,
    int* rowmap, float* mu, float* mun,
    unsigned short* PX, unsigned short* PW) {
  __shared__ float sh[2 * 64 * 68 + 32 * 33];   // Ld | Wd | tsh = 39 KB
  __shared__ int sidx[SHOTS];
  int b = blockIdx.x, tid = threadIdx.x;
  if (b == 0) {
    if (tid == 0) {
      float kap = fabsf(kappa[0]) + 1e-6f;
      float nu_ = fmaxf(nu[0], (float)(DD - 1) + 1e-6f);
      float common = nu_ + (float)SHOTS + 1.0f - (float)DD;
      float scale = (kap + SHOTS + 1.0f) / ((nu_ + SHOTS - DD + 1.0f) * (kap + SHOTS));
      cst[0] = kap;
      cst[1] = scale;
      cst[2] = common;
      cst[3] = 0.5f * (common + DD);
      cst[4] = lgammaf(0.5f * (common + DD)) - lgammaf(0.5f * common)
               - 0.5f * (float)DD * logf(common);
      cst[5] = -(kap + SHOTS);
      cst[6] = kap / (kap + SHOTS);
      cst[7] = 1.0f / (kap + SHOTS);
      cst[8] = (float)DD * logf(scale);
      cst[9] = -1.0f / (kap + SHOTS);
    }
  } else if (b < 65) {
    int c = b - 1;
    if (tid < 64) {
      int lane = tid, cnt = 0;
      for (int i0 = 0; i0 < NSUP; i0 += 64) {
        int lab = labels[i0 + lane];
        unsigned long long mm = __ballot(lab == c);
        if (lab == c) {
          int pos = cnt + __popcll(mm & ((1ull << lane) - 1ull));
          if (pos < SHOTS) idx[c * SHOTS + pos] = i0 + lane;
        }
        cnt += __popcll(mm);
      }
    }
    __syncthreads();
    if (tid < 17)
      rowmap[c * 17 + tid] = (tid < SHOTS) ? (QNQ + idx[c * SHOTS + tid])
                                           : (QNQ + NSUP + c);
  } else if (b < 129) {
    // mu/mun with locally re-derived idx; also emit PX for mu rows
    int c = b - 65;
    if (tid < 64) {
      int lane = tid, cnt = 0;
      for (int i0 = 0; i0 < NSUP; i0 += 64) {
        int lab = labels[i0 + lane];
        unsigned long long mm = __ballot(lab == c);
        if (lab == c) {
          int pos = cnt + __popcll(mm & ((1ull << lane) - 1ull));
          if (pos < SHOTS) sidx[pos] = i0 + lane;
        }
        cnt += __popcll(mm);
      }
    }
    __syncthreads();
    float kap = fabsf(kappa[0]) + 1e-6f;
    float cm = kap / (kap + SHOTS), cx = 1.0f / (kap + SHOTS);
    float* red = sh;
    float acc = 0.0f;
    size_t prow = (size_t)(3072 + c) * 1024;
    for (int d = tid; d < DD; d += 256) {
      float s = 0.0f;
      for (int sh_ = 0; sh_ < SHOTS; sh_++)
        s += Xs[(size_t)sidx[sh_] * DD + d];
      float v = cm * m[d] + cx * s;
      mu[(size_t)c * DD + d] = v;
      unsigned short h = f2bf(v), l = f2bf(v - bf2f(h));
      PX[prow + d] = h;
      PX[prow + 512 + d] = l;
      acc += v * v;
    }
    red[tid] = acc;
    __syncthreads();
    for (int off = 128; off > 0; off >>= 1) {
      if (tid < off) red[tid] += red[tid + off];
      __syncthreads();
    }
    if (tid == 0) mun[c] = red[0];
  } else if (b < 137) {
    // diag 64x64 inverse via blocked 16->32->64
    int jb = b - 129;
    float* Ld = sh;                   // [64][68]
    float* Wd = sh + 64 * 68;         // [64][68]
    float* tsh = sh + 2 * 64 * 68;    // [32][33]
    for (int t = tid; t < 4096; t += 256) {
      int r = t >> 6, c = t & 63;
      int gr = jb * 64 + r;
      float v = (r == c) ? fabsf(tdiag[gr])
              : (r > c ? tlow[(size_t)gr * DD + jb * 64 + c] : 0.0f);
      Ld[r * 68 + c] = v;
      Wd[r * 68 + c] = 0.0f;
    }
    __syncthreads();
    if (tid < 64) {
      int s = tid >> 4, t = tid & 15;
      int r0 = s * 16;
      #pragma unroll
      for (int i = 0; i < 16; i++) {
        float w = (i == t) ? 1.0f : 0.0f;
        #pragma unroll
        for (int k = 0; k < 16; k++)
          if (k < i) w -= Ld[(r0 + i) * 68 + r0 + k] * Wd[(r0 + k) * 68 + r0 + t];
        Wd[(r0 + i) * 68 + r0 + t] = w / Ld[(r0 + i) * 68 + r0 + i];
      }
    }
    __syncthreads();
    for (int g2 = 0; g2 < 2; g2++) {
      int r0 = g2 * 32 + 16, c0 = g2 * 32;
      int rr = tid >> 4, cc = tid & 15;
      float t_ = 0.0f;
      #pragma unroll
      for (int k = 0; k < 16; k++)
        t_ += Ld[(r0 + rr) * 68 + c0 + k] * Wd[(c0 + k) * 68 + c0 + cc];
      tsh[rr * 33 + cc] = t_;
      __syncthreads();
      float x = 0.0f;
      #pragma unroll
      for (int k = 0; k < 16; k++)
        x -= Wd[(r0 + rr) * 68 + r0 + k] * tsh[k * 33 + cc];
      Wd[(r0 + rr) * 68 + c0 + cc] = x;
      __syncthreads();
    }
    {
      int rr = tid >> 6, cc = tid & 63;
      #pragma unroll
      for (int p = 0; p < 4; p++) {
        int r = rr + p * 4, c = cc;
        if (c < 32) {
          float t_ = 0.0f;
          #pragma unroll
          for (int k = 0; k < 32; k++)
            t_ += Ld[(32 + r) * 68 + k] * Wd[k * 68 + c];
          tsh[r * 33 + c] = t_;
        } else {
          int c2 = c - 32;
          float t_ = 0.0f;
          #pragma unroll
          for (int k = 0; k < 32; k++)
            t_ += Ld[(32 + r + 16) * 68 + k] * Wd[k * 68 + c2];
          tsh[(r + 16) * 33 + c2] = t_;
        }
      }
      __syncthreads();
      #pragma unroll
      for (int p = 0; p < 4; p++) {
        int r = rr + p * 4, c = cc;
        int r2 = (c < 32) ? r : r + 16;
        int c2 = (c < 32) ? c : c - 32;
        float x = 0.0f;
        #pragma unroll
        for (int k = 0; k < 32; k++)
          x -= Wd[(32 + r2) * 68 + 32 + k] * tsh[k * 33 + c2];
        Wd[(32 + r2) * 68 + c2] = x;
      }
    }
    __syncthreads();
    float* Wblk = W + (size_t)(jb * 64) * DD + jb * 64;
    for (int t = tid; t < 4096; t += 256) {
      int r = t >> 6, c = t & 63;
      float v = Wd[r * 68 + c];
      Wblk[(size_t)r * DD + c] = v;
      unsigned short h = f2bf(v), l = f2bf(v - bf2f(h));
      size_t prow = (size_t)(jb * 64 + r) * 1024 + jb * 64 + c;
      PW[prow] = h;
      PW[prow + 512] = l;
    }
  } else {
    // PX for Xq/Xs rows: 4 rows per block
    int r0 = (b - 137) * 4;
    int row = r0 + (tid >> 6), lane = tid & 63;
    const float* src = (row < QNQ) ? Xq + (size_t)row * DD
                                   : Xs + (size_t)(row - QNQ) * DD;
    size_t prow = (size_t)row * 1024;
    #pragma unroll
    for (int p = 0; p < 2; p++) {
      int col = lane * 8 + p * 4;
      float4 v = *(const float4*)(src + col);
      ushort4 hi, lo;
      hi.x = f2bf(v.x); lo.x = f2bf(v.x - bf2f(hi.x));
      hi.y = f2bf(v.y); lo.y = f2bf(v.y - bf2f(hi.y));
      hi.z = f2bf(v.z); lo.z = f2bf(v.z - bf2f(hi.z));
      hi.w = f2bf(v.w); lo.w = f2bf(v.w - bf2f(hi.w));
      *(ushort4*)(PX + prow + col) = hi;
      *(ushort4*)(PX + prow + 512 + col) = lo;
    }
  }
}

// ---- 64x64 tile helpers (stride-68 LDS) ----
__device__ __forceinline__ void tile_stage(float* S, const float* __restrict__ G, int ldg) {
  int tid = threadIdx.x;
  #pragma unroll
  for (int p = 0; p < 4; p++) {
    int f4 = tid + 256 * p;
    int row = f4 >> 4, c4 = (f4 & 15) * 4;
    *(float4*)&S[row * 68 + c4] = *(const float4*)(G + (size_t)row * ldg + c4);
  }
}
__device__ __forceinline__ void tile_fma(float acc[4][4], const float* As, const float* Bs) {
  int tid = threadIdx.x, tr = tid >> 4, tc = tid & 15;
  #pragma unroll
  for (int kk = 0; kk < 64; kk++) {
    float a[4];
    #pragma unroll
    for (int x = 0; x < 4; x++) a[x] = As[(tr * 4 + x) * 68 + kk];
    float4 bv = *(const float4*)&Bs[kk * 68 + tc * 4];
    float bb[4] = {bv.x, bv.y, bv.z, bv.w};
    #pragma unroll
    for (int x = 0; x < 4; x++)
      #pragma unroll
      for (int y = 0; y < 4; y++) acc[x][y] += a[x] * bb[y];
  }
}
__device__ __forceinline__ void tile_out_neg(const float acc[4][4], float* W,
    unsigned short* PW, int gr0, int gc0) {
  int tid = threadIdx.x, tr = tid >> 4, tc = tid & 15;
  #pragma unroll
  for (int x = 0; x < 4; x++) {
    #pragma unroll
    for (int y = 0; y < 4; y++) {
      float v = -acc[x][y];
      W[(size_t)(gr0 + tr * 4 + x) * DD + gc0 + tc * 4 + y] = v;
      unsigned short h = f2bf(v), l = f2bf(v - bf2f(h));
      size_t prow = (size_t)(gr0 + tr * 4 + x) * 1024 + gc0 + tc * 4 + y;
      PW[prow] = h;
      PW[prow + 512] = l;
    }
  }
}

#define GBK 16
// ============ merged trinv level 128 (T+X in one) fused with xmu partials ============
// xmu stored transposed: xmup[p][c][q] for coalesced k_logits reads
__global__ __launch_bounds__(256) void k_m128_xmu(const float* __restrict__ tlow,
    const float* __restrict__ W_, float* __restrict__ Wout,
    const float* __restrict__ Xq, const float* __restrict__ Mu,
    float* __restrict__ xmup, unsigned short* __restrict__ PW) {
  __shared__ float sh[3 * 64 * 68];   // As | Bs | tsh = 52.2 KB
  int b = blockIdx.x, tid = threadIdx.x;
  if (b < 4) {
    float* As = sh;
    float* Bs = sh + 64 * 68;
    float* tsh = sh + 2 * 64 * 68;
    int base = b * 128;
    float tacc[4][4] = {};
    tile_stage(As, tlow + (size_t)(base + 64) * DD + base, DD);   // C
    tile_stage(Bs, W_ + (size_t)base * DD + base, DD);            // Ainv
    __syncthreads();
    tile_fma(tacc, As, Bs);
    __syncthreads();
    {
      int tr = tid >> 4, tc = tid & 15;
      #pragma unroll
      for (int x = 0; x < 4; x++)
        #pragma unroll
        for (int y = 0; y < 4; y++) tsh[(tr * 4 + x) * 68 + tc * 4 + y] = tacc[x][y];
    }
    tile_stage(As, W_ + (size_t)(base + 64) * DD + base + 64, DD); // Binv
    __syncthreads();
    float xacc[4][4] = {};
    tile_fma(xacc, As, tsh);
    tile_out_neg(xacc, Wout, PW, base + 64, base);
  } else {                  // xmu partials transposed: 32 q-cols x 64 c-rows
    float* Ms = sh;               // Mu: 64 rows x 16k, stride 68
    float* Qs = sh + 64 * 68;     // Xq: 32 rows x 16k, stride 36
    int xb = b - 4;
    int bm = (xb & 63) * 32, kq = xb >> 6;
    int tr = tid >> 4, tc = tid & 15;   // tr: c-group of 4, tc: q-pair
    float acc[4][2] = {};
    int k0s = kq * (DD / XKS), k0e = k0s + DD / XKS;
    for (int k0 = k0s; k0 < k0e; k0 += GBK) {
      {
        int row = tid >> 2, k4 = tid & 3;   // Mu 64x16 = 256 float4
        float4 v = *(const float4*)(Mu + (size_t)row * DD + k0 + k4 * 4);
        Ms[(k4 * 4 + 0) * 68 + row] = v.x; Ms[(k4 * 4 + 1) * 68 + row] = v.y;
        Ms[(k4 * 4 + 2) * 68 + row] = v.z; Ms[(k4 * 4 + 3) * 68 + row] = v.w;
      }
      if (tid < 128) {
        int row = tid >> 2, k4 = tid & 3;   // Xq 32x16 = 128 float4
        float4 v = *(const float4*)(Xq + (size_t)(bm + row) * DD + k0 + k4 * 4);
        Qs[(k4 * 4 + 0) * 36 + row] = v.x; Qs[(k4 * 4 + 1) * 36 + row] = v.y;
        Qs[(k4 * 4 + 2) * 36 + row] = v.z; Qs[(k4 * 4 + 3) * 36 + row] = v.w;
      }
      __syncthreads();
      #pragma unroll
      for (int kk = 0; kk < GBK; kk++) {
        float4 m0 = *(const float4*)&Ms[kk * 68 + tr * 4];
        float a[4] = {m0.x, m0.y, m0.z, m0.w};
        float q0 = Qs[kk * 36 + tc * 2], q1 = Qs[kk * 36 + tc * 2 + 1];
        #pragma unroll
        for (int y = 0; y < 4; y++) {
          acc[y][0] += a[y] * q0;
          acc[y][1] += a[y] * q1;
        }
      }
      __syncthreads();
    }
    #pragma unroll
    for (int y = 0; y < 4; y++) {
      float2 v = make_float2(acc[y][0], acc[y][1]);
      *(float2*)(xmup + ((size_t)kq * CNUM + tr * 4 + y) * QNQ + bm + tc * 2) = v;
    }
  }
}

// ============ merged trinv level 256: X(i,j) = -Binv(i,:)*C*Ainv(:,j) ============
__global__ __launch_bounds__(256) void k_m256(const float* __restrict__ tlow,
    float* __restrict__ W, unsigned short* __restrict__ PW) {
  __shared__ float sh[3 * 64 * 68];
  float* As = sh;
  float* Bs = sh + 64 * 68;
  float* tsh = sh + 2 * 64 * 68;
  int b = blockIdx.x, tid = threadIdx.x;
  int g = b >> 2, rem = b & 3, i = rem >> 1, j = rem & 1;
  int base = g * 256;
  float xacc[4][4] = {};
  for (int k = 0; k <= i; k++) {
    float tacc[4][4] = {};
    for (int l = j; l < 2; l++) {
      __syncthreads();
      tile_stage(As, tlow + (size_t)(base + 128 + 64 * k) * DD + base + 64 * l, DD); // C(k,l)
      tile_stage(Bs, W + (size_t)(base + 64 * l) * DD + base + 64 * j, DD);          // Ainv(l,j)
      __syncthreads();
      tile_fma(tacc, As, Bs);
    }
    __syncthreads();
    {
      int tr = tid >> 4, tc = tid & 15;
      #pragma unroll
      for (int x = 0; x < 4; x++)
        #pragma unroll
        for (int y = 0; y < 4; y++) tsh[(tr * 4 + x) * 68 + tc * 4 + y] = tacc[x][y];
    }
    tile_stage(As, W + (size_t)(base + 128 + 64 * i) * DD + base + 128 + 64 * k, DD); // Binv(i,k)
    __syncthreads();
    tile_fma(xacc, As, tsh);
  }
  tile_out_neg(xacc, W, PW, base + 128 + 64 * i, base + 64 * j);
}

// 64x64 NN GEMM tile on caller LDS (stride 68)
__device__ __forceinline__ void nn64_sh(float* As, float* Bs,
    const float* __restrict__ A, int lda, const float* __restrict__ B, int ldb,
    float* __restrict__ Cd, int ldc, int k0, int k1, float sgn,
    unsigned short* __restrict__ Pw, int gr0, int gc0) {
  int tid = threadIdx.x, tr = tid >> 4, tc = tid & 15;
  float acc[4][4] = {};
  for (int kc = k0; kc < k1; kc += 64) {
    #pragma unroll
    for (int p = 0; p < 4; p++) {
      int f4 = tid + 256 * p;
      int row = f4 >> 4, c4 = f4 & 15;
      *(float4*)&As[row * 68 + c4 * 4] = *(const float4*)(A + (size_t)row * lda + kc + c4 * 4);
      *(float4*)&Bs[row * 68 + c4 * 4] = *(const float4*)(B + (size_t)(kc + row) * ldb + c4 * 4);
    }
    __syncthreads();
    #pragma unroll
    for (int kk = 0; kk < 64; kk++) {
      float a[4];
      #pragma unroll
      for (int x = 0; x < 4; x++) a[x] = As[(tr * 4 + x) * 68 + kk];
      float4 bv = *(const float4*)&Bs[kk * 68 + tc * 4];
      float bb[4] = {bv.x, bv.y, bv.z, bv.w};
      #pragma unroll
      for (int x = 0; x < 4; x++)
        #pragma unroll
        for (int y = 0; y < 4; y++) acc[x][y] += a[x] * bb[y];
    }
    __syncthreads();
  }
  #pragma unroll
  for (int x = 0; x < 4; x++) {
    float4 v = make_float4(sgn * acc[x][0], sgn * acc[x][1],
                           sgn * acc[x][2], sgn * acc[x][3]);
    *(float4*)(Cd + (size_t)(tr * 4 + x) * ldc + tc * 4) = v;
    if (Pw) {
      size_t prow = (size_t)(gr0 + tr * 4 + x) * 1024 + gc0 + tc * 4;
      float vv[4] = {v.x, v.y, v.z, v.w};
      #pragma unroll
      for (int y = 0; y < 4; y++) {
        unsigned short h = f2bf(vv[y]), l = f2bf(vv[y] - bf2f(h));
        Pw[prow + y] = h;
        Pw[prow + 512 + y] = l;
      }
    }
  }
}

// trinv level-512 T: reads tlow directly (region strictly lower)
__global__ __launch_bounds__(256) void k_triT(const float* __restrict__ tlow,
                                              const float* __restrict__ W,
                                              float* __restrict__ T, int s) {
  __shared__ float sh[2 * 64 * 68];
  int h = s >> 1, tiles = h >> 6, per = tiles * tiles;
  int g = blockIdx.x / per, rem = blockIdx.x % per;
  int ti = rem / tiles, tj = rem % tiles;
  int base = g * s;
  const float* A = tlow + (size_t)(base + h + ti * 64) * DD + base;
  const float* B = W + (size_t)base * DD + base + tj * 64;
  float* Cd = T + (size_t)g * h * h + (size_t)(ti * 64) * h + tj * 64;
  nn64_sh(sh, sh + 64 * 68, A, DD, B, DD, Cd, h, tj * 64, h, 1.0f, nullptr, 0, 0);
}

// trinv level-512 X (emits PW)
__global__ __launch_bounds__(256) void k_triX(float* __restrict__ W,
                                              const float* __restrict__ T, int s,
                                              unsigned short* __restrict__ PW) {
  __shared__ float sh[2 * 64 * 68];
  int h = s >> 1, tiles = h >> 6, per = tiles * tiles;
  int g = blockIdx.x / per, rem = blockIdx.x % per;
  int ti = rem / tiles, tj = rem % tiles;
  int base = g * s;
  const float* A = W + (size_t)(base + h + ti * 64) * DD + base + h;
  const float* B = T + (size_t)g * h * h + tj * 64;
  int gr0 = base + h + ti * 64, gc0 = base + tj * 64;
  float* Cd = W + (size_t)gr0 * DD + gc0;
  nn64_sh(sh, sh + 64 * 68, A, DD, B, h, Cd, DD, 0, (ti + 1) * 64, -1.0f, PW, gr0, gc0);
}

#define PSTR 80   // LDS row stride in bf16
// ============ F3: Y-GEMM via 4-combo bf16-split MFMA (tri-skip) + wm ============
__global__ __launch_bounds__(256) void f_y_wm(const unsigned short* __restrict__ PX,
    const unsigned short* __restrict__ PW, const float* __restrict__ W,
    const float* __restrict__ m, float* __restrict__ Y,
    unsigned short* __restrict__ Pm, float* __restrict__ wm) {
  __shared__ unsigned short AshH[64 * PSTR];
  __shared__ unsigned short AshL[64 * PSTR];
  __shared__ unsigned short BshH[64 * PSTR];
  __shared__ unsigned short BshL[64 * PSTR];
  int b = blockIdx.x, tid = threadIdx.x;
  if (b < 392) {            // 49 m-tiles x 8 n-tiles, 64x64
    int mt = b >> 3, nt = b & 7;
    int bm = mt * 64, bn = nt * 64;
    int lane = tid & 63, wave = tid >> 6;
    int wr = wave >> 1, wc = wave & 1;
    int mrow = lane & 15, q = lane >> 4;
    f32x4 acc00 = {}, acc01 = {}, acc10 = {}, acc11 = {};
    int kchunks = nt + 1;   // W lower-triangular: k < bn+64
    for (int it = 0; it < kchunks; it++) {
      int kc = it * 64;
      #pragma unroll
      for (int p = 0; p < 2; p++) {
        int idx = tid + 256 * p;
        int row = idx >> 3, c8 = (idx & 7) * 8;
        *(short8*)&AshH[row * PSTR + c8] =
            *(const short8*)(PX + (size_t)(bm + row) * 1024 + kc + c8);
        *(short8*)&AshL[row * PSTR + c8] =
            *(const short8*)(PX + (size_t)(bm + row) * 1024 + 512 + kc + c8);
        *(short8*)&BshH[row * PSTR + c8] =
            *(const short8*)(PW + (size_t)(bn + row) * 1024 + kc + c8);
        *(short8*)&BshL[row * PSTR + c8] =
            *(const short8*)(PW + (size_t)(bn + row) * 1024 + 512 + kc + c8);
      }
      __syncthreads();
      #pragma unroll
      for (int ks = 0; ks < 2; ks++) {
        int ko = ks * 32 + q * 8;
        short8 ah0 = *(const short8*)&AshH[(wr * 32 + mrow) * PSTR + ko];
        short8 ah1 = *(const short8*)&AshH[(wr * 32 + 16 + mrow) * PSTR + ko];
        short8 al0 = *(const short8*)&AshL[(wr * 32 + mrow) * PSTR + ko];
        short8 al1 = *(const short8*)&AshL[(wr * 32 + 16 + mrow) * PSTR + ko];
        short8 bh0 = *(const short8*)&BshH[(wc * 32 + mrow) * PSTR + ko];
        short8 bh1 = *(const short8*)&BshH[(wc * 32 + 16 + mrow) * PSTR + ko];
        short8 bl0 = *(const short8*)&BshL[(wc * 32 + mrow) * PSTR + ko];
        short8 bl1 = *(const short8*)&BshL[(wc * 32 + 16 + mrow) * PSTR + ko];
        acc00 = __builtin_amdgcn_mfma_f32_16x16x32_bf16(ah0, bh0, acc00, 0, 0, 0);
        acc00 = __builtin_amdgcn_mfma_f32_16x16x32_bf16(ah0, bl0, acc00, 0, 0, 0);
        acc00 = __builtin_amdgcn_mfma_f32_16x16x32_bf16(al0, bh0, acc00, 0, 0, 0);
        acc00 = __builtin_amdgcn_mfma_f32_16x16x32_bf16(al0, bl0, acc00, 0, 0, 0);
        acc01 = __builtin_amdgcn_mfma_f32_16x16x32_bf16(ah0, bh1, acc01, 0, 0, 0);
        acc01 = __builtin_amdgcn_mfma_f32_16x16x32_bf16(ah0, bl1, acc01, 0, 0, 0);
        acc01 = __builtin_amdgcn_mfma_f32_16x16x32_bf16(al0, bh1, acc01, 0, 0, 0);
        acc01 = __builtin_amdgcn_mfma_f32_16x16x32_bf16(al0, bl1, acc01, 0, 0, 0);
        acc10 = __builtin_amdgcn_mfma_f32_16x16x32_bf16(ah1, bh0, acc10, 0, 0, 0);
        acc10 = __builtin_amdgcn_mfma_f32_16x16x32_bf16(ah1, bl0, acc10, 0, 0, 0);
        acc10 = __builtin_amdgcn_mfma_f32_16x16x32_bf16(al1, bh0, acc10, 0, 0, 0);
        acc10 = __builtin_amdgcn_mfma_f32_16x16x32_bf16(al1, bl0, acc10, 0, 0, 0);
        acc11 = __builtin_amdgcn_mfma_f32_16x16x32_bf16(ah1, bh1, acc11, 0, 0, 0);
        acc11 = __builtin_amdgcn_mfma_f32_16x16x32_bf16(ah1, bl1, acc11, 0, 0, 0);
        acc11 = __builtin_amdgcn_mfma_f32_16x16x32_bf16(al1, bh1, acc11, 0, 0, 0);
        acc11 = __builtin_amdgcn_mfma_f32_16x16x32_bf16(al1, bl1, acc11, 0, 0, 0);
      }
      __syncthreads();
    }
    #pragma unroll
    for (int r = 0; r < 4; r++) {
      int row0 = bm + wr * 32 + q * 4 + r;
      int row1 = row0 + 16;
      int col0 = bn + wc * 32 + mrow;
      float vv[4] = {acc00[r], acc01[r], acc10[r], acc11[r]};
      int rows[4] = {row0, row0, row1, row1};
      int cols[4] = {col0, col0 + 16, col0, col0 + 16};
      #pragma unroll
      for (int e = 0; e < 4; e++) {
        Y[(size_t)rows[e] * DD + cols[e]] = vv[e];
        unsigned short h = f2bf(vv[e]), l = f2bf(vv[e] - bf2f(h));
        Pm[(size_t)rows[e] * 1024 + cols[e]] = h;
        Pm[(size_t)rows[e] * 1024 + 512 + cols[e]] = l;
      }
    }
  } else {                  // wm[row] = W[row, 0..row] . m  (triangular-bounded)
    int wave = tid >> 6, lane = tid & 63;
    int row = (b - 392) * 4 + wave;
    float s = 0.0f;
    for (int j = lane; j <= row; j += 64) s += W[(size_t)row * DD + j] * m[j];
    for (int off = 32; off > 0; off >>= 1) s += __shfl_down(s, off);
    if (lane == 0) wm[row] = s;
  }
}

// ============ F5: Rg MFMA + query z/qn/yn + SM consts + gram/minv (one launch) ============
// gram blocks are self-sufficient: recompute csm/logdetB from wm/tdiag locally.
__global__ __launch_bounds__(256) void f_z_rg_gram(const unsigned short* __restrict__ Pm,
    const float* __restrict__ Y, const float* __restrict__ tdiag,
    const int* __restrict__ rowmap, const float* __restrict__ Xq,
    const float* __restrict__ wm, float* __restrict__ cst,
    float* __restrict__ Rg,
    float* __restrict__ z, float* __restrict__ qn, float* __restrict__ yn,
    float* __restrict__ zg, float* __restrict__ Vmu, float* __restrict__ muBmu,
    float* __restrict__ Minv, float* __restrict__ bias) {
  __shared__ float sh[9920];   // 39.7 KB union (MFMA staging 30.7 KB | gram 39.6 KB)
  __shared__ int pivrow;
  __shared__ float detacc, csmS, ldbS;
  int b = blockIdx.x, tid = threadIdx.x;
  if (b < 544) {            // Rg: 17 m-tiles x 32 n-tiles, 64x64 out, both xor-passes
    unsigned short* ush = (unsigned short*)sh;
    unsigned short* Ash = ush;
    unsigned short* Bsh = ush + 64 * PSTR;
    unsigned short* Csh = ush + 2 * 64 * PSTR;
    int bm = (b >> 5) * 64, bn = (b & 31) * 64;
    int lane = tid & 63, wave = tid >> 6;
    int wr = wave >> 1, wc = wave & 1;
    int mrow = lane & 15, q = lane >> 4;
    int srowA[2];
    #pragma unroll
    for (int p = 0; p < 2; p++) srowA[p] = rowmap[bm + ((tid + 256 * p) >> 3)];
    f32x4 acc00 = {}, acc01 = {}, acc10 = {}, acc11 = {};
    for (int it = 0; it < 16; it++) {
      int kc = it * 64;
      int kcX = kc ^ 512;
      #pragma unroll
      for (int p = 0; p < 2; p++) {
        int idx = tid + 256 * p;
        int row = idx >> 3, c8 = (idx & 7) * 8;
        *(short8*)&Ash[row * PSTR + c8] =
            *(const short8*)(Pm + (size_t)srowA[p] * 1024 + kc + c8);
        *(short8*)&Bsh[row * PSTR + c8] =
            *(const short8*)(Pm + (size_t)(bn + row) * 1024 + kc + c8);
        *(short8*)&Csh[row * PSTR + c8] =
            *(const short8*)(Pm + (size_t)(bn + row) * 1024 + kcX + c8);
      }
      __syncthreads();
      #pragma unroll
      for (int ks = 0; ks < 2; ks++) {
        int ko = ks * 32 + q * 8;
        short8 a0 = *(const short8*)&Ash[(wr * 32 + mrow) * PSTR + ko];
        short8 a1 = *(const short8*)&Ash[(wr * 32 + 16 + mrow) * PSTR + ko];
        short8 b0 = *(const short8*)&Bsh[(wc * 32 + mrow) * PSTR + ko];
        short8 b1 = *(const short8*)&Bsh[(wc * 32 + 16 + mrow) * PSTR + ko];
        short8 c0 = *(const short8*)&Csh[(wc * 32 + mrow) * PSTR + ko];
        short8 c1 = *(const short8*)&Csh[(wc * 32 + 16 + mrow) * PSTR + ko];
        acc00 = __builtin_amdgcn_mfma_f32_16x16x32_bf16(a0, b0, acc00, 0, 0, 0);
        acc01 = __builtin_amdgcn_mfma_f32_16x16x32_bf16(a0, b1, acc01, 0, 0, 0);
        acc10 = __builtin_amdgcn_mfma_f32_16x16x32_bf16(a1, b0, acc10, 0, 0, 0);
        acc11 = __builtin_amdgcn_mfma_f32_16x16x32_bf16(a1, b1, acc11, 0, 0, 0);
        acc00 = __builtin_amdgcn_mfma_f32_16x16x32_bf16(a0, c0, acc00, 0, 0, 0);
        acc01 = __builtin_amdgcn_mfma_f32_16x16x32_bf16(a0, c1, acc01, 0, 0, 0);
        acc10 = __builtin_amdgcn_mfma_f32_16x16x32_bf16(a1, c0, acc10, 0, 0, 0);
        acc11 = __builtin_amdgcn_mfma_f32_16x16x32_bf16(a1, c1, acc11, 0, 0, 0);
      }
      __syncthreads();
    }
    #pragma unroll
    for (int r = 0; r < 4; r++) {
      int row0 = bm + wr * 32 + q * 4 + r;
      int row1 = row0 + 16;
      int col0 = bn + wc * 32 + mrow;
      Rg[(size_t)row0 * QNQ + col0]      = acc00[r];
      Rg[(size_t)row0 * QNQ + col0 + 16] = acc01[r];
      Rg[(size_t)row1 * QNQ + col0]      = acc10[r];
      Rg[(size_t)row1 * QNQ + col0 + 16] = acc11[r];
    }
  } else if (b < 1056) {    // query rows: z = Y.wm, qn = |x|^2, yn = |Y|^2
    int wave = tid >> 6, lane = tid & 63;
    int row = (b - 544) * 4 + wave;
    const float* xr = Xq + (size_t)row * DD;
    const float* yr = Y + (size_t)row * DD;
    float sz = 0.0f, s1 = 0.0f, s2 = 0.0f;
    for (int j4 = lane; j4 < 128; j4 += 64) {
      float4 xv = *(const float4*)(xr + j4 * 4);
      float4 yv = *(const float4*)(yr + j4 * 4);
      float4 wv = *(const float4*)(wm + j4 * 4);
      sz += yv.x * wv.x + yv.y * wv.y + yv.z * wv.z + yv.w * wv.w;
      s1 += xv.x * xv.x + xv.y * xv.y + xv.z * xv.z + xv.w * xv.w;
      s2 += yv.x * yv.x + yv.y * yv.y + yv.z * yv.z + yv.w * yv.w;
    }
    for (int off = 32; off > 0; off >>= 1) {
      sz += __shfl_down(sz, off);
      s1 += __shfl_down(s1, off);
      s2 += __shfl_down(s2, off);
    }
    if (lane == 0) {
      z[row] = sz;
      qn[row] = s1;
      yn[row] = s2;
    }
  } else if (b == 1056) {   // SM consts (for k_logits)
    float* red = sh;
    float* red2 = sh + 256;
    float a = 0.0f, l = 0.0f;
    for (int t = tid; t < DD; t += 256) {
      float w = wm[t]; a += w * w;
      l += logf(fabsf(tdiag[t]));
    }
    red[tid] = a; red2[tid] = l;
    __syncthreads();
    for (int off = 128; off > 0; off >>= 1) {
      if (tid < off) { red[tid] += red[tid + off]; red2[tid] += red2[tid + off]; }
      __syncthreads();
    }
    if (tid == 0) {
      float kap = cst[0], ss = red[0];
      cst[10] = kap / (1.0f + kap * ss);
      cst[11] = 2.0f * red2[0] + logf(1.0f + kap * ss);
    }
  } else {                  // gram + GJ inverse + bias (self-sufficient csm/logdetB)
    int c = b - 1057;
    float* red = sh;
    float* red2 = sh + 256;
    // local SM consts
    {
      float a = 0.0f, l = 0.0f;
      for (int t = tid; t < DD; t += 256) {
        float w = wm[t]; a += w * w;
        l += logf(fabsf(tdiag[t]));
      }
      red[tid] = a; red2[tid] = l;
      __syncthreads();
      for (int off = 128; off > 0; off >>= 1) {
        if (tid < off) { red[tid] += red[tid + off]; red2[tid] += red2[tid + off]; }
        __syncthreads();
      }
      if (tid == 0) {
        float kap = cst[0], ss = red[0];
        csmS = kap / (1.0f + kap * ss);
        ldbS = 2.0f * red2[0] + logf(1.0f + kap * ss);
      }
      __syncthreads();
    }
    float* Ys  = sh;                 // 17 x 516 = 8772
    float* aug = sh + 8772;          // 17 x 35 = 595
    float* zs  = aug + 595;          // 17
    float* colk = zs + 17;           // 17
    for (int t = tid; t < 17 * 128; t += 256) {
      int r = t >> 7, col = t & 127;
      *(float4*)&Ys[r * 516 + col * 4] =
          *(const float4*)(Y + (size_t)rowmap[c * 17 + r] * DD + col * 4);
    }
    __syncthreads();
    {
      int wave = tid >> 6, lane = tid & 63;
      for (int a = wave; a < 17; a += 4) {
        float s = 0.0f;
        for (int j = lane; j < DD; j += 64) s += Ys[a * 516 + j] * wm[j];
        for (int off = 32; off > 0; off >>= 1) s += __shfl_down(s, off);
        if (lane == 0) zs[a] = s;
      }
    }
    __syncthreads();
    float csm = csmS;
    for (int e = tid; e < 289; e += 256) {
      int a = e / 17, bb = e % 17;
      const float* ra = &Ys[a * 516];
      const float* rb = &Ys[bb * 516];
      float s = 0.0f;
      for (int k = 0; k < 128; k++) {
        float4 va = *(const float4*)&ra[k * 4];
        float4 vb = *(const float4*)&rb[k * 4];
        s += va.x * vb.x + va.y * vb.y + va.z * vb.z + va.w * vb.w;
      }
      float g = s - csm * zs[a] * zs[bb];
      if (a == bb) g += (a < 16) ? 1.0f : cst[9];
      aug[a * 35 + bb] = g;
      aug[a * 35 + 17 + bb] = (a == bb) ? 1.0f : 0.0f;
    }
    __syncthreads();
    if (tid < 17) {
      float gv = aug[tid * 35 + 16];
      if (tid == 16) gv -= cst[9];
      Vmu[c * 17 + tid] = gv;
      if (tid == 16) muBmu[c] = gv;
      zg[c * 17 + tid] = zs[tid];
    }
    if (tid == 0) detacc = 0.0f;
    __syncthreads();
    for (int k = 0; k < 17; k++) {
      if (tid == 0) {
        int p = k; float best = fabsf(aug[k * 35 + k]);
        for (int r = k + 1; r < 17; r++) {
          float v = fabsf(aug[r * 35 + k]);
          if (v > best) { best = v; p = r; }
        }
        pivrow = p;
      }
      __syncthreads();
      int p = pivrow;
      if (p != k) {
        for (int cc = tid; cc < 34; cc += 256) {
          float tmp = aug[k * 35 + cc]; aug[k * 35 + cc] = aug[p * 35 + cc]; aug[p * 35 + cc] = tmp;
        }
      }
      __syncthreads();
      if (tid == 0) detacc += logf(fabsf(aug[k * 35 + k]));
      if (tid < 17) colk[tid] = aug[tid * 35 + k];
      __syncthreads();
      float invp = 1.0f / aug[k * 35 + k];
      for (int cc = tid; cc < 34; cc += 256) aug[k * 35 + cc] *= invp;
      __syncthreads();
      for (int t = tid; t < 17 * 34; t += 256) {
        int r = t / 34, cc = t % 34;
        if (r != k) aug[r * 35 + cc] -= colk[r] * aug[k * 35 + cc];
      }
      __syncthreads();
    }
    for (int t = tid; t < 289; t += 256)
      Minv[(size_t)c * 289 + t] = aug[(t / 17) * 35 + 17 + t % 17];
    if (tid == 0) {
      float slog = logf(fabsf(cst[5])) + detacc;
      float logdetSigma = cst[8] + ldbS + slog;
      bias[c] = cst[4] - 0.5f * logdetSigma;
    }
  }
}

// final epilogue: Woodbury-corrected Mahalanobis -> logits[q,c]
__global__ __launch_bounds__(256) void k_logits(const float* __restrict__ Rg,
    const float* z, const float* zg,
    const float* Vmu, const float* muBmu, const float* mun, const float* yn,
    const float* qn, const float* xmup, const float* Minv, const float* bias,
    const float* cst, float* out) {
  __shared__ float Ms[289], Vs[17], Zs[17];
  int c = blockIdx.y;
  int q = blockIdx.x * 256 + threadIdx.x;
  for (int t = threadIdx.x; t < 289; t += 256) Ms[t] = Minv[(size_t)c * 289 + t];
  if (threadIdx.x < 17) {
    Vs[threadIdx.x] = Vmu[c * 17 + threadIdx.x];
    Zs[threadIdx.x] = zg[c * 17 + threadIdx.x];
  }
  __syncthreads();
  float csm = cst[10], scale = cst[1], common = cst[2], coef = cst[3];
  float zq = z[q];
  float r[17];
  float xBmu = 0.0f;
  for (int a = 0; a < 17; a++) {
    float raw = Rg[(size_t)(c * 17 + a) * QNQ + q] - csm * Zs[a] * zq;
    if (a == 16) xBmu = raw;
    r[a] = raw - Vs[a];
  }
  float qB = yn[q] - csm * zq * zq;
  float quadB = qB - 2.0f * xBmu + muBmu[c];
  float corr = 0.0f;
  for (int a = 0; a < 17; a++) {
    float e = 0.0f;
    for (int bb = 0; bb < 17; bb++) e += Ms[a * 17 + bb] * r[bb];
    corr += r[a] * e;
  }
  float distB = (quadB - corr) / scale;
  float xm = 0.0f;
  #pragma unroll
  for (int p = 0; p < XKS; p++)
    xm += xmup[((size_t)(p * CNUM + c)) * QNQ + q];   // [p][c][q]: coalesced in q
  float dn = qn[q] - 2.0f * xm + mun[c];
  float dist = (1.0f - REGP) * distB + REGP * dn;
  out[(size_t)q * CNUM + c] = bias[c] - coef * log1pf(dist / common);
}

// ---------------- host ----------------
extern "C" void kernel_launch(void* const* d_in, const int* in_sizes, int n_in,
                              void* d_out, int out_size, void* d_ws, size_t ws_size,
                              hipStream_t stream) {
  const float* Xs    = (const float*)d_in[0];
  const int*   labels= (const int*)d_in[1];
  const float* Xq    = (const float*)d_in[2];
  const float* m     = (const float*)d_in[3];
  const float* kappa = (const float*)d_in[4];
  const float* nu    = (const float*)d_in[5];
  const float* tdiag = (const float*)d_in[6];
  const float* tlow  = (const float*)d_in[7];
  float* ws = (float*)d_ws;
  float* W    = ws + OFF_W;
  float* mu   = ws + OFF_MU;
  float* Y    = ws + OFF_Y;
  float* z    = ws + OFF_Z;
  float* wm   = ws + OFF_WM;
  float* cst  = ws + OFF_CONST;
  int*   idx  = (int*)(ws + OFF_IDX);
  int*   rmap = (int*)(ws + OFF_RMAP);
  float* zg   = ws + OFF_ZG;
  float* Vmu  = ws + OFF_VMU;
  float* muBmu= ws + OFF_MUBMU;
  float* mun  = ws + OFF_MUN;
  float* Minv = ws + OFF_MINV;
  float* bias = ws + OFF_BIAS;
  float* qn   = ws + OFF_QNRM;
  float* yn   = ws + OFF_YN;
  float* xmup = ws + OFF_XMU;
  float* Rg   = ws + OFF_RG;
  unsigned short* P  = (unsigned short*)(ws + OFF_P);
  unsigned short* PX = (unsigned short*)(ws + OFF_PX);
  unsigned short* PW = (unsigned short*)(ws + OFF_PW);
  float* Ttmp = ws + OFF_RG;       // trinv scratch, reused (Rg written later)
  float* out  = (float*)d_out;

  // F1: consts + classidx + mu/mun(+PX) + diag-inv(+PW) + PX(Xq/Xs)
  f_init<<<905, 256, 0, stream>>>(tdiag, tlow, kappa, nu, labels, Xs, Xq, m,
                                  W, cst, idx, rmap, mu, mun, PX, PW);
  // trinv: merged level-128 (T+X, fused with transposed xmu), merged 256, split 512
  k_m128_xmu<<<260, 256, 0, stream>>>(tlow, W, W, Xq, mu, xmup, PW);
  k_m256<<<8, 256, 0, stream>>>(tlow, W, PW);
  k_triT<<<16, 256, 0, stream>>>(tlow, W, Ttmp, 512);
  k_triX<<<16, 256, 0, stream>>>(W, Ttmp, 512, PW);
  // Y via 4-combo split MFMA (tri-skip) + wm (triangular-bounded)
  f_y_wm<<<520, 256, 0, stream>>>(PX, PW, W, m, Y, P, wm);
  // Rg MFMA + query z/qn/yn + SM consts + gram/minv/bias (one launch)
  f_z_rg_gram<<<544 + 512 + 1 + 64, 256, 0, stream>>>(P, Y, tdiag, rmap, Xq, wm,
                                                      cst, Rg, z, qn, yn,
                                                      zg, Vmu, muBmu, Minv, bias);
  k_logits<<<dim3(QNQ / 256, CNUM), 256, 0, stream>>>(Rg, z, zg, Vmu, muBmu,
                                                      mun, yn, qn, xmup, Minv, bias,
                                                      cst, out);
  (void)in_sizes; (void)n_in; (void)out_size; (void)ws_size;
}